// Round 1
// baseline (2674.160 us; speedup 1.0000x reference)
//
#include <hip/hip_runtime.h>
#include <cstddef>

#define NPTS 2048

// ---------------------------------------------------------------- knn1 + cov
__global__ __launch_bounds__(256) void k_knn1_cov(const float* __restrict__ x,
                                                  float* __restrict__ h0) {
  const int b = blockIdx.y;
  const int tid = threadIdx.x;
  const int lane = tid & 63;
  const int w = tid >> 6;
  __shared__ float xs[NPTS * 3];
  __shared__ float sqs[NPTS];
  const float* xb = x + (size_t)b * NPTS * 3;
  for (int i = tid; i < NPTS * 3; i += 256) xs[i] = xb[i];
  __syncthreads();
  for (int n = tid; n < NPTS; n += 256) {
    float a0 = xs[3 * n], a1 = xs[3 * n + 1], a2 = xs[3 * n + 2];
    sqs[n] = fmaf(a0, a0, fmaf(a1, a1, a2 * a2));
  }
  __syncthreads();
  for (int qi = 0; qi < 16; ++qi) {
    const int nq = blockIdx.x * 64 + w * 16 + qi;
    const float qx = xs[3 * nq], qy = xs[3 * nq + 1], qz = xs[3 * nq + 2];
    const float sqq = sqs[nq];
    float d[32];
#pragma unroll
    for (int j = 0; j < 32; ++j) {
      int m = j * 64 + lane;
      float mx = xs[3 * m], my = xs[3 * m + 1], mz = xs[3 * m + 2];
      float dot = qx * mx;
      dot = fmaf(qy, my, dot);
      dot = fmaf(qz, mz, dot);
      d[j] = fmaf(-2.f, dot, sqq + sqs[m]);
    }
    unsigned mask = 0;
    int widx[16];
#pragma unroll
    for (int r = 0; r < 16; ++r) {
      float vmin = 3.4e38f;
      int mmin = 0x7fffffff;
#pragma unroll
      for (int j = 0; j < 32; ++j) {
        bool ok = !((mask >> j) & 1u) && (d[j] < vmin);
        if (ok) { vmin = d[j]; mmin = j * 64 + lane; }
      }
#pragma unroll
      for (int s = 1; s < 64; s <<= 1) {
        float ov = __shfl_xor(vmin, s, 64);
        int om = __shfl_xor(mmin, s, 64);
        if (ov < vmin || (ov == vmin && om < mmin)) { vmin = ov; mmin = om; }
      }
      widx[r] = mmin;
      if (lane == (mmin & 63)) mask |= 1u << (mmin >> 6);
    }
    // two-pass mean/cov (wave-uniform values)
    float sx = 0, sy = 0, sz = 0;
#pragma unroll
    for (int r = 0; r < 16; ++r) {
      int m = widx[r];
      sx += xs[3 * m]; sy += xs[3 * m + 1]; sz += xs[3 * m + 2];
    }
    const float mx = sx * 0.0625f, my = sy * 0.0625f, mz = sz * 0.0625f;
    float cxx = 0, cxy = 0, cxz = 0, cyy = 0, cyz = 0, czz = 0;
#pragma unroll
    for (int r = 0; r < 16; ++r) {
      int m = widx[r];
      float ax = xs[3 * m] - mx, ay = xs[3 * m + 1] - my, az = xs[3 * m + 2] - mz;
      cxx = fmaf(ax, ax, cxx); cxy = fmaf(ax, ay, cxy); cxz = fmaf(ax, az, cxz);
      cyy = fmaf(ay, ay, cyy); cyz = fmaf(ay, az, cyz); czz = fmaf(az, az, czz);
    }
    if (lane == 0) {
      float* o = h0 + ((size_t)b * NPTS + nq) * 12;
      o[0] = qx; o[1] = qy; o[2] = qz;
      o[3] = cxx; o[4] = cxy; o[5] = cxz;
      o[6] = cxy; o[7] = cyy; o[8] = cyz;
      o[9] = cxz; o[10] = cyz; o[11] = czz;
    }
  }
}

// ---------------------------------------------------------------- MLP1 (12->12->64->64, BN folded)
__global__ __launch_bounds__(256) void k_mlp1(
    const float* __restrict__ h0,
    const float* __restrict__ w1, const float* __restrict__ cb1,
    const float* __restrict__ w2, const float* __restrict__ cb2,
    const float* __restrict__ w3, const float* __restrict__ cb3,
    const float* __restrict__ bn1g, const float* __restrict__ bn1b,
    const float* __restrict__ bn1m, const float* __restrict__ bn1v,
    const float* __restrict__ bn2g, const float* __restrict__ bn2b,
    const float* __restrict__ bn2m, const float* __restrict__ bn2v,
    const float* __restrict__ bn3g, const float* __restrict__ bn3b,
    const float* __restrict__ bn3m, const float* __restrict__ bn3v,
    float* __restrict__ h3out) {
  __shared__ float W1[144], W2[768], W3[4096];
  __shared__ float S1[12], F1[12], S2[64], F2[64], S3[64], F3[64];
  __shared__ float h0s[64][12];
  __shared__ float A2[64][65];
  const int tid = threadIdx.x;
  for (int i = tid; i < 144; i += 256) W1[i] = w1[i];
  for (int i = tid; i < 768; i += 256) W2[i] = w2[i];
  for (int i = tid; i < 4096; i += 256) W3[i] = w3[i];
  if (tid < 12) {
    float s = bn1g[tid] * rsqrtf(bn1v[tid] + 1e-3f);
    S1[tid] = s; F1[tid] = (cb1[tid] - bn1m[tid]) * s + bn1b[tid];
  }
  if (tid < 64) {
    float s2 = bn2g[tid] * rsqrtf(bn2v[tid] + 1e-3f);
    S2[tid] = s2; F2[tid] = (cb2[tid] - bn2m[tid]) * s2 + bn2b[tid];
    float s3 = bn3g[tid] * rsqrtf(bn3v[tid] + 1e-3f);
    S3[tid] = s3; F3[tid] = (cb3[tid] - bn3m[tid]) * s3 + bn3b[tid];
  }
  const int p0 = blockIdx.x * 64;
  for (int i = tid; i < 64 * 12; i += 256)
    h0s[i / 12][i % 12] = h0[(size_t)p0 * 12 + i];
  __syncthreads();
  const int pl = tid >> 2;
  const int q = tid & 3;
  float v1[12];
#pragma unroll
  for (int o = 0; o < 12; ++o) {
    float a = 0.f;
#pragma unroll
    for (int i = 0; i < 12; ++i) a = fmaf(h0s[pl][i], W1[i * 12 + o], a);
    v1[o] = fmaxf(fmaf(a, S1[o], F1[o]), 0.f);
  }
#pragma unroll
  for (int o = 0; o < 16; ++o) {
    int oo = q * 16 + o;
    float a = 0.f;
#pragma unroll
    for (int i = 0; i < 12; ++i) a = fmaf(v1[i], W2[i * 64 + oo], a);
    A2[pl][oo] = fmaxf(fmaf(a, S2[oo], F2[oo]), 0.f);
  }
  __syncthreads();
  float acc[16];
#pragma unroll
  for (int o = 0; o < 16; ++o) acc[o] = 0.f;
  for (int i = 0; i < 64; ++i) {
    float xv = A2[pl][i];
#pragma unroll
    for (int o = 0; o < 16; ++o) acc[o] = fmaf(xv, W3[i * 64 + q * 16 + o], acc[o]);
  }
  float* orow = h3out + (size_t)(p0 + pl) * 64 + q * 16;
#pragma unroll
  for (int o4 = 0; o4 < 4; ++o4) {
    float4 v;
    int oo = q * 16 + 4 * o4;
    v.x = fmaxf(fmaf(acc[4 * o4 + 0], S3[oo + 0], F3[oo + 0]), 0.f);
    v.y = fmaxf(fmaf(acc[4 * o4 + 1], S3[oo + 1], F3[oo + 1]), 0.f);
    v.z = fmaxf(fmaf(acc[4 * o4 + 2], S3[oo + 2], F3[oo + 2]), 0.f);
    v.w = fmaxf(fmaf(acc[4 * o4 + 3], S3[oo + 3], F3[oo + 3]), 0.f);
    *(float4*)&orow[4 * o4] = v;
  }
}

// ---------------------------------------------------------------- sq norms
template <int C>
__global__ __launch_bounds__(256) void k_sqnorm(const float* __restrict__ h,
                                                float* __restrict__ sq) {
  const int p = blockIdx.x * 256 + threadIdx.x;
  const float* row = h + (size_t)p * C;
  float a = 0.f;
#pragma unroll
  for (int i = 0; i < C; ++i) a = fmaf(row[i], row[i], a);
  sq[p] = a;
}

// ---------------------------------------------------------------- transpose [B,N,C] -> [B,C,N]
template <int C>
__global__ __launch_bounds__(256) void k_transpose(const float* __restrict__ h,
                                                   float* __restrict__ hT) {
  __shared__ float t[64][65];
  const int b = blockIdx.z, n0 = blockIdx.x * 64, c0 = blockIdx.y * 64;
  const int tx = threadIdx.x & 63, ty = threadIdx.x >> 6;
  const size_t base = (size_t)b * NPTS * C;
#pragma unroll
  for (int k = 0; k < 16; ++k) {
    int row = 4 * k + ty;
    t[row][tx] = h[base + (size_t)(n0 + row) * C + c0 + tx];
  }
  __syncthreads();
#pragma unroll
  for (int k = 0; k < 16; ++k) {
    int row = 4 * k + ty;
    hT[base + (size_t)(c0 + row) * NPTS + n0 + tx] = t[tx][row];
  }
}

// ---------------------------------------------------------------- knn + gather-max
template <int C>
__device__ __forceinline__ void knn_select_gather(float (&d)[32], int lane, size_t hb,
                                                  int nq, const float* __restrict__ h,
                                                  float* __restrict__ outm) {
  unsigned mask = 0;
  int widx[16];
#pragma unroll
  for (int r = 0; r < 16; ++r) {
    float vmin = 3.4e38f;
    int mmin = 0x7fffffff;
#pragma unroll
    for (int j = 0; j < 32; ++j) {
      int m = (j >> 1) * 128 + 2 * lane + (j & 1);
      bool ok = !((mask >> j) & 1u) && (d[j] < vmin);
      if (ok) { vmin = d[j]; mmin = m; }
    }
#pragma unroll
    for (int s = 1; s < 64; s <<= 1) {
      float ov = __shfl_xor(vmin, s, 64);
      int om = __shfl_xor(mmin, s, 64);
      if (ov < vmin || (ov == vmin && om < mmin)) { vmin = ov; mmin = om; }
    }
    widx[r] = mmin;
    if (lane == ((mmin & 127) >> 1))
      mask |= 1u << (((mmin >> 7) << 1) | (mmin & 1));
  }
  float g0 = -3.4e38f, g1 = -3.4e38f;
#pragma unroll
  for (int r = 0; r < 16; ++r) {
    const float* row = h + hb + (size_t)widx[r] * C;
    g0 = fmaxf(g0, row[lane]);
    if (C == 128) g1 = fmaxf(g1, row[64 + lane]);
  }
  float* orow = outm + hb + (size_t)nq * C;
  orow[lane] = g0;
  if (C == 128) orow[64 + lane] = g1;
}

template <int C>
__global__ __launch_bounds__(256) void k_knn_max(const float* __restrict__ h,
                                                 const float* __restrict__ hT,
                                                 const float* __restrict__ sq,
                                                 float* __restrict__ outm) {
  constexpr int NT = NPTS / 128;  // 16
  __shared__ float tile[C * 128];
  __shared__ float qb[8 * C];
  __shared__ float sqall[NPTS];
  const int b = blockIdx.y, tid = threadIdx.x, lane = tid & 63, w = tid >> 6;
  const int nq0 = blockIdx.x * 8;
  const size_t hb = (size_t)b * NPTS * C;
  for (int i = tid; i < 8 * C; i += 256) qb[i] = h[hb + (size_t)nq0 * C + i];
  for (int i = tid; i < NPTS; i += 256) sqall[i] = sq[b * NPTS + i];
  __syncthreads();
  const int qa = 2 * w, qbi = 2 * w + 1;
  const float sqqA = sqall[nq0 + qa];
  const float sqqB = sqall[nq0 + qbi];
  float dA[2 * NT], dB[2 * NT];
#pragma unroll
  for (int t = 0; t < NT; ++t) {
    __syncthreads();  // protect tile from previous iteration's readers
    for (int i = tid; i < C * 128; i += 256) {
      int c = i >> 7, nl = i & 127;
      tile[i] = hT[hb + (size_t)c * NPTS + t * 128 + nl];
    }
    __syncthreads();
    float a0 = 0, a1 = 0, b0 = 0, b1 = 0;
#pragma unroll 4
    for (int c = 0; c < C; ++c) {
      float2 cv = *(const float2*)&tile[c * 128 + 2 * lane];
      float qav = qb[qa * C + c];
      float qbv = qb[qbi * C + c];
      a0 = fmaf(qav, cv.x, a0); a1 = fmaf(qav, cv.y, a1);
      b0 = fmaf(qbv, cv.x, b0); b1 = fmaf(qbv, cv.y, b1);
    }
    int m0 = t * 128 + 2 * lane;
    float s0 = sqall[m0], s1 = sqall[m0 + 1];
    dA[2 * t] = fmaf(-2.f, a0, sqqA + s0);
    dA[2 * t + 1] = fmaf(-2.f, a1, sqqA + s1);
    dB[2 * t] = fmaf(-2.f, b0, sqqB + s0);
    dB[2 * t + 1] = fmaf(-2.f, b1, sqqB + s1);
  }
  knn_select_gather<C>(dA, lane, hb, nq0 + qa, h, outm);
  knn_select_gather<C>(dB, lane, hb, nq0 + qbi, h, outm);
}

// ---------------------------------------------------------------- combine two denses: Wc = lw*cw, bc = lb*cw + cb
__global__ __launch_bounds__(256) void k_combine(const float* __restrict__ lw,
                                                 const float* __restrict__ lb,
                                                 const float* __restrict__ cw,
                                                 const float* __restrict__ cb,
                                                 float* __restrict__ Wc,
                                                 float* __restrict__ bc, int K, int M) {
  const int id = blockIdx.x * 256 + threadIdx.x;
  if (id < K * M) {
    int i = id / M, o = id % M;
    float a = 0.f;
    for (int k = 0; k < K; ++k) a = fmaf(lw[i * K + k], cw[k * M + o], a);
    Wc[id] = a;
  }
  if (id < M) {
    float a = cb[id];
    for (int k = 0; k < K; ++k) a = fmaf(lb[k], cw[k * M + id], a);
    bc[id] = a;
  }
}

// ---------------------------------------------------------------- GEMM apply: out = A[32768,K] * W[K,M] (+bias) [relu | colmax]
template <int K, bool RELU, bool COLMAX>
__global__ __launch_bounds__(256) void k_apply(const float* __restrict__ A,
                                               const float* __restrict__ W,
                                               const float* __restrict__ bias,
                                               float* __restrict__ out, int M) {
  __shared__ float As[64][K + 4];
  __shared__ float Bs[K][64];
  __shared__ float cm[16][64];
  const int tid = threadIdx.x;
  const int tx = tid & 15, ty = tid >> 4;
  const int rt = blockIdx.x;
  const int col0 = blockIdx.y * 64;
  const int r0 = rt * 64;
  for (int i = tid; i < 64 * K; i += 256) {
    int r = i / K, c = i % K;
    As[r][c] = A[(size_t)(r0 + r) * K + c];
  }
  for (int i = tid; i < K * 64; i += 256) {
    int k = i >> 6, j = i & 63;
    Bs[k][j] = W[(size_t)k * M + col0 + j];
  }
  __syncthreads();
  float acc[4][4];
#pragma unroll
  for (int i = 0; i < 4; ++i)
#pragma unroll
    for (int j = 0; j < 4; ++j) acc[i][j] = 0.f;
  for (int k = 0; k < K; k += 4) {
    float4 av4[4], bv4[4];
#pragma unroll
    for (int i = 0; i < 4; ++i) av4[i] = *(const float4*)&As[4 * ty + i][k];
#pragma unroll
    for (int kk = 0; kk < 4; ++kk) bv4[kk] = *(const float4*)&Bs[k + kk][4 * tx];
    float a_[4][4], b_[4][4];
#pragma unroll
    for (int i = 0; i < 4; ++i) {
      a_[i][0] = av4[i].x; a_[i][1] = av4[i].y; a_[i][2] = av4[i].z; a_[i][3] = av4[i].w;
      b_[i][0] = bv4[i].x; b_[i][1] = bv4[i].y; b_[i][2] = bv4[i].z; b_[i][3] = bv4[i].w;
    }
#pragma unroll
    for (int kk = 0; kk < 4; ++kk)
#pragma unroll
      for (int i = 0; i < 4; ++i)
#pragma unroll
        for (int j = 0; j < 4; ++j)
          acc[i][j] = fmaf(a_[i][kk], b_[kk][j], acc[i][j]);
  }
  if (RELU) {
#pragma unroll
    for (int i = 0; i < 4; ++i) {
      int r = r0 + 4 * ty + i;
      float4 v;
      v.x = fmaxf(acc[i][0] + bias[col0 + 4 * tx + 0], 0.f);
      v.y = fmaxf(acc[i][1] + bias[col0 + 4 * tx + 1], 0.f);
      v.z = fmaxf(acc[i][2] + bias[col0 + 4 * tx + 2], 0.f);
      v.w = fmaxf(acc[i][3] + bias[col0 + 4 * tx + 3], 0.f);
      *(float4*)&out[(size_t)r * M + col0 + 4 * tx] = v;
    }
  }
  if (COLMAX) {
#pragma unroll
    for (int j = 0; j < 4; ++j) {
      float mj = fmaxf(fmaxf(acc[0][j], acc[1][j]), fmaxf(acc[2][j], acc[3][j]));
      cm[ty][4 * tx + j] = mj;
    }
    __syncthreads();
    if (tid < 64) {
      float mj = cm[0][tid];
#pragma unroll
      for (int r = 1; r < 16; ++r) mj = fmaxf(mj, cm[r][tid]);
      out[(size_t)rt * M + col0 + tid] = mj + bias[col0 + tid];
    }
  }
}

// ---------------------------------------------------------------- reduce P[512][1024] -> gmax[16][1024]
__global__ __launch_bounds__(256) void k_reduce_max(const float* __restrict__ P,
                                                    float* __restrict__ gmax) {
  const int b = blockIdx.x, tid = threadIdx.x;
  for (int c = tid; c < 1024; c += 256) {
    float m = P[(size_t)(b * 32) * 1024 + c];
    for (int rt = 1; rt < 32; ++rt)
      m = fmaxf(m, P[(size_t)(b * 32 + rt) * 1024 + c]);
    gmax[b * 1024 + c] = m;
  }
}

// ---------------------------------------------------------------- head: relu(gmax*W4+b4)*W5+b5
__global__ __launch_bounds__(256) void k_head(const float* __restrict__ gmax,
                                              const float* __restrict__ w4,
                                              const float* __restrict__ b4,
                                              const float* __restrict__ w5,
                                              const float* __restrict__ b5,
                                              float* __restrict__ out) {
  __shared__ float xb[1024], hb[1024];
  const int b = blockIdx.x, tid = threadIdx.x;
  for (int i = tid; i < 1024; i += 256) xb[i] = gmax[b * 1024 + i];
  __syncthreads();
  {
    float acc[4];
#pragma unroll
    for (int j = 0; j < 4; ++j) acc[j] = b4[tid + 256 * j];
    for (int i = 0; i < 1024; ++i) {
      float xv = xb[i];
      const float* wrow = w4 + (size_t)i * 1024;
#pragma unroll
      for (int j = 0; j < 4; ++j) acc[j] = fmaf(xv, wrow[tid + 256 * j], acc[j]);
    }
#pragma unroll
    for (int j = 0; j < 4; ++j) hb[tid + 256 * j] = fmaxf(acc[j], 0.f);
  }
  __syncthreads();
  {
    float acc[2];
#pragma unroll
    for (int j = 0; j < 2; ++j) acc[j] = b5[tid + 256 * j];
    for (int i = 0; i < 1024; ++i) {
      float xv = hb[i];
      const float* wrow = w5 + (size_t)i * 512;
#pragma unroll
      for (int j = 0; j < 2; ++j) acc[j] = fmaf(xv, wrow[tid + 256 * j], acc[j]);
    }
#pragma unroll
    for (int j = 0; j < 2; ++j) out[(size_t)b * 512 + tid + 256 * j] = acc[j];
  }
}

// ----------------------------------------------------------------
extern "C" void kernel_launch(void* const* d_in, const int* in_sizes, int n_in,
                              void* d_out, int out_size, void* d_ws, size_t ws_size,
                              hipStream_t stream) {
  (void)in_sizes; (void)n_in; (void)out_size; (void)ws_size;
  const float* x = (const float*)d_in[0];
  const float* w1 = (const float*)d_in[1];  const float* b1 = (const float*)d_in[2];
  const float* w2 = (const float*)d_in[3];  const float* b2 = (const float*)d_in[4];
  const float* w3 = (const float*)d_in[5];  const float* b3 = (const float*)d_in[6];
  const float* g1lw = (const float*)d_in[7];  const float* g1lb = (const float*)d_in[8];
  const float* g1cw = (const float*)d_in[9];  const float* g1cb = (const float*)d_in[10];
  const float* g2lw = (const float*)d_in[11]; const float* g2lb = (const float*)d_in[12];
  const float* g2cw = (const float*)d_in[13]; const float* g2cb = (const float*)d_in[14];
  const float* w4 = (const float*)d_in[15]; const float* b4 = (const float*)d_in[16];
  const float* w5 = (const float*)d_in[17]; const float* b5 = (const float*)d_in[18];
  const float* bn1g = (const float*)d_in[19]; const float* bn1b = (const float*)d_in[20];
  const float* bn1m = (const float*)d_in[21]; const float* bn1v = (const float*)d_in[22];
  const float* bn2g = (const float*)d_in[23]; const float* bn2b = (const float*)d_in[24];
  const float* bn2m = (const float*)d_in[25]; const float* bn2v = (const float*)d_in[26];
  const float* bn3g = (const float*)d_in[27]; const float* bn3b = (const float*)d_in[28];
  const float* bn3m = (const float*)d_in[29]; const float* bn3v = (const float*)d_in[30];

  float* ws = (float*)d_ws;
  size_t off = 0;
  auto alloc = [&](size_t n) { float* p = ws + off; off += (n + 63) & ~(size_t)63; return p; };
  float* slotA = alloc(16u * 2048 * 128);   // h0 (k1-k2) then h4 (k7-k10)
  float* slotB = alloc(16u * 2048 * 64);    // h3
  float* slotC = alloc(16u * 128 * 2048);   // h3T then h4T
  float* slotD = alloc(16u * 2048 * 128);   // m1 then m2
  float* sqb  = alloc(16u * 2048);          // sq3 then sq4
  float* Wc   = alloc(128u * 1024);         // combined weights (g1 then g2)
  float* bc   = alloc(1024);                // combined bias
  float* P    = alloc(512u * 1024);         // per-tile col maxes
  float* gm   = alloc(16u * 1024);          // global max

  // 1: knn on xyz + covariance -> h0[B,N,12]
  k_knn1_cov<<<dim3(32, 16), 256, 0, stream>>>(x, slotA);
  // 2: MLP1 -> h3[B,N,64]
  k_mlp1<<<512, 256, 0, stream>>>(slotA, w1, b1, w2, b2, w3, b3,
                                  bn1g, bn1b, bn1m, bn1v,
                                  bn2g, bn2b, bn2m, bn2v,
                                  bn3g, bn3b, bn3m, bn3v, slotB);
  // 3-5: knn(64) + gather-max -> m1
  k_sqnorm<64><<<128, 256, 0, stream>>>(slotB, sqb);
  k_transpose<64><<<dim3(32, 1, 16), 256, 0, stream>>>(slotB, slotC);
  k_knn_max<64><<<dim3(256, 16), 256, 0, stream>>>(slotB, slotC, sqb, slotD);
  // 6-7: g1 combined dense 64->128 + relu -> h4
  k_combine<<<32, 256, 0, stream>>>(g1lw, g1lb, g1cw, g1cb, Wc, bc, 64, 128);
  k_apply<64, true, false><<<dim3(512, 2), 256, 0, stream>>>(slotD, Wc, bc, slotA, 128);
  // 8-10: knn(128) + gather-max -> m2
  k_sqnorm<128><<<128, 256, 0, stream>>>(slotA, sqb);
  k_transpose<128><<<dim3(32, 2, 16), 256, 0, stream>>>(slotA, slotC);
  k_knn_max<128><<<dim3(256, 16), 256, 0, stream>>>(slotA, slotC, sqb, slotD);
  // 11-12: g2 combined dense 128->1024 fused with per-tile col-max -> P
  k_combine<<<512, 256, 0, stream>>>(g2lw, g2lb, g2cw, g2cb, Wc, bc, 128, 1024);
  k_apply<128, false, true><<<dim3(512, 16), 256, 0, stream>>>(slotD, Wc, bc, P, 1024);
  // 13: reduce -> gmax[16][1024]
  k_reduce_max<<<16, 256, 0, stream>>>(P, gm);
  // 14: head -> out[16][512]
  k_head<<<16, 256, 0, stream>>>(gm, w4, b4, w5, b5, (float*)d_out);
}

// Round 2
// 1964.221 us; speedup vs baseline: 1.3614x; 1.3614x over previous
//
#include <hip/hip_runtime.h>
#include <cstddef>

#define NPTS 2048

// ---------------------------------------------------------------- knn1 + cov
__global__ __launch_bounds__(256) void k_knn1_cov(const float* __restrict__ x,
                                                  float* __restrict__ h0) {
  const int b = blockIdx.y;
  const int tid = threadIdx.x;
  const int lane = tid & 63;
  const int w = tid >> 6;
  __shared__ float xs[NPTS * 3];
  __shared__ float sqs[NPTS];
  const float* xb = x + (size_t)b * NPTS * 3;
  for (int i = tid; i < NPTS * 3; i += 256) xs[i] = xb[i];
  __syncthreads();
  for (int n = tid; n < NPTS; n += 256) {
    float a0 = xs[3 * n], a1 = xs[3 * n + 1], a2 = xs[3 * n + 2];
    sqs[n] = fmaf(a0, a0, fmaf(a1, a1, a2 * a2));
  }
  __syncthreads();
  for (int qi = 0; qi < 16; ++qi) {
    const int nq = blockIdx.x * 64 + w * 16 + qi;
    const float qx = xs[3 * nq], qy = xs[3 * nq + 1], qz = xs[3 * nq + 2];
    const float sqq = sqs[nq];
    float d[32];
#pragma unroll
    for (int j = 0; j < 32; ++j) {
      int m = j * 64 + lane;
      float mx = xs[3 * m], my = xs[3 * m + 1], mz = xs[3 * m + 2];
      float dot = qx * mx;
      dot = fmaf(qy, my, dot);
      dot = fmaf(qz, mz, dot);
      d[j] = fmaf(-2.f, dot, sqq + sqs[m]);
    }
    unsigned mask = 0;
    int widx[16];
#pragma unroll
    for (int r = 0; r < 16; ++r) {
      float vmin = 3.4e38f;
      int mmin = 0x7fffffff;
#pragma unroll
      for (int j = 0; j < 32; ++j) {
        bool ok = !((mask >> j) & 1u) && (d[j] < vmin);
        if (ok) { vmin = d[j]; mmin = j * 64 + lane; }
      }
#pragma unroll
      for (int s = 1; s < 64; s <<= 1) {
        float ov = __shfl_xor(vmin, s, 64);
        int om = __shfl_xor(mmin, s, 64);
        if (ov < vmin || (ov == vmin && om < mmin)) { vmin = ov; mmin = om; }
      }
      widx[r] = mmin;
      if (lane == (mmin & 63)) mask |= 1u << (mmin >> 6);
    }
    float sx = 0, sy = 0, sz = 0;
#pragma unroll
    for (int r = 0; r < 16; ++r) {
      int m = widx[r];
      sx += xs[3 * m]; sy += xs[3 * m + 1]; sz += xs[3 * m + 2];
    }
    const float mx = sx * 0.0625f, my = sy * 0.0625f, mz = sz * 0.0625f;
    float cxx = 0, cxy = 0, cxz = 0, cyy = 0, cyz = 0, czz = 0;
#pragma unroll
    for (int r = 0; r < 16; ++r) {
      int m = widx[r];
      float ax = xs[3 * m] - mx, ay = xs[3 * m + 1] - my, az = xs[3 * m + 2] - mz;
      cxx = fmaf(ax, ax, cxx); cxy = fmaf(ax, ay, cxy); cxz = fmaf(ax, az, cxz);
      cyy = fmaf(ay, ay, cyy); cyz = fmaf(ay, az, cyz); czz = fmaf(az, az, czz);
    }
    if (lane == 0) {
      float* o = h0 + ((size_t)b * NPTS + nq) * 12;
      o[0] = qx; o[1] = qy; o[2] = qz;
      o[3] = cxx; o[4] = cxy; o[5] = cxz;
      o[6] = cxy; o[7] = cyy; o[8] = cyz;
      o[9] = cxz; o[10] = cyz; o[11] = czz;
    }
  }
}

// ---------------------------------------------------------------- MLP1 (12->12->64->64, BN folded)
__global__ __launch_bounds__(256) void k_mlp1(
    const float* __restrict__ h0,
    const float* __restrict__ w1, const float* __restrict__ cb1,
    const float* __restrict__ w2, const float* __restrict__ cb2,
    const float* __restrict__ w3, const float* __restrict__ cb3,
    const float* __restrict__ bn1g, const float* __restrict__ bn1b,
    const float* __restrict__ bn1m, const float* __restrict__ bn1v,
    const float* __restrict__ bn2g, const float* __restrict__ bn2b,
    const float* __restrict__ bn2m, const float* __restrict__ bn2v,
    const float* __restrict__ bn3g, const float* __restrict__ bn3b,
    const float* __restrict__ bn3m, const float* __restrict__ bn3v,
    float* __restrict__ h3out) {
  __shared__ float W1[144], W2[768], W3[4096];
  __shared__ float S1[12], F1[12], S2[64], F2[64], S3[64], F3[64];
  __shared__ float h0s[64][12];
  __shared__ float A2[64][65];
  const int tid = threadIdx.x;
  for (int i = tid; i < 144; i += 256) W1[i] = w1[i];
  for (int i = tid; i < 768; i += 256) W2[i] = w2[i];
  for (int i = tid; i < 4096; i += 256) W3[i] = w3[i];
  if (tid < 12) {
    float s = bn1g[tid] * rsqrtf(bn1v[tid] + 1e-3f);
    S1[tid] = s; F1[tid] = (cb1[tid] - bn1m[tid]) * s + bn1b[tid];
  }
  if (tid < 64) {
    float s2 = bn2g[tid] * rsqrtf(bn2v[tid] + 1e-3f);
    S2[tid] = s2; F2[tid] = (cb2[tid] - bn2m[tid]) * s2 + bn2b[tid];
    float s3 = bn3g[tid] * rsqrtf(bn3v[tid] + 1e-3f);
    S3[tid] = s3; F3[tid] = (cb3[tid] - bn3m[tid]) * s3 + bn3b[tid];
  }
  const int p0 = blockIdx.x * 64;
  for (int i = tid; i < 64 * 12; i += 256)
    h0s[i / 12][i % 12] = h0[(size_t)p0 * 12 + i];
  __syncthreads();
  const int pl = tid >> 2;
  const int q = tid & 3;
  float v1[12];
#pragma unroll
  for (int o = 0; o < 12; ++o) {
    float a = 0.f;
#pragma unroll
    for (int i = 0; i < 12; ++i) a = fmaf(h0s[pl][i], W1[i * 12 + o], a);
    v1[o] = fmaxf(fmaf(a, S1[o], F1[o]), 0.f);
  }
#pragma unroll
  for (int o = 0; o < 16; ++o) {
    int oo = q * 16 + o;
    float a = 0.f;
#pragma unroll
    for (int i = 0; i < 12; ++i) a = fmaf(v1[i], W2[i * 64 + oo], a);
    A2[pl][oo] = fmaxf(fmaf(a, S2[oo], F2[oo]), 0.f);
  }
  __syncthreads();
  float acc[16];
#pragma unroll
  for (int o = 0; o < 16; ++o) acc[o] = 0.f;
  for (int i = 0; i < 64; ++i) {
    float xv = A2[pl][i];
#pragma unroll
    for (int o = 0; o < 16; ++o) acc[o] = fmaf(xv, W3[i * 64 + q * 16 + o], acc[o]);
  }
  float* orow = h3out + (size_t)(p0 + pl) * 64 + q * 16;
#pragma unroll
  for (int o4 = 0; o4 < 4; ++o4) {
    float4 v;
    int oo = q * 16 + 4 * o4;
    v.x = fmaxf(fmaf(acc[4 * o4 + 0], S3[oo + 0], F3[oo + 0]), 0.f);
    v.y = fmaxf(fmaf(acc[4 * o4 + 1], S3[oo + 1], F3[oo + 1]), 0.f);
    v.z = fmaxf(fmaf(acc[4 * o4 + 2], S3[oo + 2], F3[oo + 2]), 0.f);
    v.w = fmaxf(fmaf(acc[4 * o4 + 3], S3[oo + 3], F3[oo + 3]), 0.f);
    *(float4*)&orow[4 * o4] = v;
  }
}

// ---------------------------------------------------------------- sq norms
template <int C>
__global__ __launch_bounds__(256) void k_sqnorm(const float* __restrict__ h,
                                                float* __restrict__ sq) {
  const int p = blockIdx.x * 256 + threadIdx.x;
  const float* row = h + (size_t)p * C;
  float a = 0.f;
#pragma unroll
  for (int i = 0; i < C; ++i) a = fmaf(row[i], row[i], a);
  sq[p] = a;
}

// ---------------------------------------------------------------- transpose [B,N,C] -> [B,C,N]
template <int C>
__global__ __launch_bounds__(256) void k_transpose(const float* __restrict__ h,
                                                   float* __restrict__ hT) {
  __shared__ float t[64][65];
  const int b = blockIdx.z, n0 = blockIdx.x * 64, c0 = blockIdx.y * 64;
  const int tx = threadIdx.x & 63, ty = threadIdx.x >> 6;
  const size_t base = (size_t)b * NPTS * C;
#pragma unroll
  for (int k = 0; k < 16; ++k) {
    int row = 4 * k + ty;
    t[row][tx] = h[base + (size_t)(n0 + row) * C + c0 + tx];
  }
  __syncthreads();
#pragma unroll
  for (int k = 0; k < 16; ++k) {
    int row = 4 * k + ty;
    hT[base + (size_t)(c0 + row) * NPTS + n0 + tx] = t[tx][row];
  }
}

// ---------------------------------------------------------------- knn + gather-max v2
// block: 256 thr / 4 waves; 16 queries per block (4 per wave)
// LDS: double-buffered tile[32 c][256 m] (32KB each); q reads via uniform
// (scalar) loads; d[4][32] in registers; selection fused with gather.
template <int C>
__global__ __launch_bounds__(256) void k_knn_max2(const float* __restrict__ h,
                                                  const float* __restrict__ hT,
                                                  const float* __restrict__ sq,
                                                  float* __restrict__ outm) {
  constexpr int NCC = C / 32;
  __shared__ float tile[2][32 * 256];
  const int tid = threadIdx.x;
  const int lane = tid & 63;
  const int w = tid >> 6;
  const int b = blockIdx.y;
  const int nq0 = blockIdx.x * 16;
  const size_t hb = (size_t)b * NPTS * C;
  const float* __restrict__ hbp = h + hb;
  const float* __restrict__ hTb = hT + hb;
  const float* __restrict__ sqb = sq + (size_t)b * NPTS;

  // wave-uniform query base (force scalar path)
  const int wq = __builtin_amdgcn_readfirstlane(w);
  const float* qru = hbp + (size_t)(nq0 + wq * 4) * C;
  float qsq[4];
#pragma unroll
  for (int i = 0; i < 4; ++i) qsq[i] = sqb[nq0 + wq * 4 + i];

  float d[4][32];
#pragma unroll
  for (int i = 0; i < 4; ++i)
#pragma unroll
    for (int j = 0; j < 32; ++j) d[i][j] = 0.f;

  float4 sreg[8];
  const int sm = 4 * lane;       // 256 floats of a c-row per wave
  const int sw = w;              // wave stages rows {sw, sw+4, ...}

  auto ldreg = [&](int mt, int cc) {
#pragma unroll
    for (int j = 0; j < 8; ++j)
      sreg[j] = *(const float4*)&hTb[(size_t)(cc * 32 + 4 * j + sw) * NPTS + mt * 256 + sm];
  };
  auto stlds = [&](int bf) {
#pragma unroll
    for (int j = 0; j < 8; ++j)
      *(float4*)&tile[bf][(4 * j + sw) * 256 + sm] = sreg[j];
  };

  ldreg(0, 0);
  stlds(0);
  __syncthreads();
  int buf = 0;

#pragma unroll
  for (int mt = 0; mt < 8; ++mt) {
    for (int cc = 0; cc < NCC; ++cc) {
      const bool last = (mt == 7) && (cc == NCC - 1);
      if (!last) {
        const int ncc = (cc == NCC - 1) ? 0 : cc + 1;
        const int nmt = (cc == NCC - 1) ? mt + 1 : mt;
        ldreg(nmt, ncc);
      }
      const float* tb = &tile[buf][0];
#pragma unroll 1
      for (int c4 = 0; c4 < 8; ++c4) {
        float4 qv[4];
#pragma unroll
        for (int i = 0; i < 4; ++i)
          qv[i] = *(const float4*)(qru + i * C + cc * 32 + c4 * 4);
#pragma unroll
        for (int u = 0; u < 4; ++u) {
          float4 tv = *(const float4*)&tb[(c4 * 4 + u) * 256 + 4 * lane];
#pragma unroll
          for (int i = 0; i < 4; ++i) {
            float qc = (&qv[i].x)[u];
            d[i][mt * 4 + 0] = fmaf(qc, tv.x, d[i][mt * 4 + 0]);
            d[i][mt * 4 + 1] = fmaf(qc, tv.y, d[i][mt * 4 + 1]);
            d[i][mt * 4 + 2] = fmaf(qc, tv.z, d[i][mt * 4 + 2]);
            d[i][mt * 4 + 3] = fmaf(qc, tv.w, d[i][mt * 4 + 3]);
          }
        }
      }
      if (!last) stlds(buf ^ 1);
      __syncthreads();
      buf ^= 1;
    }
    // finalize this mt: d = -2*dot + qsq + sq[m]
    float4 sv = *(const float4*)&sqb[mt * 256 + 4 * lane];
#pragma unroll
    for (int i = 0; i < 4; ++i) {
      d[i][mt * 4 + 0] = fmaf(-2.f, d[i][mt * 4 + 0], qsq[i] + sv.x);
      d[i][mt * 4 + 1] = fmaf(-2.f, d[i][mt * 4 + 1], qsq[i] + sv.y);
      d[i][mt * 4 + 2] = fmaf(-2.f, d[i][mt * 4 + 2], qsq[i] + sv.z);
      d[i][mt * 4 + 3] = fmaf(-2.f, d[i][mt * 4 + 3], qsq[i] + sv.w);
    }
  }

  // selection (exact, lowest-index tie-break) fused with gather-max
#pragma unroll
  for (int i = 0; i < 4; ++i) {
    unsigned mask = 0u;
    float g0 = -3.4e38f, g1 = -3.4e38f;
#pragma unroll 1
    for (int r = 0; r < 16; ++r) {
      float vmin = 3.4e38f;
      int mmin = 0x7fffffff;
#pragma unroll
      for (int j = 0; j < 32; ++j) {
        const int m = (j >> 2) * 256 + 4 * lane + (j & 3);
        bool ok = !((mask >> j) & 1u) && (d[i][j] < vmin);
        if (ok) { vmin = d[i][j]; mmin = m; }
      }
#pragma unroll
      for (int s = 1; s < 64; s <<= 1) {
        float ov = __shfl_xor(vmin, s, 64);
        int om = __shfl_xor(mmin, s, 64);
        if (ov < vmin || (ov == vmin && om < mmin)) { vmin = ov; mmin = om; }
      }
      if (lane == ((mmin >> 2) & 63)) mask |= 1u << (((mmin >> 8) << 2) | (mmin & 3));
      const float* row = hbp + (size_t)mmin * C;
      g0 = fmaxf(g0, row[lane]);
      if (C == 128) g1 = fmaxf(g1, row[64 + lane]);
    }
    float* orow = outm + hb + (size_t)(nq0 + wq * 4 + i) * C;
    orow[lane] = g0;
    if (C == 128) orow[64 + lane] = g1;
  }
}

// ---------------------------------------------------------------- combine two denses: Wc = lw*cw, bc = lb*cw + cb
__global__ __launch_bounds__(256) void k_combine(const float* __restrict__ lw,
                                                 const float* __restrict__ lb,
                                                 const float* __restrict__ cw,
                                                 const float* __restrict__ cb,
                                                 float* __restrict__ Wc,
                                                 float* __restrict__ bc, int K, int M) {
  const int id = blockIdx.x * 256 + threadIdx.x;
  if (id < K * M) {
    int i = id / M, o = id % M;
    float a = 0.f;
    for (int k = 0; k < K; ++k) a = fmaf(lw[i * K + k], cw[k * M + o], a);
    Wc[id] = a;
  }
  if (id < M) {
    float a = cb[id];
    for (int k = 0; k < K; ++k) a = fmaf(lb[k], cw[k * M + id], a);
    bc[id] = a;
  }
}

// ---------------------------------------------------------------- GEMM apply: out = A[32768,K] * W[K,M] (+bias) [relu | colmax]
template <int K, bool RELU, bool COLMAX>
__global__ __launch_bounds__(256) void k_apply(const float* __restrict__ A,
                                               const float* __restrict__ W,
                                               const float* __restrict__ bias,
                                               float* __restrict__ out, int M) {
  __shared__ float As[64][K + 4];
  __shared__ float Bs[K][64];
  __shared__ float cm[16][64];
  const int tid = threadIdx.x;
  const int tx = tid & 15, ty = tid >> 4;
  const int rt = blockIdx.x;
  const int col0 = blockIdx.y * 64;
  const int r0 = rt * 64;
  for (int i = tid; i < 64 * K; i += 256) {
    int r = i / K, c = i % K;
    As[r][c] = A[(size_t)(r0 + r) * K + c];
  }
  for (int i = tid; i < K * 64; i += 256) {
    int k = i >> 6, j = i & 63;
    Bs[k][j] = W[(size_t)k * M + col0 + j];
  }
  __syncthreads();
  float acc[4][4];
#pragma unroll
  for (int i = 0; i < 4; ++i)
#pragma unroll
    for (int j = 0; j < 4; ++j) acc[i][j] = 0.f;
  for (int k = 0; k < K; k += 4) {
    float4 av4[4], bv4[4];
#pragma unroll
    for (int i = 0; i < 4; ++i) av4[i] = *(const float4*)&As[4 * ty + i][k];
#pragma unroll
    for (int kk = 0; kk < 4; ++kk) bv4[kk] = *(const float4*)&Bs[k + kk][4 * tx];
    float a_[4][4], b_[4][4];
#pragma unroll
    for (int i = 0; i < 4; ++i) {
      a_[i][0] = av4[i].x; a_[i][1] = av4[i].y; a_[i][2] = av4[i].z; a_[i][3] = av4[i].w;
      b_[i][0] = bv4[i].x; b_[i][1] = bv4[i].y; b_[i][2] = bv4[i].z; b_[i][3] = bv4[i].w;
    }
#pragma unroll
    for (int kk = 0; kk < 4; ++kk)
#pragma unroll
      for (int i = 0; i < 4; ++i)
#pragma unroll
        for (int j = 0; j < 4; ++j)
          acc[i][j] = fmaf(a_[i][kk], b_[kk][j], acc[i][j]);
  }
  if (RELU) {
#pragma unroll
    for (int i = 0; i < 4; ++i) {
      int r = r0 + 4 * ty + i;
      float4 v;
      v.x = fmaxf(acc[i][0] + bias[col0 + 4 * tx + 0], 0.f);
      v.y = fmaxf(acc[i][1] + bias[col0 + 4 * tx + 1], 0.f);
      v.z = fmaxf(acc[i][2] + bias[col0 + 4 * tx + 2], 0.f);
      v.w = fmaxf(acc[i][3] + bias[col0 + 4 * tx + 3], 0.f);
      *(float4*)&out[(size_t)r * M + col0 + 4 * tx] = v;
    }
  }
  if (COLMAX) {
#pragma unroll
    for (int j = 0; j < 4; ++j) {
      float mj = fmaxf(fmaxf(acc[0][j], acc[1][j]), fmaxf(acc[2][j], acc[3][j]));
      cm[ty][4 * tx + j] = mj;
    }
    __syncthreads();
    if (tid < 64) {
      float mj = cm[0][tid];
#pragma unroll
      for (int r = 1; r < 16; ++r) mj = fmaxf(mj, cm[r][tid]);
      out[(size_t)rt * M + col0 + tid] = mj + bias[col0 + tid];
    }
  }
}

// ---------------------------------------------------------------- reduce P[512][1024] -> gmax[16][1024]
__global__ __launch_bounds__(256) void k_reduce_max(const float* __restrict__ P,
                                                    float* __restrict__ gmax) {
  const int b = blockIdx.x, tid = threadIdx.x;
  for (int c = tid; c < 1024; c += 256) {
    float m = P[(size_t)(b * 32) * 1024 + c];
    for (int rt = 1; rt < 32; ++rt)
      m = fmaxf(m, P[(size_t)(b * 32 + rt) * 1024 + c]);
    gmax[b * 1024 + c] = m;
  }
}

// ---------------------------------------------------------------- head: relu(gmax*W4+b4)*W5+b5
__global__ __launch_bounds__(256) void k_head(const float* __restrict__ gmax,
                                              const float* __restrict__ w4,
                                              const float* __restrict__ b4,
                                              const float* __restrict__ w5,
                                              const float* __restrict__ b5,
                                              float* __restrict__ out) {
  __shared__ float xb[1024], hbuf[1024];
  const int b = blockIdx.x, tid = threadIdx.x;
  for (int i = tid; i < 1024; i += 256) xb[i] = gmax[b * 1024 + i];
  __syncthreads();
  {
    float acc[4];
#pragma unroll
    for (int j = 0; j < 4; ++j) acc[j] = b4[tid + 256 * j];
    for (int i = 0; i < 1024; ++i) {
      float xv = xb[i];
      const float* wrow = w4 + (size_t)i * 1024;
#pragma unroll
      for (int j = 0; j < 4; ++j) acc[j] = fmaf(xv, wrow[tid + 256 * j], acc[j]);
    }
#pragma unroll
    for (int j = 0; j < 4; ++j) hbuf[tid + 256 * j] = fmaxf(acc[j], 0.f);
  }
  __syncthreads();
  {
    float acc[2];
#pragma unroll
    for (int j = 0; j < 2; ++j) acc[j] = b5[tid + 256 * j];
    for (int i = 0; i < 1024; ++i) {
      float xv = hbuf[i];
      const float* wrow = w5 + (size_t)i * 512;
#pragma unroll
      for (int j = 0; j < 2; ++j) acc[j] = fmaf(xv, wrow[tid + 256 * j], acc[j]);
    }
#pragma unroll
    for (int j = 0; j < 2; ++j) out[(size_t)b * 512 + tid + 256 * j] = acc[j];
  }
}

// ----------------------------------------------------------------
extern "C" void kernel_launch(void* const* d_in, const int* in_sizes, int n_in,
                              void* d_out, int out_size, void* d_ws, size_t ws_size,
                              hipStream_t stream) {
  (void)in_sizes; (void)n_in; (void)out_size; (void)ws_size;
  const float* x = (const float*)d_in[0];
  const float* w1 = (const float*)d_in[1];  const float* b1 = (const float*)d_in[2];
  const float* w2 = (const float*)d_in[3];  const float* b2 = (const float*)d_in[4];
  const float* w3 = (const float*)d_in[5];  const float* b3 = (const float*)d_in[6];
  const float* g1lw = (const float*)d_in[7];  const float* g1lb = (const float*)d_in[8];
  const float* g1cw = (const float*)d_in[9];  const float* g1cb = (const float*)d_in[10];
  const float* g2lw = (const float*)d_in[11]; const float* g2lb = (const float*)d_in[12];
  const float* g2cw = (const float*)d_in[13]; const float* g2cb = (const float*)d_in[14];
  const float* w4 = (const float*)d_in[15]; const float* b4 = (const float*)d_in[16];
  const float* w5 = (const float*)d_in[17]; const float* b5 = (const float*)d_in[18];
  const float* bn1g = (const float*)d_in[19]; const float* bn1b = (const float*)d_in[20];
  const float* bn1m = (const float*)d_in[21]; const float* bn1v = (const float*)d_in[22];
  const float* bn2g = (const float*)d_in[23]; const float* bn2b = (const float*)d_in[24];
  const float* bn2m = (const float*)d_in[25]; const float* bn2v = (const float*)d_in[26];
  const float* bn3g = (const float*)d_in[27]; const float* bn3b = (const float*)d_in[28];
  const float* bn3m = (const float*)d_in[29]; const float* bn3v = (const float*)d_in[30];

  float* ws = (float*)d_ws;
  size_t off = 0;
  auto alloc = [&](size_t n) { float* p = ws + off; off += (n + 63) & ~(size_t)63; return p; };
  float* slotA = alloc(16u * 2048 * 128);   // h0 (k1-k2) then h4 (k7-k10)
  float* slotB = alloc(16u * 2048 * 64);    // h3
  float* slotC = alloc(16u * 128 * 2048);   // h3T then h4T
  float* slotD = alloc(16u * 2048 * 128);   // m1 then m2
  float* sqb  = alloc(16u * 2048);          // sq3 then sq4
  float* Wc   = alloc(128u * 1024);         // combined weights (g1 then g2)
  float* bc   = alloc(1024);                // combined bias
  float* P    = alloc(512u * 1024);         // per-tile col maxes
  float* gm   = alloc(16u * 1024);          // global max

  // 1: knn on xyz + covariance -> h0[B,N,12]
  k_knn1_cov<<<dim3(32, 16), 256, 0, stream>>>(x, slotA);
  // 2: MLP1 -> h3[B,N,64]
  k_mlp1<<<512, 256, 0, stream>>>(slotA, w1, b1, w2, b2, w3, b3,
                                  bn1g, bn1b, bn1m, bn1v,
                                  bn2g, bn2b, bn2m, bn2v,
                                  bn3g, bn3b, bn3m, bn3v, slotB);
  // 3-5: knn(64) + gather-max -> m1
  k_sqnorm<64><<<128, 256, 0, stream>>>(slotB, sqb);
  k_transpose<64><<<dim3(32, 1, 16), 256, 0, stream>>>(slotB, slotC);
  k_knn_max2<64><<<dim3(128, 16), 256, 0, stream>>>(slotB, slotC, sqb, slotD);
  // 6-7: g1 combined dense 64->128 + relu -> h4
  k_combine<<<32, 256, 0, stream>>>(g1lw, g1lb, g1cw, g1cb, Wc, bc, 64, 128);
  k_apply<64, true, false><<<dim3(512, 2), 256, 0, stream>>>(slotD, Wc, bc, slotA, 128);
  // 8-10: knn(128) + gather-max -> m2
  k_sqnorm<128><<<128, 256, 0, stream>>>(slotA, sqb);
  k_transpose<128><<<dim3(32, 2, 16), 256, 0, stream>>>(slotA, slotC);
  k_knn_max2<128><<<dim3(128, 16), 256, 0, stream>>>(slotA, slotC, sqb, slotD);
  // 11-12: g2 combined dense 128->1024 fused with per-tile col-max -> P
  k_combine<<<512, 256, 0, stream>>>(g2lw, g2lb, g2cw, g2cb, Wc, bc, 128, 1024);
  k_apply<128, false, true><<<dim3(512, 16), 256, 0, stream>>>(slotD, Wc, bc, P, 1024);
  // 13: reduce -> gmax[16][1024]
  k_reduce_max<<<16, 256, 0, stream>>>(P, gm);
  // 14: head -> out[16][512]
  k_head<<<16, 256, 0, stream>>>(gm, w4, b4, w5, b5, (float*)d_out);
}

// Round 3
// 1650.268 us; speedup vs baseline: 1.6204x; 1.1902x over previous
//
#include <hip/hip_runtime.h>
#include <cstddef>
#include <cstdint>

#define NPTS 2048

// async global->LDS 16B per lane (wave-uniform LDS base + lane*16)
__device__ __forceinline__ void gll16(const void* g, void* l) {
  typedef __attribute__((address_space(3))) void lds_void;
  typedef const __attribute__((address_space(1))) void glb_void;
  __builtin_amdgcn_global_load_lds((glb_void*)g, (lds_void*)l, 16, 0, 0);
}

// ---------------------------------------------------------------- knn1 + cov
__global__ __launch_bounds__(256) void k_knn1_cov(const float* __restrict__ x,
                                                  float* __restrict__ h0) {
  const int b = blockIdx.y;
  const int tid = threadIdx.x;
  const int lane = tid & 63;
  const int w = tid >> 6;
  __shared__ float xs[NPTS * 3];
  __shared__ float sqs[NPTS];
  const float* xb = x + (size_t)b * NPTS * 3;
  for (int i = tid; i < NPTS * 3; i += 256) xs[i] = xb[i];
  __syncthreads();
  for (int n = tid; n < NPTS; n += 256) {
    float a0 = xs[3 * n], a1 = xs[3 * n + 1], a2 = xs[3 * n + 2];
    sqs[n] = fmaf(a0, a0, fmaf(a1, a1, a2 * a2));
  }
  __syncthreads();
  for (int qi = 0; qi < 16; ++qi) {
    const int nq = blockIdx.x * 64 + w * 16 + qi;
    const float qx = xs[3 * nq], qy = xs[3 * nq + 1], qz = xs[3 * nq + 2];
    const float sqq = sqs[nq];
    float d[32];
#pragma unroll
    for (int j = 0; j < 32; ++j) {
      int m = j * 64 + lane;
      float mx = xs[3 * m], my = xs[3 * m + 1], mz = xs[3 * m + 2];
      float dot = qx * mx;
      dot = fmaf(qy, my, dot);
      dot = fmaf(qz, mz, dot);
      d[j] = fmaf(-2.f, dot, sqq + sqs[m]);
    }
    unsigned mask = 0;
    int widx[16];
#pragma unroll
    for (int r = 0; r < 16; ++r) {
      float vmin = 3.4e38f;
      int mmin = 0x7fffffff;
#pragma unroll
      for (int j = 0; j < 32; ++j) {
        bool ok = !((mask >> j) & 1u) && (d[j] < vmin);
        if (ok) { vmin = d[j]; mmin = j * 64 + lane; }
      }
#pragma unroll
      for (int s = 1; s < 64; s <<= 1) {
        float ov = __shfl_xor(vmin, s, 64);
        int om = __shfl_xor(mmin, s, 64);
        if (ov < vmin || (ov == vmin && om < mmin)) { vmin = ov; mmin = om; }
      }
      widx[r] = mmin;
      if (lane == (mmin & 63)) mask |= 1u << (mmin >> 6);
    }
    float sx = 0, sy = 0, sz = 0;
#pragma unroll
    for (int r = 0; r < 16; ++r) {
      int m = widx[r];
      sx += xs[3 * m]; sy += xs[3 * m + 1]; sz += xs[3 * m + 2];
    }
    const float mx = sx * 0.0625f, my = sy * 0.0625f, mz = sz * 0.0625f;
    float cxx = 0, cxy = 0, cxz = 0, cyy = 0, cyz = 0, czz = 0;
#pragma unroll
    for (int r = 0; r < 16; ++r) {
      int m = widx[r];
      float ax = xs[3 * m] - mx, ay = xs[3 * m + 1] - my, az = xs[3 * m + 2] - mz;
      cxx = fmaf(ax, ax, cxx); cxy = fmaf(ax, ay, cxy); cxz = fmaf(ax, az, cxz);
      cyy = fmaf(ay, ay, cyy); cyz = fmaf(ay, az, cyz); czz = fmaf(az, az, czz);
    }
    if (lane == 0) {
      float* o = h0 + ((size_t)b * NPTS + nq) * 12;
      o[0] = qx; o[1] = qy; o[2] = qz;
      o[3] = cxx; o[4] = cxy; o[5] = cxz;
      o[6] = cxy; o[7] = cyy; o[8] = cyz;
      o[9] = cxz; o[10] = cyz; o[11] = czz;
    }
  }
}

// ---------------------------------------------------------------- MLP1 (12->12->64->64, BN folded)
__global__ __launch_bounds__(256) void k_mlp1(
    const float* __restrict__ h0,
    const float* __restrict__ w1, const float* __restrict__ cb1,
    const float* __restrict__ w2, const float* __restrict__ cb2,
    const float* __restrict__ w3, const float* __restrict__ cb3,
    const float* __restrict__ bn1g, const float* __restrict__ bn1b,
    const float* __restrict__ bn1m, const float* __restrict__ bn1v,
    const float* __restrict__ bn2g, const float* __restrict__ bn2b,
    const float* __restrict__ bn2m, const float* __restrict__ bn2v,
    const float* __restrict__ bn3g, const float* __restrict__ bn3b,
    const float* __restrict__ bn3m, const float* __restrict__ bn3v,
    float* __restrict__ h3out) {
  __shared__ float W1[144], W2[768], W3[4096];
  __shared__ float S1[12], F1[12], S2[64], F2[64], S3[64], F3[64];
  __shared__ float h0s[64][12];
  __shared__ float A2[64][65];
  const int tid = threadIdx.x;
  for (int i = tid; i < 144; i += 256) W1[i] = w1[i];
  for (int i = tid; i < 768; i += 256) W2[i] = w2[i];
  for (int i = tid; i < 4096; i += 256) W3[i] = w3[i];
  if (tid < 12) {
    float s = bn1g[tid] * rsqrtf(bn1v[tid] + 1e-3f);
    S1[tid] = s; F1[tid] = (cb1[tid] - bn1m[tid]) * s + bn1b[tid];
  }
  if (tid < 64) {
    float s2 = bn2g[tid] * rsqrtf(bn2v[tid] + 1e-3f);
    S2[tid] = s2; F2[tid] = (cb2[tid] - bn2m[tid]) * s2 + bn2b[tid];
    float s3 = bn3g[tid] * rsqrtf(bn3v[tid] + 1e-3f);
    S3[tid] = s3; F3[tid] = (cb3[tid] - bn3m[tid]) * s3 + bn3b[tid];
  }
  const int p0 = blockIdx.x * 64;
  for (int i = tid; i < 64 * 12; i += 256)
    h0s[i / 12][i % 12] = h0[(size_t)p0 * 12 + i];
  __syncthreads();
  const int pl = tid >> 2;
  const int q = tid & 3;
  float v1[12];
#pragma unroll
  for (int o = 0; o < 12; ++o) {
    float a = 0.f;
#pragma unroll
    for (int i = 0; i < 12; ++i) a = fmaf(h0s[pl][i], W1[i * 12 + o], a);
    v1[o] = fmaxf(fmaf(a, S1[o], F1[o]), 0.f);
  }
#pragma unroll
  for (int o = 0; o < 16; ++o) {
    int oo = q * 16 + o;
    float a = 0.f;
#pragma unroll
    for (int i = 0; i < 12; ++i) a = fmaf(v1[i], W2[i * 64 + oo], a);
    A2[pl][oo] = fmaxf(fmaf(a, S2[oo], F2[oo]), 0.f);
  }
  __syncthreads();
  float acc[16];
#pragma unroll
  for (int o = 0; o < 16; ++o) acc[o] = 0.f;
  for (int i = 0; i < 64; ++i) {
    float xv = A2[pl][i];
#pragma unroll
    for (int o = 0; o < 16; ++o) acc[o] = fmaf(xv, W3[i * 64 + q * 16 + o], acc[o]);
  }
  float* orow = h3out + (size_t)(p0 + pl) * 64 + q * 16;
#pragma unroll
  for (int o4 = 0; o4 < 4; ++o4) {
    float4 v;
    int oo = q * 16 + 4 * o4;
    v.x = fmaxf(fmaf(acc[4 * o4 + 0], S3[oo + 0], F3[oo + 0]), 0.f);
    v.y = fmaxf(fmaf(acc[4 * o4 + 1], S3[oo + 1], F3[oo + 1]), 0.f);
    v.z = fmaxf(fmaf(acc[4 * o4 + 2], S3[oo + 2], F3[oo + 2]), 0.f);
    v.w = fmaxf(fmaf(acc[4 * o4 + 3], S3[oo + 3], F3[oo + 3]), 0.f);
    *(float4*)&orow[4 * o4] = v;
  }
}

// ---------------------------------------------------------------- sq norms
template <int C>
__global__ __launch_bounds__(256) void k_sqnorm(const float* __restrict__ h,
                                                float* __restrict__ sq) {
  const int p = blockIdx.x * 256 + threadIdx.x;
  const float* row = h + (size_t)p * C;
  float a = 0.f;
#pragma unroll
  for (int i = 0; i < C; ++i) a = fmaf(row[i], row[i], a);
  sq[p] = a;
}

// ---------------------------------------------------------------- transpose [B,N,C] -> [B,C,N]
template <int C>
__global__ __launch_bounds__(256) void k_transpose(const float* __restrict__ h,
                                                   float* __restrict__ hT) {
  __shared__ float t[64][65];
  const int b = blockIdx.z, n0 = blockIdx.x * 64, c0 = blockIdx.y * 64;
  const int tx = threadIdx.x & 63, ty = threadIdx.x >> 6;
  const size_t base = (size_t)b * NPTS * C;
#pragma unroll
  for (int k = 0; k < 16; ++k) {
    int row = 4 * k + ty;
    t[row][tx] = h[base + (size_t)(n0 + row) * C + c0 + tx];
  }
  __syncthreads();
#pragma unroll
  for (int k = 0; k < 16; ++k) {
    int row = 4 * k + ty;
    hT[base + (size_t)(c0 + row) * NPTS + n0 + tx] = t[tx][row];
  }
}

// ---------------------------------------------------------------- knn + gather-max v3
// 256 thr / 4 waves; 16 queries per block (4 per wave); flat grid with XCD
// swizzle (2 batches per XCD). Staging via global_load_lds (no reg roundtrip),
// __launch_bounds__(256,2) -> 256 VGPR cap, d[4][32] stays in registers.
template <int C>
__global__ __launch_bounds__(256, 2) void k_knn_max3(const float* __restrict__ h,
                                                     const float* __restrict__ hT,
                                                     const float* __restrict__ sq,
                                                     float* __restrict__ outm) {
  constexpr int NCC = C / 32;
  __shared__ float tile[2][32 * 256];
  const int tid = threadIdx.x;
  const int lane = tid & 63;
  const int w = tid >> 6;
  // XCD swizzle: flat id f -> g = (f%8)*256 + f/8 ; batch = g/128, qtile = g%128
  const int f = blockIdx.x;
  const int g = ((f & 7) << 8) | (f >> 3);
  const int b = g >> 7;
  const int nq0 = (g & 127) * 16;
  const size_t hb = (size_t)b * NPTS * C;
  const float* __restrict__ hbp = h + hb;
  const float* __restrict__ hTb = hT + hb;
  const float* __restrict__ sqb = sq + (size_t)b * NPTS;

  // wave-uniform query base (force scalar path)
  const int wq = __builtin_amdgcn_readfirstlane(w);
  const float* qru = hbp + (size_t)(nq0 + wq * 4) * C;
  float qsq[4];
#pragma unroll
  for (int i = 0; i < 4; ++i) qsq[i] = sqb[nq0 + wq * 4 + i];

  float d[4][32];
#pragma unroll
  for (int i = 0; i < 4; ++i)
#pragma unroll
    for (int j = 0; j < 32; ++j) d[i][j] = 0.f;

  const int sw = w;  // wave stages rows {sw, sw+4, ...}

  auto stage = [&](int bf, int mt, int cc) {
#pragma unroll
    for (int j = 0; j < 8; ++j) {
      const float* gp = hTb + (size_t)(cc * 32 + 4 * j + sw) * NPTS + mt * 256 + 4 * lane;
      const int ldsrow = __builtin_amdgcn_readfirstlane((4 * j + sw) * 256);
      gll16(gp, &tile[bf][ldsrow]);
    }
  };

  stage(0, 0, 0);
  __syncthreads();
  int buf = 0;

#pragma unroll
  for (int mt = 0; mt < 8; ++mt) {
    for (int cc = 0; cc < NCC; ++cc) {
      const bool last = (mt == 7) && (cc == NCC - 1);
      if (!last) {
        const int ncc = (cc == NCC - 1) ? 0 : cc + 1;
        const int nmt = (cc == NCC - 1) ? mt + 1 : mt;
        stage(buf ^ 1, nmt, ncc);
      }
      const float* tb = &tile[buf][0];
#pragma unroll 1
      for (int c4 = 0; c4 < 8; ++c4) {
        float4 qv[4];
#pragma unroll
        for (int i = 0; i < 4; ++i)
          qv[i] = *(const float4*)(qru + i * C + cc * 32 + c4 * 4);
#pragma unroll
        for (int u = 0; u < 4; ++u) {
          float4 tv = *(const float4*)&tb[(c4 * 4 + u) * 256 + 4 * lane];
#pragma unroll
          for (int i = 0; i < 4; ++i) {
            float qc = (&qv[i].x)[u];
            d[i][mt * 4 + 0] = fmaf(qc, tv.x, d[i][mt * 4 + 0]);
            d[i][mt * 4 + 1] = fmaf(qc, tv.y, d[i][mt * 4 + 1]);
            d[i][mt * 4 + 2] = fmaf(qc, tv.z, d[i][mt * 4 + 2]);
            d[i][mt * 4 + 3] = fmaf(qc, tv.w, d[i][mt * 4 + 3]);
          }
        }
      }
      __syncthreads();  // drains vmcnt (staged loads) + protects tile swap
      buf ^= 1;
    }
    // finalize this mt: d = -2*dot + qsq + sq[m]
    float4 sv = *(const float4*)&sqb[mt * 256 + 4 * lane];
#pragma unroll
    for (int i = 0; i < 4; ++i) {
      d[i][mt * 4 + 0] = fmaf(-2.f, d[i][mt * 4 + 0], qsq[i] + sv.x);
      d[i][mt * 4 + 1] = fmaf(-2.f, d[i][mt * 4 + 1], qsq[i] + sv.y);
      d[i][mt * 4 + 2] = fmaf(-2.f, d[i][mt * 4 + 2], qsq[i] + sv.z);
      d[i][mt * 4 + 3] = fmaf(-2.f, d[i][mt * 4 + 3], qsq[i] + sv.w);
    }
  }

  // selection (exact, lowest-index tie-break) fused with gather-max
#pragma unroll
  for (int i = 0; i < 4; ++i) {
    unsigned mask = 0u;
    float g0 = -3.4e38f, g1 = -3.4e38f;
#pragma unroll 1
    for (int r = 0; r < 16; ++r) {
      float vmin = 3.4e38f;
      int mmin = 0x7fffffff;
#pragma unroll
      for (int j = 0; j < 32; ++j) {
        const int m = (j >> 2) * 256 + 4 * lane + (j & 3);
        bool ok = !((mask >> j) & 1u) && (d[i][j] < vmin);
        if (ok) { vmin = d[i][j]; mmin = m; }
      }
#pragma unroll
      for (int s = 1; s < 64; s <<= 1) {
        float ov = __shfl_xor(vmin, s, 64);
        int om = __shfl_xor(mmin, s, 64);
        if (ov < vmin || (ov == vmin && om < mmin)) { vmin = ov; mmin = om; }
      }
      if (lane == ((mmin >> 2) & 63)) mask |= 1u << (((mmin >> 8) << 2) | (mmin & 3));
      const float* row = hbp + (size_t)mmin * C;
      g0 = fmaxf(g0, row[lane]);
      if (C == 128) g1 = fmaxf(g1, row[64 + lane]);
    }
    float* orow = outm + hb + (size_t)(nq0 + wq * 4 + i) * C;
    orow[lane] = g0;
    if (C == 128) orow[64 + lane] = g1;
  }
}

// ---------------------------------------------------------------- combine two denses: Wc = lw*cw, bc = lb*cw + cb
__global__ __launch_bounds__(256) void k_combine(const float* __restrict__ lw,
                                                 const float* __restrict__ lb,
                                                 const float* __restrict__ cw,
                                                 const float* __restrict__ cb,
                                                 float* __restrict__ Wc,
                                                 float* __restrict__ bc, int K, int M) {
  const int id = blockIdx.x * 256 + threadIdx.x;
  if (id < K * M) {
    int i = id / M, o = id % M;
    float a = 0.f;
    for (int k = 0; k < K; ++k) a = fmaf(lw[i * K + k], cw[k * M + o], a);
    Wc[id] = a;
  }
  if (id < M) {
    float a = cb[id];
    for (int k = 0; k < K; ++k) a = fmaf(lb[k], cw[k * M + id], a);
    bc[id] = a;
  }
}

// ---------------------------------------------------------------- GEMM apply: out = A[32768,K] * W[K,M] (+bias) [relu | colmax]
template <int K, bool RELU, bool COLMAX>
__global__ __launch_bounds__(256) void k_apply(const float* __restrict__ A,
                                               const float* __restrict__ W,
                                               const float* __restrict__ bias,
                                               float* __restrict__ out, int M) {
  __shared__ float As[64][K + 4];
  __shared__ float Bs[K][64];
  __shared__ float cm[16][64];
  const int tid = threadIdx.x;
  const int tx = tid & 15, ty = tid >> 4;
  const int rt = blockIdx.x;
  const int col0 = blockIdx.y * 64;
  const int r0 = rt * 64;
  for (int i = tid; i < 64 * K; i += 256) {
    int r = i / K, c = i % K;
    As[r][c] = A[(size_t)(r0 + r) * K + c];
  }
  for (int i = tid; i < K * 64; i += 256) {
    int k = i >> 6, j = i & 63;
    Bs[k][j] = W[(size_t)k * M + col0 + j];
  }
  __syncthreads();
  float acc[4][4];
#pragma unroll
  for (int i = 0; i < 4; ++i)
#pragma unroll
    for (int j = 0; j < 4; ++j) acc[i][j] = 0.f;
  for (int k = 0; k < K; k += 4) {
    float4 av4[4], bv4[4];
#pragma unroll
    for (int i = 0; i < 4; ++i) av4[i] = *(const float4*)&As[4 * ty + i][k];
#pragma unroll
    for (int kk = 0; kk < 4; ++kk) bv4[kk] = *(const float4*)&Bs[k + kk][4 * tx];
    float a_[4][4], b_[4][4];
#pragma unroll
    for (int i = 0; i < 4; ++i) {
      a_[i][0] = av4[i].x; a_[i][1] = av4[i].y; a_[i][2] = av4[i].z; a_[i][3] = av4[i].w;
      b_[i][0] = bv4[i].x; b_[i][1] = bv4[i].y; b_[i][2] = bv4[i].z; b_[i][3] = bv4[i].w;
    }
#pragma unroll
    for (int kk = 0; kk < 4; ++kk)
#pragma unroll
      for (int i = 0; i < 4; ++i)
#pragma unroll
        for (int j = 0; j < 4; ++j)
          acc[i][j] = fmaf(a_[i][kk], b_[kk][j], acc[i][j]);
  }
  if (RELU) {
#pragma unroll
    for (int i = 0; i < 4; ++i) {
      int r = r0 + 4 * ty + i;
      float4 v;
      v.x = fmaxf(acc[i][0] + bias[col0 + 4 * tx + 0], 0.f);
      v.y = fmaxf(acc[i][1] + bias[col0 + 4 * tx + 1], 0.f);
      v.z = fmaxf(acc[i][2] + bias[col0 + 4 * tx + 2], 0.f);
      v.w = fmaxf(acc[i][3] + bias[col0 + 4 * tx + 3], 0.f);
      *(float4*)&out[(size_t)r * M + col0 + 4 * tx] = v;
    }
  }
  if (COLMAX) {
#pragma unroll
    for (int j = 0; j < 4; ++j) {
      float mj = fmaxf(fmaxf(acc[0][j], acc[1][j]), fmaxf(acc[2][j], acc[3][j]));
      cm[ty][4 * tx + j] = mj;
    }
    __syncthreads();
    if (tid < 64) {
      float mj = cm[0][tid];
#pragma unroll
      for (int r = 1; r < 16; ++r) mj = fmaxf(mj, cm[r][tid]);
      out[(size_t)rt * M + col0 + tid] = mj + bias[col0 + tid];
    }
  }
}

// ---------------------------------------------------------------- reduce P[512][1024] -> gmax[16][1024]
__global__ __launch_bounds__(256) void k_reduce_max(const float* __restrict__ P,
                                                    float* __restrict__ gmax) {
  const int b = blockIdx.x, tid = threadIdx.x;
  for (int c = tid; c < 1024; c += 256) {
    float m = P[(size_t)(b * 32) * 1024 + c];
    for (int rt = 1; rt < 32; ++rt)
      m = fmaxf(m, P[(size_t)(b * 32 + rt) * 1024 + c]);
    gmax[b * 1024 + c] = m;
  }
}

// ---------------------------------------------------------------- head: relu(gmax*W4+b4)*W5+b5
__global__ __launch_bounds__(256) void k_head(const float* __restrict__ gmax,
                                              const float* __restrict__ w4,
                                              const float* __restrict__ b4,
                                              const float* __restrict__ w5,
                                              const float* __restrict__ b5,
                                              float* __restrict__ out) {
  __shared__ float xb[1024], hbuf[1024];
  const int b = blockIdx.x, tid = threadIdx.x;
  for (int i = tid; i < 1024; i += 256) xb[i] = gmax[b * 1024 + i];
  __syncthreads();
  {
    float acc[4];
#pragma unroll
    for (int j = 0; j < 4; ++j) acc[j] = b4[tid + 256 * j];
    for (int i = 0; i < 1024; ++i) {
      float xv = xb[i];
      const float* wrow = w4 + (size_t)i * 1024;
#pragma unroll
      for (int j = 0; j < 4; ++j) acc[j] = fmaf(xv, wrow[tid + 256 * j], acc[j]);
    }
#pragma unroll
    for (int j = 0; j < 4; ++j) hbuf[tid + 256 * j] = fmaxf(acc[j], 0.f);
  }
  __syncthreads();
  {
    float acc[2];
#pragma unroll
    for (int j = 0; j < 2; ++j) acc[j] = b5[tid + 256 * j];
    for (int i = 0; i < 1024; ++i) {
      float xv = hbuf[i];
      const float* wrow = w5 + (size_t)i * 512;
#pragma unroll
      for (int j = 0; j < 2; ++j) acc[j] = fmaf(xv, wrow[tid + 256 * j], acc[j]);
    }
#pragma unroll
    for (int j = 0; j < 2; ++j) out[(size_t)b * 512 + tid + 256 * j] = acc[j];
  }
}

// ----------------------------------------------------------------
extern "C" void kernel_launch(void* const* d_in, const int* in_sizes, int n_in,
                              void* d_out, int out_size, void* d_ws, size_t ws_size,
                              hipStream_t stream) {
  (void)in_sizes; (void)n_in; (void)out_size; (void)ws_size;
  const float* x = (const float*)d_in[0];
  const float* w1 = (const float*)d_in[1];  const float* b1 = (const float*)d_in[2];
  const float* w2 = (const float*)d_in[3];  const float* b2 = (const float*)d_in[4];
  const float* w3 = (const float*)d_in[5];  const float* b3 = (const float*)d_in[6];
  const float* g1lw = (const float*)d_in[7];  const float* g1lb = (const float*)d_in[8];
  const float* g1cw = (const float*)d_in[9];  const float* g1cb = (const float*)d_in[10];
  const float* g2lw = (const float*)d_in[11]; const float* g2lb = (const float*)d_in[12];
  const float* g2cw = (const float*)d_in[13]; const float* g2cb = (const float*)d_in[14];
  const float* w4 = (const float*)d_in[15]; const float* b4 = (const float*)d_in[16];
  const float* w5 = (const float*)d_in[17]; const float* b5 = (const float*)d_in[18];
  const float* bn1g = (const float*)d_in[19]; const float* bn1b = (const float*)d_in[20];
  const float* bn1m = (const float*)d_in[21]; const float* bn1v = (const float*)d_in[22];
  const float* bn2g = (const float*)d_in[23]; const float* bn2b = (const float*)d_in[24];
  const float* bn2m = (const float*)d_in[25]; const float* bn2v = (const float*)d_in[26];
  const float* bn3g = (const float*)d_in[27]; const float* bn3b = (const float*)d_in[28];
  const float* bn3m = (const float*)d_in[29]; const float* bn3v = (const float*)d_in[30];

  float* ws = (float*)d_ws;
  size_t off = 0;
  auto alloc = [&](size_t n) { float* p = ws + off; off += (n + 63) & ~(size_t)63; return p; };
  float* slotA = alloc(16u * 2048 * 128);   // h0 (k1-k2) then h4 (k7-k10)
  float* slotB = alloc(16u * 2048 * 64);    // h3
  float* slotC = alloc(16u * 128 * 2048);   // h3T then h4T
  float* slotD = alloc(16u * 2048 * 128);   // m1 then m2
  float* sqb  = alloc(16u * 2048);          // sq3 then sq4
  float* Wc   = alloc(128u * 1024);         // combined weights (g1 then g2)
  float* bc   = alloc(1024);                // combined bias
  float* P    = alloc(512u * 1024);         // per-tile col maxes
  float* gm   = alloc(16u * 1024);          // global max

  // 1: knn on xyz + covariance -> h0[B,N,12]
  k_knn1_cov<<<dim3(32, 16), 256, 0, stream>>>(x, slotA);
  // 2: MLP1 -> h3[B,N,64]
  k_mlp1<<<512, 256, 0, stream>>>(slotA, w1, b1, w2, b2, w3, b3,
                                  bn1g, bn1b, bn1m, bn1v,
                                  bn2g, bn2b, bn2m, bn2v,
                                  bn3g, bn3b, bn3m, bn3v, slotB);
  // 3-5: knn(64) + gather-max -> m1
  k_sqnorm<64><<<128, 256, 0, stream>>>(slotB, sqb);
  k_transpose<64><<<dim3(32, 1, 16), 256, 0, stream>>>(slotB, slotC);
  k_knn_max3<64><<<2048, 256, 0, stream>>>(slotB, slotC, sqb, slotD);
  // 6-7: g1 combined dense 64->128 + relu -> h4
  k_combine<<<32, 256, 0, stream>>>(g1lw, g1lb, g1cw, g1cb, Wc, bc, 64, 128);
  k_apply<64, true, false><<<dim3(512, 2), 256, 0, stream>>>(slotD, Wc, bc, slotA, 128);
  // 8-10: knn(128) + gather-max -> m2
  k_sqnorm<128><<<128, 256, 0, stream>>>(slotA, sqb);
  k_transpose<128><<<dim3(32, 2, 16), 256, 0, stream>>>(slotA, slotC);
  k_knn_max3<128><<<2048, 256, 0, stream>>>(slotA, slotC, sqb, slotD);
  // 11-12: g2 combined dense 128->1024 fused with per-tile col-max -> P
  k_combine<<<512, 256, 0, stream>>>(g2lw, g2lb, g2cw, g2cb, Wc, bc, 128, 1024);
  k_apply<128, false, true><<<dim3(512, 16), 256, 0, stream>>>(slotD, Wc, bc, P, 1024);
  // 13: reduce -> gmax[16][1024]
  k_reduce_max<<<16, 256, 0, stream>>>(P, gm);
  // 14: head -> out[16][512]
  k_head<<<16, 256, 0, stream>>>(gm, w4, b4, w5, b5, (float*)d_out);
}

// Round 4
// 1593.089 us; speedup vs baseline: 1.6786x; 1.0359x over previous
//
#include <hip/hip_runtime.h>
#include <cstddef>
#include <cstdint>

#define NPTS 2048

typedef short bf16x8 __attribute__((ext_vector_type(8)));
typedef float f32x4 __attribute__((ext_vector_type(4)));

__device__ __forceinline__ unsigned short f2bf(float f) {
  unsigned u = __builtin_bit_cast(unsigned, f);
  unsigned r = u + 0x7fffu + ((u >> 16) & 1u);  // RNE (finite inputs)
  return (unsigned short)(r >> 16);
}
__device__ __forceinline__ float bf2f(unsigned short s) {
  unsigned u = ((unsigned)s) << 16;
  return __builtin_bit_cast(float, u);
}

// ---------------------------------------------------------------- knn1 + cov
__global__ __launch_bounds__(256) void k_knn1_cov(const float* __restrict__ x,
                                                  float* __restrict__ h0) {
  const int b = blockIdx.y;
  const int tid = threadIdx.x;
  const int lane = tid & 63;
  const int w = tid >> 6;
  __shared__ float xs[NPTS * 3];
  __shared__ float sqs[NPTS];
  const float* xb = x + (size_t)b * NPTS * 3;
  for (int i = tid; i < NPTS * 3; i += 256) xs[i] = xb[i];
  __syncthreads();
  for (int n = tid; n < NPTS; n += 256) {
    float a0 = xs[3 * n], a1 = xs[3 * n + 1], a2 = xs[3 * n + 2];
    sqs[n] = fmaf(a0, a0, fmaf(a1, a1, a2 * a2));
  }
  __syncthreads();
  for (int qi = 0; qi < 16; ++qi) {
    const int nq = blockIdx.x * 64 + w * 16 + qi;
    const float qx = xs[3 * nq], qy = xs[3 * nq + 1], qz = xs[3 * nq + 2];
    const float sqq = sqs[nq];
    float d[32];
#pragma unroll
    for (int j = 0; j < 32; ++j) {
      int m = j * 64 + lane;
      float mx = xs[3 * m], my = xs[3 * m + 1], mz = xs[3 * m + 2];
      float dot = qx * mx;
      dot = fmaf(qy, my, dot);
      dot = fmaf(qz, mz, dot);
      d[j] = fmaf(-2.f, dot, sqq + sqs[m]);
    }
    unsigned mask = 0;
    int widx[16];
#pragma unroll
    for (int r = 0; r < 16; ++r) {
      float vmin = 3.4e38f;
      int mmin = 0x7fffffff;
#pragma unroll
      for (int j = 0; j < 32; ++j) {
        bool ok = !((mask >> j) & 1u) && (d[j] < vmin);
        if (ok) { vmin = d[j]; mmin = j * 64 + lane; }
      }
#pragma unroll
      for (int s = 1; s < 64; s <<= 1) {
        float ov = __shfl_xor(vmin, s, 64);
        int om = __shfl_xor(mmin, s, 64);
        if (ov < vmin || (ov == vmin && om < mmin)) { vmin = ov; mmin = om; }
      }
      widx[r] = mmin;
      if (lane == (mmin & 63)) mask |= 1u << (mmin >> 6);
    }
    float sx = 0, sy = 0, sz = 0;
#pragma unroll
    for (int r = 0; r < 16; ++r) {
      int m = widx[r];
      sx += xs[3 * m]; sy += xs[3 * m + 1]; sz += xs[3 * m + 2];
    }
    const float mx = sx * 0.0625f, my = sy * 0.0625f, mz = sz * 0.0625f;
    float cxx = 0, cxy = 0, cxz = 0, cyy = 0, cyz = 0, czz = 0;
#pragma unroll
    for (int r = 0; r < 16; ++r) {
      int m = widx[r];
      float ax = xs[3 * m] - mx, ay = xs[3 * m + 1] - my, az = xs[3 * m + 2] - mz;
      cxx = fmaf(ax, ax, cxx); cxy = fmaf(ax, ay, cxy); cxz = fmaf(ax, az, cxz);
      cyy = fmaf(ay, ay, cyy); cyz = fmaf(ay, az, cyz); czz = fmaf(az, az, czz);
    }
    if (lane == 0) {
      float* o = h0 + ((size_t)b * NPTS + nq) * 12;
      o[0] = qx; o[1] = qy; o[2] = qz;
      o[3] = cxx; o[4] = cxy; o[5] = cxz;
      o[6] = cxy; o[7] = cyy; o[8] = cyz;
      o[9] = cxz; o[10] = cyz; o[11] = czz;
    }
  }
}

// ---------------------------------------------------------------- MLP1 (12->12->64->64, BN folded)
__global__ __launch_bounds__(256) void k_mlp1(
    const float* __restrict__ h0,
    const float* __restrict__ w1, const float* __restrict__ cb1,
    const float* __restrict__ w2, const float* __restrict__ cb2,
    const float* __restrict__ w3, const float* __restrict__ cb3,
    const float* __restrict__ bn1g, const float* __restrict__ bn1b,
    const float* __restrict__ bn1m, const float* __restrict__ bn1v,
    const float* __restrict__ bn2g, const float* __restrict__ bn2b,
    const float* __restrict__ bn2m, const float* __restrict__ bn2v,
    const float* __restrict__ bn3g, const float* __restrict__ bn3b,
    const float* __restrict__ bn3m, const float* __restrict__ bn3v,
    float* __restrict__ h3out) {
  __shared__ float W1[144], W2[768], W3[4096];
  __shared__ float S1[12], F1[12], S2[64], F2[64], S3[64], F3[64];
  __shared__ float h0s[64][12];
  __shared__ float A2[64][65];
  const int tid = threadIdx.x;
  for (int i = tid; i < 144; i += 256) W1[i] = w1[i];
  for (int i = tid; i < 768; i += 256) W2[i] = w2[i];
  for (int i = tid; i < 4096; i += 256) W3[i] = w3[i];
  if (tid < 12) {
    float s = bn1g[tid] * rsqrtf(bn1v[tid] + 1e-3f);
    S1[tid] = s; F1[tid] = (cb1[tid] - bn1m[tid]) * s + bn1b[tid];
  }
  if (tid < 64) {
    float s2 = bn2g[tid] * rsqrtf(bn2v[tid] + 1e-3f);
    S2[tid] = s2; F2[tid] = (cb2[tid] - bn2m[tid]) * s2 + bn2b[tid];
    float s3 = bn3g[tid] * rsqrtf(bn3v[tid] + 1e-3f);
    S3[tid] = s3; F3[tid] = (cb3[tid] - bn3m[tid]) * s3 + bn3b[tid];
  }
  const int p0 = blockIdx.x * 64;
  for (int i = tid; i < 64 * 12; i += 256)
    h0s[i / 12][i % 12] = h0[(size_t)p0 * 12 + i];
  __syncthreads();
  const int pl = tid >> 2;
  const int q = tid & 3;
  float v1[12];
#pragma unroll
  for (int o = 0; o < 12; ++o) {
    float a = 0.f;
#pragma unroll
    for (int i = 0; i < 12; ++i) a = fmaf(h0s[pl][i], W1[i * 12 + o], a);
    v1[o] = fmaxf(fmaf(a, S1[o], F1[o]), 0.f);
  }
#pragma unroll
  for (int o = 0; o < 16; ++o) {
    int oo = q * 16 + o;
    float a = 0.f;
#pragma unroll
    for (int i = 0; i < 12; ++i) a = fmaf(v1[i], W2[i * 64 + oo], a);
    A2[pl][oo] = fmaxf(fmaf(a, S2[oo], F2[oo]), 0.f);
  }
  __syncthreads();
  float acc[16];
#pragma unroll
  for (int o = 0; o < 16; ++o) acc[o] = 0.f;
  for (int i = 0; i < 64; ++i) {
    float xv = A2[pl][i];
#pragma unroll
    for (int o = 0; o < 16; ++o) acc[o] = fmaf(xv, W3[i * 64 + q * 16 + o], acc[o]);
  }
  float* orow = h3out + (size_t)(p0 + pl) * 64 + q * 16;
#pragma unroll
  for (int o4 = 0; o4 < 4; ++o4) {
    float4 v;
    int oo = q * 16 + 4 * o4;
    v.x = fmaxf(fmaf(acc[4 * o4 + 0], S3[oo + 0], F3[oo + 0]), 0.f);
    v.y = fmaxf(fmaf(acc[4 * o4 + 1], S3[oo + 1], F3[oo + 1]), 0.f);
    v.z = fmaxf(fmaf(acc[4 * o4 + 2], S3[oo + 2], F3[oo + 2]), 0.f);
    v.w = fmaxf(fmaf(acc[4 * o4 + 3], S3[oo + 3], F3[oo + 3]), 0.f);
    *(float4*)&orow[4 * o4] = v;
  }
}

// ---------------------------------------------------------------- sq norms
template <int C>
__global__ __launch_bounds__(256) void k_sqnorm(const float* __restrict__ h,
                                                float* __restrict__ sq) {
  const int p = blockIdx.x * 256 + threadIdx.x;
  const float* row = h + (size_t)p * C;
  float a = 0.f;
#pragma unroll
  for (int i = 0; i < C; ++i) a = fmaf(row[i], row[i], a);
  sq[p] = a;
}

// ---------------------------------------------------------------- split f32 -> bf16 hi/lo planes
__global__ __launch_bounds__(256) void k_split(const float* __restrict__ h,
                                               unsigned short* __restrict__ hi,
                                               unsigned short* __restrict__ lo) {
  const size_t g = ((size_t)blockIdx.x * 256 + threadIdx.x) * 8;
  float4 v0 = *(const float4*)&h[g];
  float4 v1 = *(const float4*)&h[g + 4];
  float f[8] = {v0.x, v0.y, v0.z, v0.w, v1.x, v1.y, v1.z, v1.w};
  bf16x8 hv, lv;
#pragma unroll
  for (int i = 0; i < 8; ++i) {
    unsigned short hb = f2bf(f[i]);
    hv[i] = (short)hb;
    lv[i] = (short)f2bf(f[i] - bf2f(hb));
  }
  *(bf16x8*)&hi[g] = hv;
  *(bf16x8*)&lo[g] = lv;
}

// ---------------------------------------------------------------- MFMA dot GEMM: Dot[bz][q][m] = <h_q, h_m> (split bf16, 3 terms)
template <int C>
__global__ __launch_bounds__(256) void k_dgemm(const unsigned short* __restrict__ hi,
                                               const unsigned short* __restrict__ lo,
                                               float* __restrict__ Dot, int batch0) {
  const int tid = threadIdx.x, lane = tid & 63, w = tid >> 6;
  const int bz = blockIdx.z;
  const int b = batch0 + bz;
  const int q0 = blockIdx.x * 64 + w * 16;
  const int m0 = blockIdx.y * 128;
  const size_t base = (size_t)b * NPTS * C;
  const int r = lane & 15, ks = (lane >> 4) * 8;
  const unsigned short* Ah = hi + base + (size_t)(q0 + r) * C + ks;
  const unsigned short* Al = lo + base + (size_t)(q0 + r) * C + ks;
  const unsigned short* Bh = hi + base + (size_t)(m0 + r) * C + ks;
  const unsigned short* Bl = lo + base + (size_t)(m0 + r) * C + ks;
  f32x4 acc[8];
#pragma unroll
  for (int mt = 0; mt < 8; ++mt) acc[mt] = (f32x4){0.f, 0.f, 0.f, 0.f};
#pragma unroll
  for (int kk = 0; kk < C; kk += 32) {
    bf16x8 ah = *(const bf16x8*)(Ah + kk);
    bf16x8 al = *(const bf16x8*)(Al + kk);
#pragma unroll
    for (int mt = 0; mt < 8; ++mt) {
      bf16x8 bh = *(const bf16x8*)(Bh + (size_t)mt * 16 * C + kk);
      bf16x8 bl = *(const bf16x8*)(Bl + (size_t)mt * 16 * C + kk);
      acc[mt] = __builtin_amdgcn_mfma_f32_16x16x32_bf16(ah, bh, acc[mt], 0, 0, 0);
      acc[mt] = __builtin_amdgcn_mfma_f32_16x16x32_bf16(ah, bl, acc[mt], 0, 0, 0);
      acc[mt] = __builtin_amdgcn_mfma_f32_16x16x32_bf16(al, bh, acc[mt], 0, 0, 0);
    }
  }
  float* Db = Dot + (size_t)bz * NPTS * NPTS + (size_t)q0 * NPTS + m0;
#pragma unroll
  for (int mt = 0; mt < 8; ++mt)
#pragma unroll
    for (int r2 = 0; r2 < 4; ++r2)
      Db[(size_t)((lane >> 4) * 4 + r2) * NPTS + mt * 16 + (lane & 15)] = acc[mt][r2];
}

// ---------------------------------------------------------------- select top16 + gather-max from Dot rows
template <int C>
__global__ __launch_bounds__(256) void k_select(const float* __restrict__ Dot,
                                                const float* __restrict__ h,
                                                const float* __restrict__ sq,
                                                float* __restrict__ outm, int batch0) {
  const int tid = threadIdx.x, lane = tid & 63, w = tid >> 6;
  const int bz = blockIdx.y, b = batch0 + bz;
  const int q = blockIdx.x * 4 + w;
  const size_t hb = (size_t)b * NPTS * C;
  const float* __restrict__ hbp = h + hb;
  const float* __restrict__ sqb = sq + (size_t)b * NPTS;
  const float* __restrict__ Drow = Dot + (size_t)bz * NPTS * NPTS + (size_t)q * NPTS;
  const float qsq = sqb[q];
  float d[32];
#pragma unroll
  for (int t = 0; t < 8; ++t) {
    float4 dv = *(const float4*)&Drow[t * 256 + 4 * lane];
    float4 sv = *(const float4*)&sqb[t * 256 + 4 * lane];
    d[4 * t + 0] = fmaf(-2.f, dv.x, qsq + sv.x);
    d[4 * t + 1] = fmaf(-2.f, dv.y, qsq + sv.y);
    d[4 * t + 2] = fmaf(-2.f, dv.z, qsq + sv.z);
    d[4 * t + 3] = fmaf(-2.f, dv.w, qsq + sv.w);
  }
  unsigned mask = 0u;
  float g0 = -3.4e38f, g1 = -3.4e38f;
#pragma unroll 1
  for (int r = 0; r < 16; ++r) {
    float vmin = 3.4e38f;
    int mmin = 0x7fffffff;
#pragma unroll
    for (int j = 0; j < 32; ++j) {
      const int m = (j >> 2) * 256 + 4 * lane + (j & 3);
      bool ok = !((mask >> j) & 1u) && (d[j] < vmin);
      if (ok) { vmin = d[j]; mmin = m; }
    }
#pragma unroll
    for (int s = 1; s < 64; s <<= 1) {
      float ov = __shfl_xor(vmin, s, 64);
      int om = __shfl_xor(mmin, s, 64);
      if (ov < vmin || (ov == vmin && om < mmin)) { vmin = ov; mmin = om; }
    }
    if (lane == ((mmin >> 2) & 63)) mask |= 1u << (((mmin >> 8) << 2) | (mmin & 3));
    const float* row = hbp + (size_t)mmin * C;
    g0 = fmaxf(g0, row[lane]);
    if (C == 128) g1 = fmaxf(g1, row[64 + lane]);
  }
  float* orow = outm + hb + (size_t)q * C;
  orow[lane] = g0;
  if (C == 128) orow[64 + lane] = g1;
}

// ---------------------------------------------------------------- combine two denses: Wc = lw*cw, bc = lb*cw + cb
__global__ __launch_bounds__(256) void k_combine(const float* __restrict__ lw,
                                                 const float* __restrict__ lb,
                                                 const float* __restrict__ cw,
                                                 const float* __restrict__ cb,
                                                 float* __restrict__ Wc,
                                                 float* __restrict__ bc, int K, int M) {
  const int id = blockIdx.x * 256 + threadIdx.x;
  if (id < K * M) {
    int i = id / M, o = id % M;
    float a = 0.f;
    for (int k = 0; k < K; ++k) a = fmaf(lw[i * K + k], cw[k * M + o], a);
    Wc[id] = a;
  }
  if (id < M) {
    float a = cb[id];
    for (int k = 0; k < K; ++k) a = fmaf(lb[k], cw[k * M + id], a);
    bc[id] = a;
  }
}

// ---------------------------------------------------------------- GEMM apply: out = A[32768,K] * W[K,M] (+bias) [relu | colmax]
template <int K, bool RELU, bool COLMAX>
__global__ __launch_bounds__(256) void k_apply(const float* __restrict__ A,
                                               const float* __restrict__ W,
                                               const float* __restrict__ bias,
                                               float* __restrict__ out, int M) {
  __shared__ float As[64][K + 4];
  __shared__ float Bs[K][64];
  __shared__ float cm[16][64];
  const int tid = threadIdx.x;
  const int tx = tid & 15, ty = tid >> 4;
  const int rt = blockIdx.x;
  const int col0 = blockIdx.y * 64;
  const int r0 = rt * 64;
  for (int i = tid; i < 64 * K; i += 256) {
    int r = i / K, c = i % K;
    As[r][c] = A[(size_t)(r0 + r) * K + c];
  }
  for (int i = tid; i < K * 64; i += 256) {
    int k = i >> 6, j = i & 63;
    Bs[k][j] = W[(size_t)k * M + col0 + j];
  }
  __syncthreads();
  float acc[4][4];
#pragma unroll
  for (int i = 0; i < 4; ++i)
#pragma unroll
    for (int j = 0; j < 4; ++j) acc[i][j] = 0.f;
  for (int k = 0; k < K; k += 4) {
    float4 av4[4], bv4[4];
#pragma unroll
    for (int i = 0; i < 4; ++i) av4[i] = *(const float4*)&As[4 * ty + i][k];
#pragma unroll
    for (int kk = 0; kk < 4; ++kk) bv4[kk] = *(const float4*)&Bs[k + kk][4 * tx];
    float a_[4][4], b_[4][4];
#pragma unroll
    for (int i = 0; i < 4; ++i) {
      a_[i][0] = av4[i].x; a_[i][1] = av4[i].y; a_[i][2] = av4[i].z; a_[i][3] = av4[i].w;
      b_[i][0] = bv4[i].x; b_[i][1] = bv4[i].y; b_[i][2] = bv4[i].z; b_[i][3] = bv4[i].w;
    }
#pragma unroll
    for (int kk = 0; kk < 4; ++kk)
#pragma unroll
      for (int i = 0; i < 4; ++i)
#pragma unroll
        for (int j = 0; j < 4; ++j)
          acc[i][j] = fmaf(a_[i][kk], b_[kk][j], acc[i][j]);
  }
  if (RELU) {
#pragma unroll
    for (int i = 0; i < 4; ++i) {
      int r = r0 + 4 * ty + i;
      float4 v;
      v.x = fmaxf(acc[i][0] + bias[col0 + 4 * tx + 0], 0.f);
      v.y = fmaxf(acc[i][1] + bias[col0 + 4 * tx + 1], 0.f);
      v.z = fmaxf(acc[i][2] + bias[col0 + 4 * tx + 2], 0.f);
      v.w = fmaxf(acc[i][3] + bias[col0 + 4 * tx + 3], 0.f);
      *(float4*)&out[(size_t)r * M + col0 + 4 * tx] = v;
    }
  }
  if (COLMAX) {
#pragma unroll
    for (int j = 0; j < 4; ++j) {
      float mj = fmaxf(fmaxf(acc[0][j], acc[1][j]), fmaxf(acc[2][j], acc[3][j]));
      cm[ty][4 * tx + j] = mj;
    }
    __syncthreads();
    if (tid < 64) {
      float mj = cm[0][tid];
#pragma unroll
      for (int r = 1; r < 16; ++r) mj = fmaxf(mj, cm[r][tid]);
      out[(size_t)rt * M + col0 + tid] = mj + bias[col0 + tid];
    }
  }
}

// ---------------------------------------------------------------- reduce P[512][1024] -> gmax[16][1024]
__global__ __launch_bounds__(256) void k_reduce_max(const float* __restrict__ P,
                                                    float* __restrict__ gmax) {
  const int b = blockIdx.x, tid = threadIdx.x;
  for (int c = tid; c < 1024; c += 256) {
    float m = P[(size_t)(b * 32) * 1024 + c];
    for (int rt = 1; rt < 32; ++rt)
      m = fmaxf(m, P[(size_t)(b * 32 + rt) * 1024 + c]);
    gmax[b * 1024 + c] = m;
  }
}

// ---------------------------------------------------------------- head: relu(gmax*W4+b4)*W5+b5
__global__ __launch_bounds__(256) void k_head(const float* __restrict__ gmax,
                                              const float* __restrict__ w4,
                                              const float* __restrict__ b4,
                                              const float* __restrict__ w5,
                                              const float* __restrict__ b5,
                                              float* __restrict__ out) {
  __shared__ float xb[1024], hbuf[1024];
  const int b = blockIdx.x, tid = threadIdx.x;
  for (int i = tid; i < 1024; i += 256) xb[i] = gmax[b * 1024 + i];
  __syncthreads();
  {
    float acc[4];
#pragma unroll
    for (int j = 0; j < 4; ++j) acc[j] = b4[tid + 256 * j];
    for (int i = 0; i < 1024; ++i) {
      float xv = xb[i];
      const float* wrow = w4 + (size_t)i * 1024;
#pragma unroll
      for (int j = 0; j < 4; ++j) acc[j] = fmaf(xv, wrow[tid + 256 * j], acc[j]);
    }
#pragma unroll
    for (int j = 0; j < 4; ++j) hbuf[tid + 256 * j] = fmaxf(acc[j], 0.f);
  }
  __syncthreads();
  {
    float acc[2];
#pragma unroll
    for (int j = 0; j < 2; ++j) acc[j] = b5[tid + 256 * j];
    for (int i = 0; i < 1024; ++i) {
      float xv = hbuf[i];
      const float* wrow = w5 + (size_t)i * 512;
#pragma unroll
      for (int j = 0; j < 2; ++j) acc[j] = fmaf(xv, wrow[tid + 256 * j], acc[j]);
    }
#pragma unroll
    for (int j = 0; j < 2; ++j) out[(size_t)b * 512 + tid + 256 * j] = acc[j];
  }
}

// ----------------------------------------------------------------
extern "C" void kernel_launch(void* const* d_in, const int* in_sizes, int n_in,
                              void* d_out, int out_size, void* d_ws, size_t ws_size,
                              hipStream_t stream) {
  (void)in_sizes; (void)n_in; (void)out_size;
  const float* x = (const float*)d_in[0];
  const float* w1 = (const float*)d_in[1];  const float* b1 = (const float*)d_in[2];
  const float* w2 = (const float*)d_in[3];  const float* b2 = (const float*)d_in[4];
  const float* w3 = (const float*)d_in[5];  const float* b3 = (const float*)d_in[6];
  const float* g1lw = (const float*)d_in[7];  const float* g1lb = (const float*)d_in[8];
  const float* g1cw = (const float*)d_in[9];  const float* g1cb = (const float*)d_in[10];
  const float* g2lw = (const float*)d_in[11]; const float* g2lb = (const float*)d_in[12];
  const float* g2cw = (const float*)d_in[13]; const float* g2cb = (const float*)d_in[14];
  const float* w4 = (const float*)d_in[15]; const float* b4 = (const float*)d_in[16];
  const float* w5 = (const float*)d_in[17]; const float* b5 = (const float*)d_in[18];
  const float* bn1g = (const float*)d_in[19]; const float* bn1b = (const float*)d_in[20];
  const float* bn1m = (const float*)d_in[21]; const float* bn1v = (const float*)d_in[22];
  const float* bn2g = (const float*)d_in[23]; const float* bn2b = (const float*)d_in[24];
  const float* bn2m = (const float*)d_in[25]; const float* bn2v = (const float*)d_in[26];
  const float* bn3g = (const float*)d_in[27]; const float* bn3b = (const float*)d_in[28];
  const float* bn3m = (const float*)d_in[29]; const float* bn3v = (const float*)d_in[30];

  float* ws = (float*)d_ws;
  size_t off = 0;
  auto alloc = [&](size_t n) { float* p = ws + off; off += (n + 63) & ~(size_t)63; return p; };
  float* slotA = alloc(16u * 2048 * 128);   // h0 then h4
  float* slotB = alloc(16u * 2048 * 64);    // h3
  float* slotD = alloc(16u * 2048 * 128);   // m1 then m2
  float* sqv  = alloc(16u * 2048);          // sq
  unsigned short* hip_ = (unsigned short*)alloc(16u * 2048 * 64);  // hi plane (bf16, max C=128)
  unsigned short* lop_ = (unsigned short*)alloc(16u * 2048 * 64);  // lo plane
  float* Wc   = alloc(128u * 1024);
  float* bc   = alloc(1024);
  float* P    = alloc(512u * 1024);
  float* gm   = alloc(16u * 1024);
  // Dot chunk buffer: CH batches of 2048x2048 f32; shrink if ws too small
  int CH = 4;
  while (CH > 1 && (off + (size_t)CH * NPTS * NPTS + 64) * 4 > ws_size) CH >>= 1;
  float* Dot = alloc((size_t)CH * NPTS * NPTS);

  // 1: knn on xyz + covariance -> h0[B,N,12]
  k_knn1_cov<<<dim3(32, 16), 256, 0, stream>>>(x, slotA);
  // 2: MLP1 -> h3[B,N,64]
  k_mlp1<<<512, 256, 0, stream>>>(slotA, w1, b1, w2, b2, w3, b3,
                                  bn1g, bn1b, bn1m, bn1v,
                                  bn2g, bn2b, bn2m, bn2v,
                                  bn3g, bn3b, bn3m, bn3v, slotB);
  // 3: knn(64) via MFMA split-bf16 + select -> m1
  k_sqnorm<64><<<128, 256, 0, stream>>>(slotB, sqv);
  k_split<<<1024, 256, 0, stream>>>(slotB, hip_, lop_);   // 16*2048*64 / 8 / 256
  for (int c = 0; c < 16; c += CH) {
    int ch = (16 - c) < CH ? (16 - c) : CH;
    k_dgemm<64><<<dim3(32, 16, ch), 256, 0, stream>>>(hip_, lop_, Dot, c);
    k_select<64><<<dim3(512, ch), 256, 0, stream>>>(Dot, slotB, sqv, slotD, c);
  }
  // 4: g1 combined dense 64->128 + relu -> h4
  k_combine<<<32, 256, 0, stream>>>(g1lw, g1lb, g1cw, g1cb, Wc, bc, 64, 128);
  k_apply<64, true, false><<<dim3(512, 2), 256, 0, stream>>>(slotD, Wc, bc, slotA, 128);
  // 5: knn(128) via MFMA + select -> m2
  k_sqnorm<128><<<128, 256, 0, stream>>>(slotA, sqv);
  k_split<<<2048, 256, 0, stream>>>(slotA, hip_, lop_);   // 16*2048*128 / 8 / 256
  for (int c = 0; c < 16; c += CH) {
    int ch = (16 - c) < CH ? (16 - c) : CH;
    k_dgemm<128><<<dim3(32, 16, ch), 256, 0, stream>>>(hip_, lop_, Dot, c);
    k_select<128><<<dim3(512, ch), 256, 0, stream>>>(Dot, slotA, sqv, slotD, c);
  }
  // 6: g2 combined dense 128->1024 fused with per-tile col-max -> P
  k_combine<<<512, 256, 0, stream>>>(g2lw, g2lb, g2cw, g2cb, Wc, bc, 128, 1024);
  k_apply<128, false, true><<<dim3(512, 16), 256, 0, stream>>>(slotD, Wc, bc, P, 1024);
  // 7: reduce -> gmax[16][1024]
  k_reduce_max<<<16, 256, 0, stream>>>(P, gm);
  // 8: head -> out[16][512]
  k_head<<<16, 256, 0, stream>>>(gm, w4, b4, w5, b5, (float*)d_out);
}

// Round 5
// 1499.015 us; speedup vs baseline: 1.7839x; 1.0628x over previous
//
#include <hip/hip_runtime.h>
#include <cstddef>
#include <cstdint>

#define NPTS 2048

typedef short bf16x8 __attribute__((ext_vector_type(8)));
typedef float f32x4 __attribute__((ext_vector_type(4)));

__device__ __forceinline__ unsigned short f2bf(float f) {
  unsigned u = __builtin_bit_cast(unsigned, f);
  unsigned r = u + 0x7fffu + ((u >> 16) & 1u);  // RNE (finite inputs)
  return (unsigned short)(r >> 16);
}
__device__ __forceinline__ float bf2f(unsigned short s) {
  unsigned u = ((unsigned)s) << 16;
  return __builtin_bit_cast(float, u);
}

// ---------------------------------------------------------------- knn1 + cov (1 query per wave)
__global__ __launch_bounds__(256) void k_knn1_cov(const float* __restrict__ x,
                                                  float* __restrict__ h0) {
  const int b = blockIdx.y;
  const int tid = threadIdx.x;
  const int lane = tid & 63;
  const int w = tid >> 6;
  __shared__ float4 xsq[NPTS];
  const float* xb = x + (size_t)b * NPTS * 3;
  for (int i = tid; i < NPTS; i += 256) {
    float a0 = xb[3 * i], a1 = xb[3 * i + 1], a2 = xb[3 * i + 2];
    xsq[i] = make_float4(a0, a1, a2, fmaf(a0, a0, fmaf(a1, a1, a2 * a2)));
  }
  __syncthreads();
  const int nq = blockIdx.x * 4 + w;
  const float4 q4 = xsq[nq];
  const float sqq = q4.w;
  float d[32];
#pragma unroll
  for (int j = 0; j < 32; ++j) {
    float4 v = xsq[j * 64 + lane];
    float dot = q4.x * v.x;
    dot = fmaf(q4.y, v.y, dot);
    dot = fmaf(q4.z, v.z, dot);
    d[j] = fmaf(-2.f, dot, sqq + v.w);
  }
  unsigned mask = 0;
  int widx[16];
#pragma unroll
  for (int r = 0; r < 16; ++r) {
    float vmin = 3.4e38f;
    int mmin = 0x7fffffff;
#pragma unroll
    for (int j = 0; j < 32; ++j) {
      bool ok = !((mask >> j) & 1u) && (d[j] < vmin);
      if (ok) { vmin = d[j]; mmin = j * 64 + lane; }
    }
#pragma unroll
    for (int s = 1; s < 64; s <<= 1) {
      float ov = __shfl_xor(vmin, s, 64);
      int om = __shfl_xor(mmin, s, 64);
      if (ov < vmin || (ov == vmin && om < mmin)) { vmin = ov; mmin = om; }
    }
    widx[r] = mmin;
    if (lane == (mmin & 63)) mask |= 1u << (mmin >> 6);
  }
  // two-pass mean/cov (wave-uniform broadcast reads)
  float sx = 0, sy = 0, sz = 0;
#pragma unroll
  for (int r = 0; r < 16; ++r) {
    float4 v = xsq[widx[r]];
    sx += v.x; sy += v.y; sz += v.z;
  }
  const float mx = sx * 0.0625f, my = sy * 0.0625f, mz = sz * 0.0625f;
  float cxx = 0, cxy = 0, cxz = 0, cyy = 0, cyz = 0, czz = 0;
#pragma unroll
  for (int r = 0; r < 16; ++r) {
    float4 v = xsq[widx[r]];
    float ax = v.x - mx, ay = v.y - my, az = v.z - mz;
    cxx = fmaf(ax, ax, cxx); cxy = fmaf(ax, ay, cxy); cxz = fmaf(ax, az, cxz);
    cyy = fmaf(ay, ay, cyy); cyz = fmaf(ay, az, cyz); czz = fmaf(az, az, czz);
  }
  if (lane == 0) {
    float* o = h0 + ((size_t)b * NPTS + nq) * 12;
    float4 o0 = make_float4(q4.x, q4.y, q4.z, cxx);
    float4 o1 = make_float4(cxy, cxz, cxy, cyy);
    float4 o2 = make_float4(cyz, cxz, cyz, czz);
    *(float4*)&o[0] = o0;
    *(float4*)&o[4] = o1;
    *(float4*)&o[8] = o2;
  }
}

// ---------------------------------------------------------------- MLP1 (12->12->64->64, BN folded)
__global__ __launch_bounds__(256) void k_mlp1(
    const float* __restrict__ h0,
    const float* __restrict__ w1, const float* __restrict__ cb1,
    const float* __restrict__ w2, const float* __restrict__ cb2,
    const float* __restrict__ w3, const float* __restrict__ cb3,
    const float* __restrict__ bn1g, const float* __restrict__ bn1b,
    const float* __restrict__ bn1m, const float* __restrict__ bn1v,
    const float* __restrict__ bn2g, const float* __restrict__ bn2b,
    const float* __restrict__ bn2m, const float* __restrict__ bn2v,
    const float* __restrict__ bn3g, const float* __restrict__ bn3b,
    const float* __restrict__ bn3m, const float* __restrict__ bn3v,
    float* __restrict__ h3out) {
  __shared__ float W1[144], W2[768], W3[4096];
  __shared__ float S1[12], F1[12], S2[64], F2[64], S3[64], F3[64];
  __shared__ float h0s[64][12];
  __shared__ float A2[64][65];
  const int tid = threadIdx.x;
  for (int i = tid; i < 144; i += 256) W1[i] = w1[i];
  for (int i = tid; i < 768; i += 256) W2[i] = w2[i];
  for (int i = tid; i < 4096; i += 256) W3[i] = w3[i];
  if (tid < 12) {
    float s = bn1g[tid] * rsqrtf(bn1v[tid] + 1e-3f);
    S1[tid] = s; F1[tid] = (cb1[tid] - bn1m[tid]) * s + bn1b[tid];
  }
  if (tid < 64) {
    float s2 = bn2g[tid] * rsqrtf(bn2v[tid] + 1e-3f);
    S2[tid] = s2; F2[tid] = (cb2[tid] - bn2m[tid]) * s2 + bn2b[tid];
    float s3 = bn3g[tid] * rsqrtf(bn3v[tid] + 1e-3f);
    S3[tid] = s3; F3[tid] = (cb3[tid] - bn3m[tid]) * s3 + bn3b[tid];
  }
  const int p0 = blockIdx.x * 64;
  for (int i = tid; i < 64 * 12; i += 256)
    h0s[i / 12][i % 12] = h0[(size_t)p0 * 12 + i];
  __syncthreads();
  const int pl = tid >> 2;
  const int q = tid & 3;
  float v1[12];
#pragma unroll
  for (int o = 0; o < 12; ++o) {
    float a = 0.f;
#pragma unroll
    for (int i = 0; i < 12; ++i) a = fmaf(h0s[pl][i], W1[i * 12 + o], a);
    v1[o] = fmaxf(fmaf(a, S1[o], F1[o]), 0.f);
  }
#pragma unroll
  for (int o = 0; o < 16; ++o) {
    int oo = q * 16 + o;
    float a = 0.f;
#pragma unroll
    for (int i = 0; i < 12; ++i) a = fmaf(v1[i], W2[i * 64 + oo], a);
    A2[pl][oo] = fmaxf(fmaf(a, S2[oo], F2[oo]), 0.f);
  }
  __syncthreads();
  float acc[16];
#pragma unroll
  for (int o = 0; o < 16; ++o) acc[o] = 0.f;
  for (int i = 0; i < 64; ++i) {
    float xv = A2[pl][i];
#pragma unroll
    for (int o = 0; o < 16; ++o) acc[o] = fmaf(xv, W3[i * 64 + q * 16 + o], acc[o]);
  }
  float* orow = h3out + (size_t)(p0 + pl) * 64 + q * 16;
#pragma unroll
  for (int o4 = 0; o4 < 4; ++o4) {
    float4 v;
    int oo = q * 16 + 4 * o4;
    v.x = fmaxf(fmaf(acc[4 * o4 + 0], S3[oo + 0], F3[oo + 0]), 0.f);
    v.y = fmaxf(fmaf(acc[4 * o4 + 1], S3[oo + 1], F3[oo + 1]), 0.f);
    v.z = fmaxf(fmaf(acc[4 * o4 + 2], S3[oo + 2], F3[oo + 2]), 0.f);
    v.w = fmaxf(fmaf(acc[4 * o4 + 3], S3[oo + 3], F3[oo + 3]), 0.f);
    *(float4*)&orow[4 * o4] = v;
  }
}

// ---------------------------------------------------------------- sq norms
template <int C>
__global__ __launch_bounds__(256) void k_sqnorm(const float* __restrict__ h,
                                                float* __restrict__ sq) {
  const int p = blockIdx.x * 256 + threadIdx.x;
  const float* row = h + (size_t)p * C;
  float a = 0.f;
#pragma unroll
  for (int i = 0; i < C; ++i) a = fmaf(row[i], row[i], a);
  sq[p] = a;
}

// ---------------------------------------------------------------- split f32 -> bf16 hi/lo planes
__global__ __launch_bounds__(256) void k_split(const float* __restrict__ h,
                                               unsigned short* __restrict__ hi,
                                               unsigned short* __restrict__ lo) {
  const size_t g = ((size_t)blockIdx.x * 256 + threadIdx.x) * 8;
  float4 v0 = *(const float4*)&h[g];
  float4 v1 = *(const float4*)&h[g + 4];
  float f[8] = {v0.x, v0.y, v0.z, v0.w, v1.x, v1.y, v1.z, v1.w};
  bf16x8 hv, lv;
#pragma unroll
  for (int i = 0; i < 8; ++i) {
    unsigned short hb = f2bf(f[i]);
    hv[i] = (short)hb;
    lv[i] = (short)f2bf(f[i] - bf2f(hb));
  }
  *(bf16x8*)&hi[g] = hv;
  *(bf16x8*)&lo[g] = lv;
}

// ---------------------------------------------------------------- MFMA dist GEMM: D[bz][q][m] = sq[q]+sq[m]-2<h_q,h_m>
template <int C>
__global__ __launch_bounds__(256) void k_dgemm(const unsigned short* __restrict__ hi,
                                               const unsigned short* __restrict__ lo,
                                               const float* __restrict__ sq,
                                               float* __restrict__ Dot, int batch0) {
  const int tid = threadIdx.x, lane = tid & 63, w = tid >> 6;
  const int bz = blockIdx.z;
  const int b = batch0 + bz;
  const int q0 = blockIdx.x * 64 + w * 16;
  const int m0 = blockIdx.y * 128;
  const size_t base = (size_t)b * NPTS * C;
  const int r = lane & 15, ks = (lane >> 4) * 8;
  const unsigned short* Ah = hi + base + (size_t)(q0 + r) * C + ks;
  const unsigned short* Al = lo + base + (size_t)(q0 + r) * C + ks;
  const unsigned short* Bh = hi + base + (size_t)(m0 + r) * C + ks;
  const unsigned short* Bl = lo + base + (size_t)(m0 + r) * C + ks;
  f32x4 acc[8];
#pragma unroll
  for (int mt = 0; mt < 8; ++mt) acc[mt] = (f32x4){0.f, 0.f, 0.f, 0.f};
#pragma unroll
  for (int kk = 0; kk < C; kk += 32) {
    bf16x8 ah = *(const bf16x8*)(Ah + kk);
    bf16x8 al = *(const bf16x8*)(Al + kk);
#pragma unroll
    for (int mt = 0; mt < 8; ++mt) {
      bf16x8 bh = *(const bf16x8*)(Bh + (size_t)mt * 16 * C + kk);
      bf16x8 bl = *(const bf16x8*)(Bl + (size_t)mt * 16 * C + kk);
      acc[mt] = __builtin_amdgcn_mfma_f32_16x16x32_bf16(ah, bh, acc[mt], 0, 0, 0);
      acc[mt] = __builtin_amdgcn_mfma_f32_16x16x32_bf16(ah, bl, acc[mt], 0, 0, 0);
      acc[mt] = __builtin_amdgcn_mfma_f32_16x16x32_bf16(al, bh, acc[mt], 0, 0, 0);
    }
  }
  const float* __restrict__ sqb = sq + (size_t)b * NPTS;
  float sqq[4];
#pragma unroll
  for (int r2 = 0; r2 < 4; ++r2) sqq[r2] = sqb[q0 + (lane >> 4) * 4 + r2];
  float* Db = Dot + (size_t)bz * NPTS * NPTS + (size_t)q0 * NPTS + m0;
#pragma unroll
  for (int mt = 0; mt < 8; ++mt) {
    float smc = sqb[m0 + mt * 16 + (lane & 15)];
#pragma unroll
    for (int r2 = 0; r2 < 4; ++r2)
      Db[(size_t)((lane >> 4) * 4 + r2) * NPTS + mt * 16 + (lane & 15)] =
          fmaf(-2.f, acc[mt][r2], sqq[r2] + smc);
  }
}

// ---------------------------------------------------------------- select top16 + gather-max from D rows
template <int C>
__global__ __launch_bounds__(256) void k_select(const float* __restrict__ Dot,
                                                const float* __restrict__ h,
                                                float* __restrict__ outm, int batch0) {
  const int tid = threadIdx.x, lane = tid & 63, w = tid >> 6;
  const int bz = blockIdx.y, b = batch0 + bz;
  const int q = blockIdx.x * 4 + w;
  const size_t hb = (size_t)b * NPTS * C;
  const float* __restrict__ hbp = h + hb;
  const float* __restrict__ Drow = Dot + (size_t)bz * NPTS * NPTS + (size_t)q * NPTS;
  float d[32];
#pragma unroll
  for (int t = 0; t < 8; ++t) {
    float4 dv = *(const float4*)&Drow[t * 256 + 4 * lane];
    d[4 * t + 0] = dv.x;
    d[4 * t + 1] = dv.y;
    d[4 * t + 2] = dv.z;
    d[4 * t + 3] = dv.w;
  }
  unsigned mask = 0u;
  float g0 = -3.4e38f, g1 = -3.4e38f;
#pragma unroll 1
  for (int r = 0; r < 16; ++r) {
    float vmin = 3.4e38f;
    int mmin = 0x7fffffff;
#pragma unroll
    for (int j = 0; j < 32; ++j) {
      const int m = (j >> 2) * 256 + 4 * lane + (j & 3);
      bool ok = !((mask >> j) & 1u) && (d[j] < vmin);
      if (ok) { vmin = d[j]; mmin = m; }
    }
#pragma unroll
    for (int s = 1; s < 64; s <<= 1) {
      float ov = __shfl_xor(vmin, s, 64);
      int om = __shfl_xor(mmin, s, 64);
      if (ov < vmin || (ov == vmin && om < mmin)) { vmin = ov; mmin = om; }
    }
    if (lane == ((mmin >> 2) & 63)) mask |= 1u << (((mmin >> 8) << 2) | (mmin & 3));
    const float* row = hbp + (size_t)mmin * C;
    g0 = fmaxf(g0, row[lane]);
    if (C == 128) g1 = fmaxf(g1, row[64 + lane]);
  }
  float* orow = outm + hb + (size_t)q * C;
  orow[lane] = g0;
  if (C == 128) orow[64 + lane] = g1;
}

// ---------------------------------------------------------------- combine two denses: Wc = lw*cw, bc = lb*cw + cb
__global__ __launch_bounds__(256) void k_combine(const float* __restrict__ lw,
                                                 const float* __restrict__ lb,
                                                 const float* __restrict__ cw,
                                                 const float* __restrict__ cb,
                                                 float* __restrict__ Wc,
                                                 float* __restrict__ bc, int K, int M) {
  const int id = blockIdx.x * 256 + threadIdx.x;
  if (id < K * M) {
    int i = id / M, o = id % M;
    float a = 0.f;
    for (int k = 0; k < K; ++k) a = fmaf(lw[i * K + k], cw[k * M + o], a);
    Wc[id] = a;
  }
  if (id < M) {
    float a = cb[id];
    for (int k = 0; k < K; ++k) a = fmaf(lb[k], cw[k * M + id], a);
    bc[id] = a;
  }
}

// ---------------------------------------------------------------- GEMM apply: out = A[32768,K] * W[K,M] (+bias) [relu | colmax]
template <int K, bool RELU, bool COLMAX>
__global__ __launch_bounds__(256) void k_apply(const float* __restrict__ A,
                                               const float* __restrict__ W,
                                               const float* __restrict__ bias,
                                               float* __restrict__ out, int M) {
  __shared__ float As[64][K + 4];
  __shared__ float Bs[K][64];
  __shared__ float cm[16][64];
  const int tid = threadIdx.x;
  const int tx = tid & 15, ty = tid >> 4;
  const int rt = blockIdx.x;
  const int col0 = blockIdx.y * 64;
  const int r0 = rt * 64;
  for (int i = tid; i < 64 * K; i += 256) {
    int r = i / K, c = i % K;
    As[r][c] = A[(size_t)(r0 + r) * K + c];
  }
  for (int i = tid; i < K * 64; i += 256) {
    int k = i >> 6, j = i & 63;
    Bs[k][j] = W[(size_t)k * M + col0 + j];
  }
  __syncthreads();
  float acc[4][4];
#pragma unroll
  for (int i = 0; i < 4; ++i)
#pragma unroll
    for (int j = 0; j < 4; ++j) acc[i][j] = 0.f;
  for (int k = 0; k < K; k += 4) {
    float4 av4[4], bv4[4];
#pragma unroll
    for (int i = 0; i < 4; ++i) av4[i] = *(const float4*)&As[4 * ty + i][k];
#pragma unroll
    for (int kk = 0; kk < 4; ++kk) bv4[kk] = *(const float4*)&Bs[k + kk][4 * tx];
    float a_[4][4], b_[4][4];
#pragma unroll
    for (int i = 0; i < 4; ++i) {
      a_[i][0] = av4[i].x; a_[i][1] = av4[i].y; a_[i][2] = av4[i].z; a_[i][3] = av4[i].w;
      b_[i][0] = bv4[i].x; b_[i][1] = bv4[i].y; b_[i][2] = bv4[i].z; b_[i][3] = bv4[i].w;
    }
#pragma unroll
    for (int kk = 0; kk < 4; ++kk)
#pragma unroll
      for (int i = 0; i < 4; ++i)
#pragma unroll
        for (int j = 0; j < 4; ++j)
          acc[i][j] = fmaf(a_[i][kk], b_[kk][j], acc[i][j]);
  }
  if (RELU) {
#pragma unroll
    for (int i = 0; i < 4; ++i) {
      int r = r0 + 4 * ty + i;
      float4 v;
      v.x = fmaxf(acc[i][0] + bias[col0 + 4 * tx + 0], 0.f);
      v.y = fmaxf(acc[i][1] + bias[col0 + 4 * tx + 1], 0.f);
      v.z = fmaxf(acc[i][2] + bias[col0 + 4 * tx + 2], 0.f);
      v.w = fmaxf(acc[i][3] + bias[col0 + 4 * tx + 3], 0.f);
      *(float4*)&out[(size_t)r * M + col0 + 4 * tx] = v;
    }
  }
  if (COLMAX) {
#pragma unroll
    for (int j = 0; j < 4; ++j) {
      float mj = fmaxf(fmaxf(acc[0][j], acc[1][j]), fmaxf(acc[2][j], acc[3][j]));
      cm[ty][4 * tx + j] = mj;
    }
    __syncthreads();
    if (tid < 64) {
      float mj = cm[0][tid];
#pragma unroll
      for (int r = 1; r < 16; ++r) mj = fmaxf(mj, cm[r][tid]);
      out[(size_t)rt * M + col0 + tid] = mj + bias[col0 + tid];
    }
  }
}

// ---------------------------------------------------------------- reduce P[512][1024] -> gmax[16][1024]
__global__ __launch_bounds__(256) void k_reduce_max(const float* __restrict__ P,
                                                    float* __restrict__ gmax) {
  const int b = blockIdx.x, tid = threadIdx.x;
  for (int c = tid; c < 1024; c += 256) {
    float m = P[(size_t)(b * 32) * 1024 + c];
    for (int rt = 1; rt < 32; ++rt)
      m = fmaxf(m, P[(size_t)(b * 32 + rt) * 1024 + c]);
    gmax[b * 1024 + c] = m;
  }
}

// ---------------------------------------------------------------- head: relu(gmax*W4+b4)*W5+b5
__global__ __launch_bounds__(256) void k_head(const float* __restrict__ gmax,
                                              const float* __restrict__ w4,
                                              const float* __restrict__ b4,
                                              const float* __restrict__ w5,
                                              const float* __restrict__ b5,
                                              float* __restrict__ out) {
  __shared__ float xb[1024], hbuf[1024];
  const int b = blockIdx.x, tid = threadIdx.x;
  for (int i = tid; i < 1024; i += 256) xb[i] = gmax[b * 1024 + i];
  __syncthreads();
  {
    float acc[4];
#pragma unroll
    for (int j = 0; j < 4; ++j) acc[j] = b4[tid + 256 * j];
    for (int i = 0; i < 1024; ++i) {
      float xv = xb[i];
      const float* wrow = w4 + (size_t)i * 1024;
#pragma unroll
      for (int j = 0; j < 4; ++j) acc[j] = fmaf(xv, wrow[tid + 256 * j], acc[j]);
    }
#pragma unroll
    for (int j = 0; j < 4; ++j) hbuf[tid + 256 * j] = fmaxf(acc[j], 0.f);
  }
  __syncthreads();
  {
    float acc[2];
#pragma unroll
    for (int j = 0; j < 2; ++j) acc[j] = b5[tid + 256 * j];
    for (int i = 0; i < 1024; ++i) {
      float xv = hbuf[i];
      const float* wrow = w5 + (size_t)i * 512;
#pragma unroll
      for (int j = 0; j < 2; ++j) acc[j] = fmaf(xv, wrow[tid + 256 * j], acc[j]);
    }
#pragma unroll
    for (int j = 0; j < 2; ++j) out[(size_t)b * 512 + tid + 256 * j] = acc[j];
  }
}

// ----------------------------------------------------------------
extern "C" void kernel_launch(void* const* d_in, const int* in_sizes, int n_in,
                              void* d_out, int out_size, void* d_ws, size_t ws_size,
                              hipStream_t stream) {
  (void)in_sizes; (void)n_in; (void)out_size;
  const float* x = (const float*)d_in[0];
  const float* w1 = (const float*)d_in[1];  const float* b1 = (const float*)d_in[2];
  const float* w2 = (const float*)d_in[3];  const float* b2 = (const float*)d_in[4];
  const float* w3 = (const float*)d_in[5];  const float* b3 = (const float*)d_in[6];
  const float* g1lw = (const float*)d_in[7];  const float* g1lb = (const float*)d_in[8];
  const float* g1cw = (const float*)d_in[9];  const float* g1cb = (const float*)d_in[10];
  const float* g2lw = (const float*)d_in[11]; const float* g2lb = (const float*)d_in[12];
  const float* g2cw = (const float*)d_in[13]; const float* g2cb = (const float*)d_in[14];
  const float* w4 = (const float*)d_in[15]; const float* b4 = (const float*)d_in[16];
  const float* w5 = (const float*)d_in[17]; const float* b5 = (const float*)d_in[18];
  const float* bn1g = (const float*)d_in[19]; const float* bn1b = (const float*)d_in[20];
  const float* bn1m = (const float*)d_in[21]; const float* bn1v = (const float*)d_in[22];
  const float* bn2g = (const float*)d_in[23]; const float* bn2b = (const float*)d_in[24];
  const float* bn2m = (const float*)d_in[25]; const float* bn2v = (const float*)d_in[26];
  const float* bn3g = (const float*)d_in[27]; const float* bn3b = (const float*)d_in[28];
  const float* bn3m = (const float*)d_in[29]; const float* bn3v = (const float*)d_in[30];

  float* ws = (float*)d_ws;
  size_t off = 0;
  auto alloc = [&](size_t n) { float* p = ws + off; off += (n + 63) & ~(size_t)63; return p; };
  float* slotA = alloc(16u * 2048 * 128);   // h0 then h4
  float* slotB = alloc(16u * 2048 * 64);    // h3
  float* slotD = alloc(16u * 2048 * 128);   // m1 then m2
  float* sqv  = alloc(16u * 2048);          // sq
  unsigned short* hip_ = (unsigned short*)alloc(16u * 2048 * 64);  // hi plane (bf16, max C=128)
  unsigned short* lop_ = (unsigned short*)alloc(16u * 2048 * 64);  // lo plane
  float* Wc   = alloc(128u * 1024);
  float* bc   = alloc(1024);
  float* P    = alloc(512u * 1024);
  float* gm   = alloc(16u * 1024);
  // Dot chunk buffer: CH batches of 2048x2048 f32; shrink if ws too small
  int CH = 4;
  while (CH > 1 && (off + (size_t)CH * NPTS * NPTS + 64) * 4 > ws_size) CH >>= 1;
  float* Dot = alloc((size_t)CH * NPTS * NPTS);

  // 1: knn on xyz + covariance -> h0[B,N,12]
  k_knn1_cov<<<dim3(512, 16), 256, 0, stream>>>(x, slotA);
  // 2: MLP1 -> h3[B,N,64]
  k_mlp1<<<512, 256, 0, stream>>>(slotA, w1, b1, w2, b2, w3, b3,
                                  bn1g, bn1b, bn1m, bn1v,
                                  bn2g, bn2b, bn2m, bn2v,
                                  bn3g, bn3b, bn3m, bn3v, slotB);
  // 3: knn(64) via MFMA split-bf16 + select -> m1
  k_sqnorm<64><<<128, 256, 0, stream>>>(slotB, sqv);
  k_split<<<1024, 256, 0, stream>>>(slotB, hip_, lop_);
  for (int c = 0; c < 16; c += CH) {
    int ch = (16 - c) < CH ? (16 - c) : CH;
    k_dgemm<64><<<dim3(32, 16, ch), 256, 0, stream>>>(hip_, lop_, sqv, Dot, c);
    k_select<64><<<dim3(512, ch), 256, 0, stream>>>(Dot, slotB, slotD, c);
  }
  // 4: g1 combined dense 64->128 + relu -> h4
  k_combine<<<32, 256, 0, stream>>>(g1lw, g1lb, g1cw, g1cb, Wc, bc, 64, 128);
  k_apply<64, true, false><<<dim3(512, 2), 256, 0, stream>>>(slotD, Wc, bc, slotA, 128);
  // 5: knn(128) via MFMA + select -> m2
  k_sqnorm<128><<<128, 256, 0, stream>>>(slotA, sqv);
  k_split<<<2048, 256, 0, stream>>>(slotA, hip_, lop_);
  for (int c = 0; c < 16; c += CH) {
    int ch = (16 - c) < CH ? (16 - c) : CH;
    k_dgemm<128><<<dim3(32, 16, ch), 256, 0, stream>>>(hip_, lop_, sqv, Dot, c);
    k_select<128><<<dim3(512, ch), 256, 0, stream>>>(Dot, slotA, slotD, c);
  }
  // 6: g2 combined dense 128->1024 fused with per-tile col-max -> P
  k_combine<<<512, 256, 0, stream>>>(g2lw, g2lb, g2cw, g2cb, Wc, bc, 128, 1024);
  k_apply<128, false, true><<<dim3(512, 16), 256, 0, stream>>>(slotD, Wc, bc, P, 1024);
  // 7: reduce -> gmax[16][1024]
  k_reduce_max<<<16, 256, 0, stream>>>(P, gm);
  // 8: head -> out[16][512]
  k_head<<<16, 256, 0, stream>>>(gm, w4, b4, w5, b5, (float*)d_out);
}

// Round 6
// 1136.769 us; speedup vs baseline: 2.3524x; 1.3187x over previous
//
#include <hip/hip_runtime.h>
#include <cstddef>
#include <cstdint>

#define NPTS 2048

typedef short bf16x8 __attribute__((ext_vector_type(8)));
typedef float f32x4 __attribute__((ext_vector_type(4)));

__device__ __forceinline__ unsigned short f2bf(float f) {
  unsigned u = __builtin_bit_cast(unsigned, f);
  unsigned r = u + 0x7fffu + ((u >> 16) & 1u);  // RNE (finite inputs)
  return (unsigned short)(r >> 16);
}
__device__ __forceinline__ float bf2f(unsigned short s) {
  unsigned u = ((unsigned)s) << 16;
  return __builtin_bit_cast(float, u);
}
// float -> order-preserving u32 (handles negatives)
__device__ __forceinline__ unsigned f2sort(float f) {
  unsigned u = __builtin_bit_cast(unsigned, f);
  return u ^ (unsigned)(((int)u >> 31) | 0x80000000);
}

// sorted-4 pool insert (ascending); keys unique
__device__ __forceinline__ void pool_insert(uint64_t k, uint64_t& s0, uint64_t& s1,
                                            uint64_t& s2, uint64_t& s3) {
  s3 = k < s3 ? k : s3;
  uint64_t t;
  t = s2 < s3 ? s2 : s3; s3 = s2 < s3 ? s3 : s2; s2 = t;
  t = s1 < s2 ? s1 : s2; s2 = s1 < s2 ? s2 : s1; s1 = t;
  t = s0 < s1 ? s0 : s1; s1 = s0 < s1 ? s1 : s0; s0 = t;
}

// one extraction round: returns wave-uniform winning m (low 32 of min key)
__device__ __forceinline__ unsigned pool_extract(uint64_t& s0, uint64_t& s1,
                                                 uint64_t& s2, uint64_t& s3, int lane,
                                                 int& cnt) {
  unsigned h32 = (unsigned)(s0 >> 32);
  unsigned wmin = h32;
#pragma unroll
  for (int s = 1; s < 64; s <<= 1)
    wmin = min(wmin, (unsigned)__shfl_xor((int)wmin, s, 64));
  bool own = (h32 == wmin);
  unsigned long long bal = __ballot(own);
  unsigned lo = (unsigned)s0;
  unsigned wlo;
  if (__popcll(bal) > 1) {  // hi-tie (rare): resolve by low word (index)
    unsigned lo2 = own ? lo : 0xFFFFFFFFu;
#pragma unroll
    for (int s = 1; s < 64; s <<= 1)
      lo2 = min(lo2, (unsigned)__shfl_xor((int)lo2, s, 64));
    wlo = lo2;
  } else {
    int owner = __ffsll((unsigned long long)bal) - 1;
    wlo = (unsigned)__shfl((int)lo, owner, 64);
  }
  bool ex = own && (lo == wlo);
  cnt += ex ? 1 : 0;
  s0 = ex ? s1 : s0; s1 = ex ? s2 : s1; s2 = ex ? s3 : s2; s3 = ex ? ~0ull : s3;
  return wlo;
}

// ---------------------------------------------------------------- knn1 + cov (1 query per wave)
__global__ __launch_bounds__(256) void k_knn1_cov(const float* __restrict__ x,
                                                  float* __restrict__ h0) {
  const int b = blockIdx.y;
  const int tid = threadIdx.x;
  const int lane = tid & 63;
  const int w = tid >> 6;
  __shared__ float4 xsq[NPTS];
  const float* xb = x + (size_t)b * NPTS * 3;
  for (int i = tid; i < NPTS; i += 256) {
    float a0 = xb[3 * i], a1 = xb[3 * i + 1], a2 = xb[3 * i + 2];
    xsq[i] = make_float4(a0, a1, a2, fmaf(a0, a0, fmaf(a1, a1, a2 * a2)));
  }
  __syncthreads();
  const int nq = blockIdx.x * 4 + w;
  const float4 q4 = xsq[nq];
  const float sqq = q4.w;
  float d[32];
  uint64_t s0 = ~0ull, s1 = ~0ull, s2 = ~0ull, s3 = ~0ull;
#pragma unroll
  for (int j = 0; j < 32; ++j) {
    float4 v = xsq[j * 64 + lane];
    float dot = q4.x * v.x;
    dot = fmaf(q4.y, v.y, dot);
    dot = fmaf(q4.z, v.z, dot);
    float dd = fmaf(-2.f, dot, sqq + v.w);
    d[j] = dd;
    uint64_t k = ((uint64_t)f2sort(dd) << 32) | (unsigned)(j * 64 + lane);
    pool_insert(k, s0, s1, s2, s3);
  }
  int widx[16];
  int cnt = 0;
#pragma unroll
  for (int r = 0; r < 16; ++r)
    widx[r] = (int)pool_extract(s0, s1, s2, s3, lane, cnt);
  if (__ballot(cnt == 4) != 0ull) {  // rare exact fallback
    unsigned mask = 0;
#pragma unroll
    for (int r = 0; r < 16; ++r) {
      float vmin = 3.4e38f;
      int mmin = 0x7fffffff;
#pragma unroll
      for (int j = 0; j < 32; ++j) {
        bool ok = !((mask >> j) & 1u) && (d[j] < vmin);
        if (ok) { vmin = d[j]; mmin = j * 64 + lane; }
      }
#pragma unroll
      for (int s = 1; s < 64; s <<= 1) {
        float ov = __shfl_xor(vmin, s, 64);
        int om = __shfl_xor(mmin, s, 64);
        if (ov < vmin || (ov == vmin && om < mmin)) { vmin = ov; mmin = om; }
      }
      widx[r] = mmin;
      if (lane == (mmin & 63)) mask |= 1u << (mmin >> 6);
    }
  }
  // two-pass mean/cov (wave-uniform broadcast reads)
  float sx = 0, sy = 0, sz = 0;
#pragma unroll
  for (int r = 0; r < 16; ++r) {
    float4 v = xsq[widx[r]];
    sx += v.x; sy += v.y; sz += v.z;
  }
  const float mx = sx * 0.0625f, my = sy * 0.0625f, mz = sz * 0.0625f;
  float cxx = 0, cxy = 0, cxz = 0, cyy = 0, cyz = 0, czz = 0;
#pragma unroll
  for (int r = 0; r < 16; ++r) {
    float4 v = xsq[widx[r]];
    float ax = v.x - mx, ay = v.y - my, az = v.z - mz;
    cxx = fmaf(ax, ax, cxx); cxy = fmaf(ax, ay, cxy); cxz = fmaf(ax, az, cxz);
    cyy = fmaf(ay, ay, cyy); cyz = fmaf(ay, az, cyz); czz = fmaf(az, az, czz);
  }
  if (lane == 0) {
    float* o = h0 + ((size_t)b * NPTS + nq) * 12;
    *(float4*)&o[0] = make_float4(q4.x, q4.y, q4.z, cxx);
    *(float4*)&o[4] = make_float4(cxy, cxz, cxy, cyy);
    *(float4*)&o[8] = make_float4(cyz, cxz, cyz, czz);
  }
}

// ---------------------------------------------------------------- MLP1 (12->12->64->64, BN folded)
__global__ __launch_bounds__(256) void k_mlp1(
    const float* __restrict__ h0,
    const float* __restrict__ w1, const float* __restrict__ cb1,
    const float* __restrict__ w2, const float* __restrict__ cb2,
    const float* __restrict__ w3, const float* __restrict__ cb3,
    const float* __restrict__ bn1g, const float* __restrict__ bn1b,
    const float* __restrict__ bn1m, const float* __restrict__ bn1v,
    const float* __restrict__ bn2g, const float* __restrict__ bn2b,
    const float* __restrict__ bn2m, const float* __restrict__ bn2v,
    const float* __restrict__ bn3g, const float* __restrict__ bn3b,
    const float* __restrict__ bn3m, const float* __restrict__ bn3v,
    float* __restrict__ h3out) {
  __shared__ float W1[144], W2[768], W3[4096];
  __shared__ float S1[12], F1[12], S2[64], F2[64], S3[64], F3[64];
  __shared__ float h0s[64][12];
  __shared__ float A2[64][65];
  const int tid = threadIdx.x;
  for (int i = tid; i < 144; i += 256) W1[i] = w1[i];
  for (int i = tid; i < 768; i += 256) W2[i] = w2[i];
  for (int i = tid; i < 4096; i += 256) W3[i] = w3[i];
  if (tid < 12) {
    float s = bn1g[tid] * rsqrtf(bn1v[tid] + 1e-3f);
    S1[tid] = s; F1[tid] = (cb1[tid] - bn1m[tid]) * s + bn1b[tid];
  }
  if (tid < 64) {
    float s2 = bn2g[tid] * rsqrtf(bn2v[tid] + 1e-3f);
    S2[tid] = s2; F2[tid] = (cb2[tid] - bn2m[tid]) * s2 + bn2b[tid];
    float s3 = bn3g[tid] * rsqrtf(bn3v[tid] + 1e-3f);
    S3[tid] = s3; F3[tid] = (cb3[tid] - bn3m[tid]) * s3 + bn3b[tid];
  }
  const int p0 = blockIdx.x * 64;
  for (int i = tid; i < 64 * 12; i += 256)
    h0s[i / 12][i % 12] = h0[(size_t)p0 * 12 + i];
  __syncthreads();
  const int pl = tid >> 2;
  const int q = tid & 3;
  float v1[12];
#pragma unroll
  for (int o = 0; o < 12; ++o) {
    float a = 0.f;
#pragma unroll
    for (int i = 0; i < 12; ++i) a = fmaf(h0s[pl][i], W1[i * 12 + o], a);
    v1[o] = fmaxf(fmaf(a, S1[o], F1[o]), 0.f);
  }
#pragma unroll
  for (int o = 0; o < 16; ++o) {
    int oo = q * 16 + o;
    float a = 0.f;
#pragma unroll
    for (int i = 0; i < 12; ++i) a = fmaf(v1[i], W2[i * 64 + oo], a);
    A2[pl][oo] = fmaxf(fmaf(a, S2[oo], F2[oo]), 0.f);
  }
  __syncthreads();
  float acc[16];
#pragma unroll
  for (int o = 0; o < 16; ++o) acc[o] = 0.f;
  for (int i = 0; i < 64; ++i) {
    float xv = A2[pl][i];
#pragma unroll
    for (int o = 0; o < 16; ++o) acc[o] = fmaf(xv, W3[i * 64 + q * 16 + o], acc[o]);
  }
  float* orow = h3out + (size_t)(p0 + pl) * 64 + q * 16;
#pragma unroll
  for (int o4 = 0; o4 < 4; ++o4) {
    float4 v;
    int oo = q * 16 + 4 * o4;
    v.x = fmaxf(fmaf(acc[4 * o4 + 0], S3[oo + 0], F3[oo + 0]), 0.f);
    v.y = fmaxf(fmaf(acc[4 * o4 + 1], S3[oo + 1], F3[oo + 1]), 0.f);
    v.z = fmaxf(fmaf(acc[4 * o4 + 2], S3[oo + 2], F3[oo + 2]), 0.f);
    v.w = fmaxf(fmaf(acc[4 * o4 + 3], S3[oo + 3], F3[oo + 3]), 0.f);
    *(float4*)&orow[4 * o4] = v;
  }
}

// ---------------------------------------------------------------- sq norms
template <int C>
__global__ __launch_bounds__(256) void k_sqnorm(const float* __restrict__ h,
                                                float* __restrict__ sq) {
  const int p = blockIdx.x * 256 + threadIdx.x;
  const float* row = h + (size_t)p * C;
  float a = 0.f;
#pragma unroll
  for (int i = 0; i < C; ++i) a = fmaf(row[i], row[i], a);
  sq[p] = a;
}

// ---------------------------------------------------------------- split f32 -> bf16 hi/lo planes
__global__ __launch_bounds__(256) void k_split(const float* __restrict__ h,
                                               unsigned short* __restrict__ hi,
                                               unsigned short* __restrict__ lo) {
  const size_t g = ((size_t)blockIdx.x * 256 + threadIdx.x) * 8;
  float4 v0 = *(const float4*)&h[g];
  float4 v1 = *(const float4*)&h[g + 4];
  float f[8] = {v0.x, v0.y, v0.z, v0.w, v1.x, v1.y, v1.z, v1.w};
  bf16x8 hv, lv;
#pragma unroll
  for (int i = 0; i < 8; ++i) {
    unsigned short hb = f2bf(f[i]);
    hv[i] = (short)hb;
    lv[i] = (short)f2bf(f[i] - bf2f(hb));
  }
  *(bf16x8*)&hi[g] = hv;
  *(bf16x8*)&lo[g] = lv;
}

// ---------------------------------------------------------------- MFMA dist GEMM: D[bz][q][m] = sq[q]+sq[m]-2<h_q,h_m>
template <int C>
__global__ __launch_bounds__(256) void k_dgemm(const unsigned short* __restrict__ hi,
                                               const unsigned short* __restrict__ lo,
                                               const float* __restrict__ sq,
                                               float* __restrict__ Dot, int batch0) {
  const int tid = threadIdx.x, lane = tid & 63, w = tid >> 6;
  const int bz = blockIdx.z;
  const int b = batch0 + bz;
  const int q0 = blockIdx.x * 64 + w * 16;
  const int m0 = blockIdx.y * 128;
  const size_t base = (size_t)b * NPTS * C;
  const int r = lane & 15, ks = (lane >> 4) * 8;
  const unsigned short* Ah = hi + base + (size_t)(q0 + r) * C + ks;
  const unsigned short* Al = lo + base + (size_t)(q0 + r) * C + ks;
  const unsigned short* Bh = hi + base + (size_t)(m0 + r) * C + ks;
  const unsigned short* Bl = lo + base + (size_t)(m0 + r) * C + ks;
  f32x4 acc[8];
#pragma unroll
  for (int mt = 0; mt < 8; ++mt) acc[mt] = (f32x4){0.f, 0.f, 0.f, 0.f};
#pragma unroll
  for (int kk = 0; kk < C; kk += 32) {
    bf16x8 ah = *(const bf16x8*)(Ah + kk);
    bf16x8 al = *(const bf16x8*)(Al + kk);
#pragma unroll
    for (int mt = 0; mt < 8; ++mt) {
      bf16x8 bh = *(const bf16x8*)(Bh + (size_t)mt * 16 * C + kk);
      bf16x8 bl = *(const bf16x8*)(Bl + (size_t)mt * 16 * C + kk);
      acc[mt] = __builtin_amdgcn_mfma_f32_16x16x32_bf16(ah, bh, acc[mt], 0, 0, 0);
      acc[mt] = __builtin_amdgcn_mfma_f32_16x16x32_bf16(ah, bl, acc[mt], 0, 0, 0);
      acc[mt] = __builtin_amdgcn_mfma_f32_16x16x32_bf16(al, bh, acc[mt], 0, 0, 0);
    }
  }
  const float* __restrict__ sqb = sq + (size_t)b * NPTS;
  float sqq[4];
#pragma unroll
  for (int r2 = 0; r2 < 4; ++r2) sqq[r2] = sqb[q0 + (lane >> 4) * 4 + r2];
  float* Db = Dot + (size_t)bz * NPTS * NPTS + (size_t)q0 * NPTS + m0;
#pragma unroll
  for (int mt = 0; mt < 8; ++mt) {
    float smc = sqb[m0 + mt * 16 + (lane & 15)];
#pragma unroll
    for (int r2 = 0; r2 < 4; ++r2)
      Db[(size_t)((lane >> 4) * 4 + r2) * NPTS + mt * 16 + (lane & 15)] =
          fmaf(-2.f, acc[mt][r2], sqq[r2] + smc);
  }
}

// ---------------------------------------------------------------- select top16 + gather-max from D rows
template <int C>
__global__ __launch_bounds__(256) void k_select(const float* __restrict__ Dot,
                                                const float* __restrict__ h,
                                                float* __restrict__ outm, int batch0) {
  const int tid = threadIdx.x, lane = tid & 63, w = tid >> 6;
  const int bz = blockIdx.y, b = batch0 + bz;
  const int q = blockIdx.x * 4 + w;
  const size_t hb = (size_t)b * NPTS * C;
  const float* __restrict__ hbp = h + hb;
  const float* __restrict__ Drow = Dot + (size_t)bz * NPTS * NPTS + (size_t)q * NPTS;
  float d[32];
  uint64_t s0 = ~0ull, s1 = ~0ull, s2 = ~0ull, s3 = ~0ull;
#pragma unroll
  for (int t = 0; t < 8; ++t) {
    float4 dv = *(const float4*)&Drow[t * 256 + 4 * lane];
    d[4 * t + 0] = dv.x; d[4 * t + 1] = dv.y;
    d[4 * t + 2] = dv.z; d[4 * t + 3] = dv.w;
  }
#pragma unroll
  for (int j = 0; j < 32; ++j) {
    unsigned m = (unsigned)((j >> 2) * 256 + 4 * lane + (j & 3));
    uint64_t k = ((uint64_t)f2sort(d[j]) << 32) | m;
    pool_insert(k, s0, s1, s2, s3);
  }
  int cnt = 0;
  float g0 = -3.4e38f, g1 = -3.4e38f;
#pragma unroll
  for (int r = 0; r < 16; ++r) {
    unsigned m = pool_extract(s0, s1, s2, s3, lane, cnt);
    const float* row = hbp + (size_t)m * C;
    g0 = fmaxf(g0, row[lane]);
    if (C == 128) g1 = fmaxf(g1, row[64 + lane]);
  }
  if (__ballot(cnt == 4) != 0ull) {  // rare exact fallback
    unsigned mask = 0u;
    g0 = -3.4e38f; g1 = -3.4e38f;
#pragma unroll 1
    for (int r = 0; r < 16; ++r) {
      float vmin = 3.4e38f;
      int mmin = 0x7fffffff;
#pragma unroll
      for (int j = 0; j < 32; ++j) {
        const int m = (j >> 2) * 256 + 4 * lane + (j & 3);
        bool ok = !((mask >> j) & 1u) && (d[j] < vmin);
        if (ok) { vmin = d[j]; mmin = m; }
      }
#pragma unroll
      for (int s = 1; s < 64; s <<= 1) {
        float ov = __shfl_xor(vmin, s, 64);
        int om = __shfl_xor(mmin, s, 64);
        if (ov < vmin || (ov == vmin && om < mmin)) { vmin = ov; mmin = om; }
      }
      if (lane == ((mmin >> 2) & 63)) mask |= 1u << (((mmin >> 8) << 2) | (mmin & 3));
      const float* row = hbp + (size_t)mmin * C;
      g0 = fmaxf(g0, row[lane]);
      if (C == 128) g1 = fmaxf(g1, row[64 + lane]);
    }
  }
  float* orow = outm + hb + (size_t)q * C;
  orow[lane] = g0;
  if (C == 128) orow[64 + lane] = g1;
}

// ---------------------------------------------------------------- combine two denses: Wc = lw*cw, bc = lb*cw + cb
__global__ __launch_bounds__(256) void k_combine(const float* __restrict__ lw,
                                                 const float* __restrict__ lb,
                                                 const float* __restrict__ cw,
                                                 const float* __restrict__ cb,
                                                 float* __restrict__ Wc,
                                                 float* __restrict__ bc, int K, int M) {
  const int id = blockIdx.x * 256 + threadIdx.x;
  if (id < K * M) {
    int i = id / M, o = id % M;
    float a = 0.f;
    for (int k = 0; k < K; ++k) a = fmaf(lw[i * K + k], cw[k * M + o], a);
    Wc[id] = a;
  }
  if (id < M) {
    float a = cb[id];
    for (int k = 0; k < K; ++k) a = fmaf(lb[k], cw[k * M + id], a);
    bc[id] = a;
  }
}

// ---------------------------------------------------------------- GEMM apply: out = A[32768,K] * W[K,M] (+bias) [relu | colmax]
template <int K, bool RELU, bool COLMAX>
__global__ __launch_bounds__(256) void k_apply(const float* __restrict__ A,
                                               const float* __restrict__ W,
                                               const float* __restrict__ bias,
                                               float* __restrict__ out, int M) {
  __shared__ float As[64][K + 4];
  __shared__ float Bs[K][64];
  __shared__ float cm[16][64];
  const int tid = threadIdx.x;
  const int tx = tid & 15, ty = tid >> 4;
  const int rt = blockIdx.x;
  const int col0 = blockIdx.y * 64;
  const int r0 = rt * 64;
  for (int i = tid; i < 64 * K; i += 256) {
    int r = i / K, c = i % K;
    As[r][c] = A[(size_t)(r0 + r) * K + c];
  }
  for (int i = tid; i < K * 64; i += 256) {
    int k = i >> 6, j = i & 63;
    Bs[k][j] = W[(size_t)k * M + col0 + j];
  }
  __syncthreads();
  float acc[4][4];
#pragma unroll
  for (int i = 0; i < 4; ++i)
#pragma unroll
    for (int j = 0; j < 4; ++j) acc[i][j] = 0.f;
  for (int k = 0; k < K; k += 4) {
    float4 av4[4], bv4[4];
#pragma unroll
    for (int i = 0; i < 4; ++i) av4[i] = *(const float4*)&As[4 * ty + i][k];
#pragma unroll
    for (int kk = 0; kk < 4; ++kk) bv4[kk] = *(const float4*)&Bs[k + kk][4 * tx];
    float a_[4][4], b_[4][4];
#pragma unroll
    for (int i = 0; i < 4; ++i) {
      a_[i][0] = av4[i].x; a_[i][1] = av4[i].y; a_[i][2] = av4[i].z; a_[i][3] = av4[i].w;
      b_[i][0] = bv4[i].x; b_[i][1] = bv4[i].y; b_[i][2] = bv4[i].z; b_[i][3] = bv4[i].w;
    }
#pragma unroll
    for (int kk = 0; kk < 4; ++kk)
#pragma unroll
      for (int i = 0; i < 4; ++i)
#pragma unroll
        for (int j = 0; j < 4; ++j)
          acc[i][j] = fmaf(a_[i][kk], b_[kk][j], acc[i][j]);
  }
  if (RELU) {
#pragma unroll
    for (int i = 0; i < 4; ++i) {
      int r = r0 + 4 * ty + i;
      float4 v;
      v.x = fmaxf(acc[i][0] + bias[col0 + 4 * tx + 0], 0.f);
      v.y = fmaxf(acc[i][1] + bias[col0 + 4 * tx + 1], 0.f);
      v.z = fmaxf(acc[i][2] + bias[col0 + 4 * tx + 2], 0.f);
      v.w = fmaxf(acc[i][3] + bias[col0 + 4 * tx + 3], 0.f);
      *(float4*)&out[(size_t)r * M + col0 + 4 * tx] = v;
    }
  }
  if (COLMAX) {
#pragma unroll
    for (int j = 0; j < 4; ++j) {
      float mj = fmaxf(fmaxf(acc[0][j], acc[1][j]), fmaxf(acc[2][j], acc[3][j]));
      cm[ty][4 * tx + j] = mj;
    }
    __syncthreads();
    if (tid < 64) {
      float mj = cm[0][tid];
#pragma unroll
      for (int r = 1; r < 16; ++r) mj = fmaxf(mj, cm[r][tid]);
      out[(size_t)rt * M + col0 + tid] = mj + bias[col0 + tid];
    }
  }
}

// ---------------------------------------------------------------- reduce P[512][1024] -> gmax[16][1024]
__global__ __launch_bounds__(256) void k_reduce_max(const float* __restrict__ P,
                                                    float* __restrict__ gmax) {
  const int b = blockIdx.x, tid = threadIdx.x;
  for (int c = tid; c < 1024; c += 256) {
    float m = P[(size_t)(b * 32) * 1024 + c];
    for (int rt = 1; rt < 32; ++rt)
      m = fmaxf(m, P[(size_t)(b * 32 + rt) * 1024 + c]);
    gmax[b * 1024 + c] = m;
  }
}

// ---------------------------------------------------------------- head: relu(gmax*W4+b4)*W5+b5
__global__ __launch_bounds__(256) void k_head(const float* __restrict__ gmax,
                                              const float* __restrict__ w4,
                                              const float* __restrict__ b4,
                                              const float* __restrict__ w5,
                                              const float* __restrict__ b5,
                                              float* __restrict__ out) {
  __shared__ float xb[1024], hbuf[1024];
  const int b = blockIdx.x, tid = threadIdx.x;
  for (int i = tid; i < 1024; i += 256) xb[i] = gmax[b * 1024 + i];
  __syncthreads();
  {
    float acc[4];
#pragma unroll
    for (int j = 0; j < 4; ++j) acc[j] = b4[tid + 256 * j];
    for (int i = 0; i < 1024; ++i) {
      float xv = xb[i];
      const float* wrow = w4 + (size_t)i * 1024;
#pragma unroll
      for (int j = 0; j < 4; ++j) acc[j] = fmaf(xv, wrow[tid + 256 * j], acc[j]);
    }
#pragma unroll
    for (int j = 0; j < 4; ++j) hbuf[tid + 256 * j] = fmaxf(acc[j], 0.f);
  }
  __syncthreads();
  {
    float acc[2];
#pragma unroll
    for (int j = 0; j < 2; ++j) acc[j] = b5[tid + 256 * j];
    for (int i = 0; i < 1024; ++i) {
      float xv = hbuf[i];
      const float* wrow = w5 + (size_t)i * 512;
#pragma unroll
      for (int j = 0; j < 2; ++j) acc[j] = fmaf(xv, wrow[tid + 256 * j], acc[j]);
    }
#pragma unroll
    for (int j = 0; j < 2; ++j) out[(size_t)b * 512 + tid + 256 * j] = acc[j];
  }
}

// ----------------------------------------------------------------
extern "C" void kernel_launch(void* const* d_in, const int* in_sizes, int n_in,
                              void* d_out, int out_size, void* d_ws, size_t ws_size,
                              hipStream_t stream) {
  (void)in_sizes; (void)n_in; (void)out_size;
  const float* x = (const float*)d_in[0];
  const float* w1 = (const float*)d_in[1];  const float* b1 = (const float*)d_in[2];
  const float* w2 = (const float*)d_in[3];  const float* b2 = (const float*)d_in[4];
  const float* w3 = (const float*)d_in[5];  const float* b3 = (const float*)d_in[6];
  const float* g1lw = (const float*)d_in[7];  const float* g1lb = (const float*)d_in[8];
  const float* g1cw = (const float*)d_in[9];  const float* g1cb = (const float*)d_in[10];
  const float* g2lw = (const float*)d_in[11]; const float* g2lb = (const float*)d_in[12];
  const float* g2cw = (const float*)d_in[13]; const float* g2cb = (const float*)d_in[14];
  const float* w4 = (const float*)d_in[15]; const float* b4 = (const float*)d_in[16];
  const float* w5 = (const float*)d_in[17]; const float* b5 = (const float*)d_in[18];
  const float* bn1g = (const float*)d_in[19]; const float* bn1b = (const float*)d_in[20];
  const float* bn1m = (const float*)d_in[21]; const float* bn1v = (const float*)d_in[22];
  const float* bn2g = (const float*)d_in[23]; const float* bn2b = (const float*)d_in[24];
  const float* bn2m = (const float*)d_in[25]; const float* bn2v = (const float*)d_in[26];
  const float* bn3g = (const float*)d_in[27]; const float* bn3b = (const float*)d_in[28];
  const float* bn3m = (const float*)d_in[29]; const float* bn3v = (const float*)d_in[30];

  float* ws = (float*)d_ws;
  size_t off = 0;
  auto alloc = [&](size_t n) { float* p = ws + off; off += (n + 63) & ~(size_t)63; return p; };
  float* slotA = alloc(16u * 2048 * 128);   // h0 then h4
  float* slotB = alloc(16u * 2048 * 64);    // h3
  float* slotD = alloc(16u * 2048 * 128);   // m1 then m2
  float* sqv  = alloc(16u * 2048);          // sq
  unsigned short* hip_ = (unsigned short*)alloc(16u * 2048 * 64);  // hi plane (bf16, max C=128)
  unsigned short* lop_ = (unsigned short*)alloc(16u * 2048 * 64);  // lo plane
  float* Wc   = alloc(128u * 1024);
  float* bc   = alloc(1024);
  float* P    = alloc(512u * 1024);
  float* gm   = alloc(16u * 1024);
  // Dot chunk buffer: CH batches of 2048x2048 f32; shrink if ws too small
  int CH = 8;
  while (CH > 1 && (off + (size_t)CH * NPTS * NPTS + 64) * 4 > ws_size) CH >>= 1;
  float* Dot = alloc((size_t)CH * NPTS * NPTS);

  // 1: knn on xyz + covariance -> h0[B,N,12]
  k_knn1_cov<<<dim3(512, 16), 256, 0, stream>>>(x, slotA);
  // 2: MLP1 -> h3[B,N,64]
  k_mlp1<<<512, 256, 0, stream>>>(slotA, w1, b1, w2, b2, w3, b3,
                                  bn1g, bn1b, bn1m, bn1v,
                                  bn2g, bn2b, bn2m, bn2v,
                                  bn3g, bn3b, bn3m, bn3v, slotB);
  // 3: knn(64) via MFMA split-bf16 + select -> m1
  k_sqnorm<64><<<128, 256, 0, stream>>>(slotB, sqv);
  k_split<<<1024, 256, 0, stream>>>(slotB, hip_, lop_);
  for (int c = 0; c < 16; c += CH) {
    int ch = (16 - c) < CH ? (16 - c) : CH;
    k_dgemm<64><<<dim3(32, 16, ch), 256, 0, stream>>>(hip_, lop_, sqv, Dot, c);
    k_select<64><<<dim3(512, ch), 256, 0, stream>>>(Dot, slotB, slotD, c);
  }
  // 4: g1 combined dense 64->128 + relu -> h4
  k_combine<<<32, 256, 0, stream>>>(g1lw, g1lb, g1cw, g1cb, Wc, bc, 64, 128);
  k_apply<64, true, false><<<dim3(512, 2), 256, 0, stream>>>(slotD, Wc, bc, slotA, 128);
  // 5: knn(128) via MFMA + select -> m2
  k_sqnorm<128><<<128, 256, 0, stream>>>(slotA, sqv);
  k_split<<<2048, 256, 0, stream>>>(slotA, hip_, lop_);
  for (int c = 0; c < 16; c += CH) {
    int ch = (16 - c) < CH ? (16 - c) : CH;
    k_dgemm<128><<<dim3(32, 16, ch), 256, 0, stream>>>(hip_, lop_, sqv, Dot, c);
    k_select<128><<<dim3(512, ch), 256, 0, stream>>>(Dot, slotA, slotD, c);
  }
  // 6: g2 combined dense 128->1024 fused with per-tile col-max -> P
  k_combine<<<512, 256, 0, stream>>>(g2lw, g2lb, g2cw, g2cb, Wc, bc, 128, 1024);
  k_apply<128, false, true><<<dim3(512, 16), 256, 0, stream>>>(slotD, Wc, bc, P, 1024);
  // 7: reduce -> gmax[16][1024]
  k_reduce_max<<<16, 256, 0, stream>>>(P, gm);
  // 8: head -> out[16][512]
  k_head<<<16, 256, 0, stream>>>(gm, w4, b4, w5, b5, (float*)d_out);
}

// Round 7
// 1117.306 us; speedup vs baseline: 2.3934x; 1.0174x over previous
//
#include <hip/hip_runtime.h>
#include <cstddef>
#include <cstdint>

#define NPTS 2048

typedef short bf16x8 __attribute__((ext_vector_type(8)));
typedef float f32x4 __attribute__((ext_vector_type(4)));

__device__ __forceinline__ unsigned short f2bf(float f) {
  unsigned u = __builtin_bit_cast(unsigned, f);
  unsigned r = u + 0x7fffu + ((u >> 16) & 1u);  // RNE (finite inputs)
  return (unsigned short)(r >> 16);
}
__device__ __forceinline__ float bf2f(unsigned short s) {
  unsigned u = ((unsigned)s) << 16;
  return __builtin_bit_cast(float, u);
}
// float -> order-preserving u32 (handles negatives)
__device__ __forceinline__ unsigned f2sort(float f) {
  unsigned u = __builtin_bit_cast(unsigned, f);
  return u ^ (unsigned)(((int)u >> 31) | 0x80000000);
}

// sorted-4 pool insert (ascending); keys unique
__device__ __forceinline__ void pool_insert(uint64_t k, uint64_t& s0, uint64_t& s1,
                                            uint64_t& s2, uint64_t& s3) {
  s3 = k < s3 ? k : s3;
  uint64_t t;
  t = s2 < s3 ? s2 : s3; s3 = s2 < s3 ? s3 : s2; s2 = t;
  t = s1 < s2 ? s1 : s2; s2 = s1 < s2 ? s2 : s1; s1 = t;
  t = s0 < s1 ? s0 : s1; s1 = s0 < s1 ? s1 : s0; s0 = t;
}

// one extraction round: returns wave-uniform winning m (low 32 of min key)
__device__ __forceinline__ unsigned pool_extract(uint64_t& s0, uint64_t& s1,
                                                 uint64_t& s2, uint64_t& s3, int lane,
                                                 int& cnt) {
  unsigned h32 = (unsigned)(s0 >> 32);
  unsigned wmin = h32;
#pragma unroll
  for (int s = 1; s < 64; s <<= 1)
    wmin = min(wmin, (unsigned)__shfl_xor((int)wmin, s, 64));
  bool own = (h32 == wmin);
  unsigned long long bal = __ballot(own);
  unsigned lo = (unsigned)s0;
  unsigned wlo;
  if (__popcll(bal) > 1) {  // hi-tie (rare): resolve by low word (index)
    unsigned lo2 = own ? lo : 0xFFFFFFFFu;
#pragma unroll
    for (int s = 1; s < 64; s <<= 1)
      lo2 = min(lo2, (unsigned)__shfl_xor((int)lo2, s, 64));
    wlo = lo2;
  } else {
    int owner = __ffsll((unsigned long long)bal) - 1;
    wlo = (unsigned)__shfl((int)lo, owner, 64);
  }
  bool ex = own && (lo == wlo);
  cnt += ex ? 1 : 0;
  s0 = ex ? s1 : s0; s1 = ex ? s2 : s1; s2 = ex ? s3 : s2; s3 = ex ? ~0ull : s3;
  return wlo;
}

// ---------------------------------------------------------------- knn1 + cov (1 query per wave)
__global__ __launch_bounds__(256) void k_knn1_cov(const float* __restrict__ x,
                                                  float* __restrict__ h0) {
  const int b = blockIdx.y;
  const int tid = threadIdx.x;
  const int lane = tid & 63;
  const int w = tid >> 6;
  __shared__ float4 xsq[NPTS];
  const float* xb = x + (size_t)b * NPTS * 3;
  for (int i = tid; i < NPTS; i += 256) {
    float a0 = xb[3 * i], a1 = xb[3 * i + 1], a2 = xb[3 * i + 2];
    xsq[i] = make_float4(a0, a1, a2, fmaf(a0, a0, fmaf(a1, a1, a2 * a2)));
  }
  __syncthreads();
  const int nq = blockIdx.x * 4 + w;
  const float4 q4 = xsq[nq];
  const float sqq = q4.w;
  float d[32];
  uint64_t s0 = ~0ull, s1 = ~0ull, s2 = ~0ull, s3 = ~0ull;
#pragma unroll
  for (int j = 0; j < 32; ++j) {
    float4 v = xsq[j * 64 + lane];
    float dot = q4.x * v.x;
    dot = fmaf(q4.y, v.y, dot);
    dot = fmaf(q4.z, v.z, dot);
    float dd = fmaf(-2.f, dot, sqq + v.w);
    d[j] = dd;
    uint64_t k = ((uint64_t)f2sort(dd) << 32) | (unsigned)(j * 64 + lane);
    pool_insert(k, s0, s1, s2, s3);
  }
  int widx[16];
  int cnt = 0;
#pragma unroll
  for (int r = 0; r < 16; ++r)
    widx[r] = (int)pool_extract(s0, s1, s2, s3, lane, cnt);
  if (__ballot(cnt == 4) != 0ull) {  // rare exact fallback
    unsigned mask = 0;
#pragma unroll
    for (int r = 0; r < 16; ++r) {
      float vmin = 3.4e38f;
      int mmin = 0x7fffffff;
#pragma unroll
      for (int j = 0; j < 32; ++j) {
        bool ok = !((mask >> j) & 1u) && (d[j] < vmin);
        if (ok) { vmin = d[j]; mmin = j * 64 + lane; }
      }
#pragma unroll
      for (int s = 1; s < 64; s <<= 1) {
        float ov = __shfl_xor(vmin, s, 64);
        int om = __shfl_xor(mmin, s, 64);
        if (ov < vmin || (ov == vmin && om < mmin)) { vmin = ov; mmin = om; }
      }
      widx[r] = mmin;
      if (lane == (mmin & 63)) mask |= 1u << (mmin >> 6);
    }
  }
  // two-pass mean/cov (wave-uniform broadcast reads)
  float sx = 0, sy = 0, sz = 0;
#pragma unroll
  for (int r = 0; r < 16; ++r) {
    float4 v = xsq[widx[r]];
    sx += v.x; sy += v.y; sz += v.z;
  }
  const float mx = sx * 0.0625f, my = sy * 0.0625f, mz = sz * 0.0625f;
  float cxx = 0, cxy = 0, cxz = 0, cyy = 0, cyz = 0, czz = 0;
#pragma unroll
  for (int r = 0; r < 16; ++r) {
    float4 v = xsq[widx[r]];
    float ax = v.x - mx, ay = v.y - my, az = v.z - mz;
    cxx = fmaf(ax, ax, cxx); cxy = fmaf(ax, ay, cxy); cxz = fmaf(ax, az, cxz);
    cyy = fmaf(ay, ay, cyy); cyz = fmaf(ay, az, cyz); czz = fmaf(az, az, czz);
  }
  if (lane == 0) {
    float* o = h0 + ((size_t)b * NPTS + nq) * 12;
    *(float4*)&o[0] = make_float4(q4.x, q4.y, q4.z, cxx);
    *(float4*)&o[4] = make_float4(cxy, cxz, cxy, cyy);
    *(float4*)&o[8] = make_float4(cyz, cxz, cyz, czz);
  }
}

// ---------------------------------------------------------------- MLP1 (12->12->64->64, BN folded) + bf16 plane epilogue
__global__ __launch_bounds__(256) void k_mlp1(
    const float* __restrict__ h0,
    const float* __restrict__ w1, const float* __restrict__ cb1,
    const float* __restrict__ w2, const float* __restrict__ cb2,
    const float* __restrict__ w3, const float* __restrict__ cb3,
    const float* __restrict__ bn1g, const float* __restrict__ bn1b,
    const float* __restrict__ bn1m, const float* __restrict__ bn1v,
    const float* __restrict__ bn2g, const float* __restrict__ bn2b,
    const float* __restrict__ bn2m, const float* __restrict__ bn2v,
    const float* __restrict__ bn3g, const float* __restrict__ bn3b,
    const float* __restrict__ bn3m, const float* __restrict__ bn3v,
    float* __restrict__ h3out,
    unsigned short* __restrict__ h3hi, unsigned short* __restrict__ h3lo) {
  __shared__ float W1[144], W2[768], W3[4096];
  __shared__ float S1[12], F1[12], S2[64], F2[64], S3[64], F3[64];
  __shared__ float h0s[64][12];
  __shared__ float A2[64][65];
  const int tid = threadIdx.x;
  for (int i = tid; i < 144; i += 256) W1[i] = w1[i];
  for (int i = tid; i < 768; i += 256) W2[i] = w2[i];
  for (int i = tid; i < 4096; i += 256) W3[i] = w3[i];
  if (tid < 12) {
    float s = bn1g[tid] * rsqrtf(bn1v[tid] + 1e-3f);
    S1[tid] = s; F1[tid] = (cb1[tid] - bn1m[tid]) * s + bn1b[tid];
  }
  if (tid < 64) {
    float s2 = bn2g[tid] * rsqrtf(bn2v[tid] + 1e-3f);
    S2[tid] = s2; F2[tid] = (cb2[tid] - bn2m[tid]) * s2 + bn2b[tid];
    float s3 = bn3g[tid] * rsqrtf(bn3v[tid] + 1e-3f);
    S3[tid] = s3; F3[tid] = (cb3[tid] - bn3m[tid]) * s3 + bn3b[tid];
  }
  const int p0 = blockIdx.x * 64;
  for (int i = tid; i < 64 * 12; i += 256)
    h0s[i / 12][i % 12] = h0[(size_t)p0 * 12 + i];
  __syncthreads();
  const int pl = tid >> 2;
  const int q = tid & 3;
  float v1[12];
#pragma unroll
  for (int o = 0; o < 12; ++o) {
    float a = 0.f;
#pragma unroll
    for (int i = 0; i < 12; ++i) a = fmaf(h0s[pl][i], W1[i * 12 + o], a);
    v1[o] = fmaxf(fmaf(a, S1[o], F1[o]), 0.f);
  }
#pragma unroll
  for (int o = 0; o < 16; ++o) {
    int oo = q * 16 + o;
    float a = 0.f;
#pragma unroll
    for (int i = 0; i < 12; ++i) a = fmaf(v1[i], W2[i * 64 + oo], a);
    A2[pl][oo] = fmaxf(fmaf(a, S2[oo], F2[oo]), 0.f);
  }
  __syncthreads();
  float acc[16];
#pragma unroll
  for (int o = 0; o < 16; ++o) acc[o] = 0.f;
  for (int i = 0; i < 64; ++i) {
    float xv = A2[pl][i];
#pragma unroll
    for (int o = 0; o < 16; ++o) acc[o] = fmaf(xv, W3[i * 64 + q * 16 + o], acc[o]);
  }
  float vals[16];
#pragma unroll
  for (int o = 0; o < 16; ++o) {
    int oo = q * 16 + o;
    vals[o] = fmaxf(fmaf(acc[o], S3[oo], F3[oo]), 0.f);
  }
  const size_t rowo = (size_t)(p0 + pl) * 64 + q * 16;
  float* orow = h3out + rowo;
#pragma unroll
  for (int o4 = 0; o4 < 4; ++o4)
    *(float4*)&orow[4 * o4] = make_float4(vals[4 * o4], vals[4 * o4 + 1],
                                          vals[4 * o4 + 2], vals[4 * o4 + 3]);
  bf16x8 hv0, hv1, lv0, lv1;
#pragma unroll
  for (int o = 0; o < 8; ++o) {
    unsigned short hb = f2bf(vals[o]);
    hv0[o] = (short)hb; lv0[o] = (short)f2bf(vals[o] - bf2f(hb));
    unsigned short hb1 = f2bf(vals[8 + o]);
    hv1[o] = (short)hb1; lv1[o] = (short)f2bf(vals[8 + o] - bf2f(hb1));
  }
  *(bf16x8*)&h3hi[rowo] = hv0; *(bf16x8*)&h3hi[rowo + 8] = hv1;
  *(bf16x8*)&h3lo[rowo] = lv0; *(bf16x8*)&h3lo[rowo + 8] = lv1;
}

// ---------------------------------------------------------------- sq norms
template <int C>
__global__ __launch_bounds__(256) void k_sqnorm(const float* __restrict__ h,
                                                float* __restrict__ sq) {
  const int p = blockIdx.x * 256 + threadIdx.x;
  const float* row = h + (size_t)p * C;
  float a = 0.f;
#pragma unroll
  for (int i = 0; i < C; ++i) a = fmaf(row[i], row[i], a);
  sq[p] = a;
}

// ---------------------------------------------------------------- MFMA dist GEMM: D[bz][q][m] = sq[q]+sq[m]-2<h_q,h_m>
template <int C>
__global__ __launch_bounds__(256) void k_dgemm(const unsigned short* __restrict__ hi,
                                               const unsigned short* __restrict__ lo,
                                               const float* __restrict__ sq,
                                               float* __restrict__ Dot, int batch0) {
  const int tid = threadIdx.x, lane = tid & 63, w = tid >> 6;
  const int bz = blockIdx.z;
  const int b = batch0 + bz;
  const int q0 = blockIdx.x * 64 + w * 16;
  const int m0 = blockIdx.y * 128;
  const size_t base = (size_t)b * NPTS * C;
  const int r = lane & 15, ks = (lane >> 4) * 8;
  const unsigned short* Ah = hi + base + (size_t)(q0 + r) * C + ks;
  const unsigned short* Al = lo + base + (size_t)(q0 + r) * C + ks;
  const unsigned short* Bh = hi + base + (size_t)(m0 + r) * C + ks;
  const unsigned short* Bl = lo + base + (size_t)(m0 + r) * C + ks;
  f32x4 acc[8];
#pragma unroll
  for (int mt = 0; mt < 8; ++mt) acc[mt] = (f32x4){0.f, 0.f, 0.f, 0.f};
#pragma unroll
  for (int kk = 0; kk < C; kk += 32) {
    bf16x8 ah = *(const bf16x8*)(Ah + kk);
    bf16x8 al = *(const bf16x8*)(Al + kk);
#pragma unroll
    for (int mt = 0; mt < 8; ++mt) {
      bf16x8 bh = *(const bf16x8*)(Bh + (size_t)mt * 16 * C + kk);
      bf16x8 bl = *(const bf16x8*)(Bl + (size_t)mt * 16 * C + kk);
      acc[mt] = __builtin_amdgcn_mfma_f32_16x16x32_bf16(ah, bh, acc[mt], 0, 0, 0);
      acc[mt] = __builtin_amdgcn_mfma_f32_16x16x32_bf16(ah, bl, acc[mt], 0, 0, 0);
      acc[mt] = __builtin_amdgcn_mfma_f32_16x16x32_bf16(al, bh, acc[mt], 0, 0, 0);
    }
  }
  const float* __restrict__ sqb = sq + (size_t)b * NPTS;
  float sqq[4];
#pragma unroll
  for (int r2 = 0; r2 < 4; ++r2) sqq[r2] = sqb[q0 + (lane >> 4) * 4 + r2];
  float* Db = Dot + (size_t)bz * NPTS * NPTS + (size_t)q0 * NPTS + m0;
#pragma unroll
  for (int mt = 0; mt < 8; ++mt) {
    float smc = sqb[m0 + mt * 16 + (lane & 15)];
#pragma unroll
    for (int r2 = 0; r2 < 4; ++r2)
      Db[(size_t)((lane >> 4) * 4 + r2) * NPTS + mt * 16 + (lane & 15)] =
          fmaf(-2.f, acc[mt][r2], sqq[r2] + smc);
  }
}

// ---------------------------------------------------------------- select top16 + gather-max -> bf16 hi/lo planes
template <int C>
__global__ __launch_bounds__(256) void k_select(const float* __restrict__ Dot,
                                                const float* __restrict__ h,
                                                unsigned short* __restrict__ mhi,
                                                unsigned short* __restrict__ mlo,
                                                int batch0) {
  const int tid = threadIdx.x, lane = tid & 63, w = tid >> 6;
  const int bz = blockIdx.y, b = batch0 + bz;
  const int q = blockIdx.x * 4 + w;
  const size_t hb = (size_t)b * NPTS * C;
  const float* __restrict__ hbp = h + hb;
  const float* __restrict__ Drow = Dot + (size_t)bz * NPTS * NPTS + (size_t)q * NPTS;
  float d[32];
  uint64_t s0 = ~0ull, s1 = ~0ull, s2 = ~0ull, s3 = ~0ull;
#pragma unroll
  for (int t = 0; t < 8; ++t) {
    float4 dv = *(const float4*)&Drow[t * 256 + 4 * lane];
    d[4 * t + 0] = dv.x; d[4 * t + 1] = dv.y;
    d[4 * t + 2] = dv.z; d[4 * t + 3] = dv.w;
  }
#pragma unroll
  for (int j = 0; j < 32; ++j) {
    unsigned m = (unsigned)((j >> 2) * 256 + 4 * lane + (j & 3));
    uint64_t k = ((uint64_t)f2sort(d[j]) << 32) | m;
    pool_insert(k, s0, s1, s2, s3);
  }
  int cnt = 0;
  float g0 = -3.4e38f, g1 = -3.4e38f;
#pragma unroll
  for (int r = 0; r < 16; ++r) {
    unsigned m = pool_extract(s0, s1, s2, s3, lane, cnt);
    const float* row = hbp + (size_t)m * C;
    g0 = fmaxf(g0, row[lane]);
    if (C == 128) g1 = fmaxf(g1, row[64 + lane]);
  }
  if (__ballot(cnt == 4) != 0ull) {  // rare exact fallback
    unsigned mask = 0u;
    g0 = -3.4e38f; g1 = -3.4e38f;
#pragma unroll 1
    for (int r = 0; r < 16; ++r) {
      float vmin = 3.4e38f;
      int mmin = 0x7fffffff;
#pragma unroll
      for (int j = 0; j < 32; ++j) {
        const int m = (j >> 2) * 256 + 4 * lane + (j & 3);
        bool ok = !((mask >> j) & 1u) && (d[j] < vmin);
        if (ok) { vmin = d[j]; mmin = m; }
      }
#pragma unroll
      for (int s = 1; s < 64; s <<= 1) {
        float ov = __shfl_xor(vmin, s, 64);
        int om = __shfl_xor(mmin, s, 64);
        if (ov < vmin || (ov == vmin && om < mmin)) { vmin = ov; mmin = om; }
      }
      if (lane == ((mmin >> 2) & 63)) mask |= 1u << (((mmin >> 8) << 2) | (mmin & 3));
      const float* row = hbp + (size_t)mmin * C;
      g0 = fmaxf(g0, row[lane]);
      if (C == 128) g1 = fmaxf(g1, row[64 + lane]);
    }
  }
  const size_t orow = hb + (size_t)q * C;
  unsigned short h0b = f2bf(g0);
  mhi[orow + lane] = h0b;
  mlo[orow + lane] = f2bf(g0 - bf2f(h0b));
  if (C == 128) {
    unsigned short h1b = f2bf(g1);
    mhi[orow + 64 + lane] = h1b;
    mlo[orow + 64 + lane] = f2bf(g1 - bf2f(h1b));
  }
}

// ---------------------------------------------------------------- combine denses -> W^T bf16 planes + bias
__global__ __launch_bounds__(256) void k_combine_t(const float* __restrict__ lw,
                                                   const float* __restrict__ lb,
                                                   const float* __restrict__ cw,
                                                   const float* __restrict__ cb,
                                                   unsigned short* __restrict__ wthi,
                                                   unsigned short* __restrict__ wtlo,
                                                   float* __restrict__ bc, int K, int M) {
  const int id = blockIdx.x * 256 + threadIdx.x;
  if (id < K * M) {
    int i = id / M, o = id % M;
    float a = 0.f;
    for (int k = 0; k < K; ++k) a = fmaf(lw[i * K + k], cw[k * M + o], a);
    unsigned short hb = f2bf(a);
    wthi[(size_t)o * K + i] = hb;
    wtlo[(size_t)o * K + i] = f2bf(a - bf2f(hb));
  }
  if (id < M) {
    float a = cb[id];
    for (int k = 0; k < K; ++k) a = fmaf(lb[k], cw[k * M + id], a);
    bc[id] = a;
  }
}

// ---------------------------------------------------------------- MFMA apply: out = A[32768,K]*W[K,M]+bias, RELU->f32+planes | COLMAX->P
template <int K, int M, bool RELU, bool COLMAX>
__global__ __launch_bounds__(256) void k_apply_mfma(
    const unsigned short* __restrict__ Ah, const unsigned short* __restrict__ Al,
    const unsigned short* __restrict__ Wh, const unsigned short* __restrict__ Wl,
    const float* __restrict__ bias, float* __restrict__ fout,
    unsigned short* __restrict__ phi, unsigned short* __restrict__ plo) {
  __shared__ float cm[4][128];
  const int tid = threadIdx.x, lane = tid & 63, w = tid >> 6;
  const int rt = blockIdx.x;
  const int q0 = rt * 64 + w * 16;
  const int m0 = blockIdx.y * 128;
  const int r = lane & 15, ks = (lane >> 4) * 8;
  const unsigned short* ap_h = Ah + (size_t)(q0 + r) * K + ks;
  const unsigned short* ap_l = Al + (size_t)(q0 + r) * K + ks;
  const unsigned short* bp_h = Wh + (size_t)(m0 + r) * K + ks;
  const unsigned short* bp_l = Wl + (size_t)(m0 + r) * K + ks;
  f32x4 acc[8];
#pragma unroll
  for (int mt = 0; mt < 8; ++mt) acc[mt] = (f32x4){0.f, 0.f, 0.f, 0.f};
#pragma unroll
  for (int kk = 0; kk < K; kk += 32) {
    bf16x8 ah = *(const bf16x8*)(ap_h + kk);
    bf16x8 al = *(const bf16x8*)(ap_l + kk);
#pragma unroll
    for (int mt = 0; mt < 8; ++mt) {
      bf16x8 bh = *(const bf16x8*)(bp_h + (size_t)mt * 16 * K + kk);
      bf16x8 bl = *(const bf16x8*)(bp_l + (size_t)mt * 16 * K + kk);
      acc[mt] = __builtin_amdgcn_mfma_f32_16x16x32_bf16(ah, bh, acc[mt], 0, 0, 0);
      acc[mt] = __builtin_amdgcn_mfma_f32_16x16x32_bf16(ah, bl, acc[mt], 0, 0, 0);
      acc[mt] = __builtin_amdgcn_mfma_f32_16x16x32_bf16(al, bh, acc[mt], 0, 0, 0);
    }
  }
  if (RELU) {
#pragma unroll
    for (int mt = 0; mt < 8; ++mt) {
      const int col = m0 + mt * 16 + (lane & 15);
      const float bv = bias[col];
#pragma unroll
      for (int r2 = 0; r2 < 4; ++r2) {
        const int row = q0 + (lane >> 4) * 4 + r2;
        float v = fmaxf(acc[mt][r2] + bv, 0.f);
        const size_t idx = (size_t)row * M + col;
        fout[idx] = v;
        unsigned short hb = f2bf(v);
        phi[idx] = hb;
        plo[idx] = f2bf(v - bf2f(hb));
      }
    }
  }
  if (COLMAX) {
#pragma unroll
    for (int mt = 0; mt < 8; ++mt) {
      float v = fmaxf(fmaxf(acc[mt][0], acc[mt][1]), fmaxf(acc[mt][2], acc[mt][3]));
      v = fmaxf(v, __shfl_xor(v, 16, 64));
      v = fmaxf(v, __shfl_xor(v, 32, 64));
      cm[w][mt * 16 + (lane & 15)] = v;
    }
    __syncthreads();
    if (tid < 128) {
      float m = fmaxf(fmaxf(cm[0][tid], cm[1][tid]), fmaxf(cm[2][tid], cm[3][tid]));
      fout[(size_t)rt * M + m0 + tid] = m + bias[m0 + tid];
    }
  }
}

// ---------------------------------------------------------------- reduce P[512][1024] -> gmax[16][1024]
__global__ __launch_bounds__(256) void k_reduce_max(const float* __restrict__ P,
                                                    float* __restrict__ gmax) {
  const int b = blockIdx.x, tid = threadIdx.x;
  for (int c = tid; c < 1024; c += 256) {
    float m = P[(size_t)(b * 32) * 1024 + c];
    for (int rt = 1; rt < 32; ++rt)
      m = fmaxf(m, P[(size_t)(b * 32 + rt) * 1024 + c]);
    gmax[b * 1024 + c] = m;
  }
}

// ---------------------------------------------------------------- head: relu(gmax*W4+b4)*W5+b5
__global__ __launch_bounds__(256) void k_head(const float* __restrict__ gmax,
                                              const float* __restrict__ w4,
                                              const float* __restrict__ b4,
                                              const float* __restrict__ w5,
                                              const float* __restrict__ b5,
                                              float* __restrict__ out) {
  __shared__ float xb[1024], hbuf[1024];
  const int b = blockIdx.x, tid = threadIdx.x;
  for (int i = tid; i < 1024; i += 256) xb[i] = gmax[b * 1024 + i];
  __syncthreads();
  {
    float acc[4];
#pragma unroll
    for (int j = 0; j < 4; ++j) acc[j] = b4[tid + 256 * j];
    for (int i = 0; i < 1024; ++i) {
      float xv = xb[i];
      const float* wrow = w4 + (size_t)i * 1024;
#pragma unroll
      for (int j = 0; j < 4; ++j) acc[j] = fmaf(xv, wrow[tid + 256 * j], acc[j]);
    }
#pragma unroll
    for (int j = 0; j < 4; ++j) hbuf[tid + 256 * j] = fmaxf(acc[j], 0.f);
  }
  __syncthreads();
  {
    float acc[2];
#pragma unroll
    for (int j = 0; j < 2; ++j) acc[j] = b5[tid + 256 * j];
    for (int i = 0; i < 1024; ++i) {
      float xv = hbuf[i];
      const float* wrow = w5 + (size_t)i * 512;
#pragma unroll
      for (int j = 0; j < 2; ++j) acc[j] = fmaf(xv, wrow[tid + 256 * j], acc[j]);
    }
#pragma unroll
    for (int j = 0; j < 2; ++j) out[(size_t)b * 512 + tid + 256 * j] = acc[j];
  }
}

// ----------------------------------------------------------------
extern "C" void kernel_launch(void* const* d_in, const int* in_sizes, int n_in,
                              void* d_out, int out_size, void* d_ws, size_t ws_size,
                              hipStream_t stream) {
  (void)in_sizes; (void)n_in; (void)out_size;
  const float* x = (const float*)d_in[0];
  const float* w1 = (const float*)d_in[1];  const float* b1 = (const float*)d_in[2];
  const float* w2 = (const float*)d_in[3];  const float* b2 = (const float*)d_in[4];
  const float* w3 = (const float*)d_in[5];  const float* b3 = (const float*)d_in[6];
  const float* g1lw = (const float*)d_in[7];  const float* g1lb = (const float*)d_in[8];
  const float* g1cw = (const float*)d_in[9];  const float* g1cb = (const float*)d_in[10];
  const float* g2lw = (const float*)d_in[11]; const float* g2lb = (const float*)d_in[12];
  const float* g2cw = (const float*)d_in[13]; const float* g2cb = (const float*)d_in[14];
  const float* w4 = (const float*)d_in[15]; const float* b4 = (const float*)d_in[16];
  const float* w5 = (const float*)d_in[17]; const float* b5 = (const float*)d_in[18];
  const float* bn1g = (const float*)d_in[19]; const float* bn1b = (const float*)d_in[20];
  const float* bn1m = (const float*)d_in[21]; const float* bn1v = (const float*)d_in[22];
  const float* bn2g = (const float*)d_in[23]; const float* bn2b = (const float*)d_in[24];
  const float* bn2m = (const float*)d_in[25]; const float* bn2v = (const float*)d_in[26];
  const float* bn3g = (const float*)d_in[27]; const float* bn3b = (const float*)d_in[28];
  const float* bn3m = (const float*)d_in[29]; const float* bn3v = (const float*)d_in[30];

  float* ws = (float*)d_ws;
  size_t off = 0;
  auto alloc = [&](size_t n) { float* p = ws + off; off += (n + 63) & ~(size_t)63; return p; };
  float* slotA = alloc(16u * 2048 * 128);   // h0 then h4 f32
  float* slotB = alloc(16u * 2048 * 64);    // h3 f32
  float* sqv  = alloc(16u * 2048);
  unsigned short* hi_h = (unsigned short*)alloc(16u * 2048 * 64);  // h planes (stride 64 then 128)
  unsigned short* lo_h = (unsigned short*)alloc(16u * 2048 * 64);
  unsigned short* mhi = (unsigned short*)alloc(16u * 2048 * 64);   // gather-max planes
  unsigned short* mlo = (unsigned short*)alloc(16u * 2048 * 64);
  unsigned short* wthi = (unsigned short*)alloc(65536);            // W^T planes (max 1024x128)
  unsigned short* wtlo = (unsigned short*)alloc(65536);
  float* bc   = alloc(1024);
  float* P    = alloc(512u * 1024);
  float* gm   = alloc(16u * 1024);
  int CH = 8;
  while (CH > 1 && (off + (size_t)CH * NPTS * NPTS + 64) * 4 > ws_size) CH >>= 1;
  float* Dot = alloc((size_t)CH * NPTS * NPTS);

  // 1: knn on xyz + covariance -> h0[B,N,12]
  k_knn1_cov<<<dim3(512, 16), 256, 0, stream>>>(x, slotA);
  // 2: MLP1 -> h3 f32 + bf16 planes
  k_mlp1<<<512, 256, 0, stream>>>(slotA, w1, b1, w2, b2, w3, b3,
                                  bn1g, bn1b, bn1m, bn1v,
                                  bn2g, bn2b, bn2m, bn2v,
                                  bn3g, bn3b, bn3m, bn3v, slotB, hi_h, lo_h);
  // 3: knn(64) via MFMA + select -> m1 planes
  k_sqnorm<64><<<128, 256, 0, stream>>>(slotB, sqv);
  for (int c = 0; c < 16; c += CH) {
    int ch = (16 - c) < CH ? (16 - c) : CH;
    k_dgemm<64><<<dim3(32, 16, ch), 256, 0, stream>>>(hi_h, lo_h, sqv, Dot, c);
    k_select<64><<<dim3(512, ch), 256, 0, stream>>>(Dot, slotB, mhi, mlo, c);
  }
  // 4: g1 combined dense 64->128 + relu -> h4 f32 + planes (MFMA)
  k_combine_t<<<32, 256, 0, stream>>>(g1lw, g1lb, g1cw, g1cb, wthi, wtlo, bc, 64, 128);
  k_apply_mfma<64, 128, true, false><<<dim3(512, 1), 256, 0, stream>>>(
      mhi, mlo, wthi, wtlo, bc, slotA, hi_h, lo_h);
  // 5: knn(128) via MFMA + select -> m2 planes
  k_sqnorm<128><<<128, 256, 0, stream>>>(slotA, sqv);
  for (int c = 0; c < 16; c += CH) {
    int ch = (16 - c) < CH ? (16 - c) : CH;
    k_dgemm<128><<<dim3(32, 16, ch), 256, 0, stream>>>(hi_h, lo_h, sqv, Dot, c);
    k_select<128><<<dim3(512, ch), 256, 0, stream>>>(Dot, slotA, mhi, mlo, c);
  }
  // 6: g2 combined dense 128->1024 + colmax -> P (MFMA)
  k_combine_t<<<512, 256, 0, stream>>>(g2lw, g2lb, g2cw, g2cb, wthi, wtlo, bc, 128, 1024);
  k_apply_mfma<128, 1024, false, true><<<dim3(512, 8), 256, 0, stream>>>(
      mhi, mlo, wthi, wtlo, bc, P, nullptr, nullptr);
  // 7: reduce -> gmax[16][1024]
  k_reduce_max<<<16, 256, 0, stream>>>(P, gm);
  // 8: head -> out[16][512]
  k_head<<<16, 256, 0, stream>>>(gm, w4, b4, w5, b5, (float*)d_out);
}

// Round 8
// 1116.356 us; speedup vs baseline: 2.3954x; 1.0009x over previous
//
#include <hip/hip_runtime.h>
#include <cstddef>
#include <cstdint>

#define NPTS 2048

typedef short bf16x8 __attribute__((ext_vector_type(8)));
typedef float f32x4 __attribute__((ext_vector_type(4)));

__device__ __forceinline__ unsigned short f2bf(float f) {
  unsigned u = __builtin_bit_cast(unsigned, f);
  unsigned r = u + 0x7fffu + ((u >> 16) & 1u);  // RNE (finite inputs)
  return (unsigned short)(r >> 16);
}
__device__ __forceinline__ float bf2f(unsigned short s) {
  unsigned u = ((unsigned)s) << 16;
  return __builtin_bit_cast(float, u);
}
// float -> order-preserving u32 (handles negatives)
__device__ __forceinline__ unsigned f2sort(float f) {
  unsigned u = __builtin_bit_cast(unsigned, f);
  return u ^ (unsigned)(((int)u >> 31) | 0x80000000);
}

// sorted-4 pool insert (ascending); keys unique
__device__ __forceinline__ void pool_insert(uint64_t k, uint64_t& s0, uint64_t& s1,
                                            uint64_t& s2, uint64_t& s3) {
  s3 = k < s3 ? k : s3;
  uint64_t t;
  t = s2 < s3 ? s2 : s3; s3 = s2 < s3 ? s3 : s2; s2 = t;
  t = s1 < s2 ? s1 : s2; s2 = s1 < s2 ? s2 : s1; s1 = t;
  t = s0 < s1 ? s0 : s1; s1 = s0 < s1 ? s1 : s0; s0 = t;
}

// one extraction round: returns wave-uniform winning m (low 32 of min key)
__device__ __forceinline__ unsigned pool_extract(uint64_t& s0, uint64_t& s1,
                                                 uint64_t& s2, uint64_t& s3, int lane,
                                                 int& cnt) {
  unsigned h32 = (unsigned)(s0 >> 32);
  unsigned wmin = h32;
#pragma unroll
  for (int s = 1; s < 64; s <<= 1)
    wmin = min(wmin, (unsigned)__shfl_xor((int)wmin, s, 64));
  bool own = (h32 == wmin);
  unsigned long long bal = __ballot(own);
  unsigned lo = (unsigned)s0;
  unsigned wlo;
  if (__popcll(bal) > 1) {  // hi-tie (rare): resolve by low word (index)
    unsigned lo2 = own ? lo : 0xFFFFFFFFu;
#pragma unroll
    for (int s = 1; s < 64; s <<= 1)
      lo2 = min(lo2, (unsigned)__shfl_xor((int)lo2, s, 64));
    wlo = lo2;
  } else {
    int owner = __ffsll((unsigned long long)bal) - 1;
    wlo = (unsigned)__shfl((int)lo, owner, 64);
  }
  bool ex = own && (lo == wlo);
  cnt += ex ? 1 : 0;
  s0 = ex ? s1 : s0; s1 = ex ? s2 : s1; s2 = ex ? s3 : s2; s3 = ex ? ~0ull : s3;
  return wlo;
}

// ---------------------------------------------------------------- knn1 + cov (1 query per wave)
__global__ __launch_bounds__(256) void k_knn1_cov(const float* __restrict__ x,
                                                  float* __restrict__ h0) {
  const int b = blockIdx.y;
  const int tid = threadIdx.x;
  const int lane = tid & 63;
  const int w = tid >> 6;
  __shared__ float4 xsq[NPTS];
  const float* xb = x + (size_t)b * NPTS * 3;
  for (int i = tid; i < NPTS; i += 256) {
    float a0 = xb[3 * i], a1 = xb[3 * i + 1], a2 = xb[3 * i + 2];
    xsq[i] = make_float4(a0, a1, a2, fmaf(a0, a0, fmaf(a1, a1, a2 * a2)));
  }
  __syncthreads();
  const int nq = blockIdx.x * 4 + w;
  const float4 q4 = xsq[nq];
  const float sqq = q4.w;
  float d[32];
  uint64_t s0 = ~0ull, s1 = ~0ull, s2 = ~0ull, s3 = ~0ull;
#pragma unroll
  for (int j = 0; j < 32; ++j) {
    float4 v = xsq[j * 64 + lane];
    float dot = q4.x * v.x;
    dot = fmaf(q4.y, v.y, dot);
    dot = fmaf(q4.z, v.z, dot);
    float dd = fmaf(-2.f, dot, sqq + v.w);
    d[j] = dd;
    uint64_t k = ((uint64_t)f2sort(dd) << 32) | (unsigned)(j * 64 + lane);
    pool_insert(k, s0, s1, s2, s3);
  }
  int widx[16];
  int cnt = 0;
#pragma unroll
  for (int r = 0; r < 16; ++r)
    widx[r] = (int)pool_extract(s0, s1, s2, s3, lane, cnt);
  if (__ballot(cnt == 4) != 0ull) {  // rare exact fallback
    unsigned mask = 0;
#pragma unroll
    for (int r = 0; r < 16; ++r) {
      float vmin = 3.4e38f;
      int mmin = 0x7fffffff;
#pragma unroll
      for (int j = 0; j < 32; ++j) {
        bool ok = !((mask >> j) & 1u) && (d[j] < vmin);
        if (ok) { vmin = d[j]; mmin = j * 64 + lane; }
      }
#pragma unroll
      for (int s = 1; s < 64; s <<= 1) {
        float ov = __shfl_xor(vmin, s, 64);
        int om = __shfl_xor(mmin, s, 64);
        if (ov < vmin || (ov == vmin && om < mmin)) { vmin = ov; mmin = om; }
      }
      widx[r] = mmin;
      if (lane == (mmin & 63)) mask |= 1u << (mmin >> 6);
    }
  }
  // two-pass mean/cov (wave-uniform broadcast reads)
  float sx = 0, sy = 0, sz = 0;
#pragma unroll
  for (int r = 0; r < 16; ++r) {
    float4 v = xsq[widx[r]];
    sx += v.x; sy += v.y; sz += v.z;
  }
  const float mx = sx * 0.0625f, my = sy * 0.0625f, mz = sz * 0.0625f;
  float cxx = 0, cxy = 0, cxz = 0, cyy = 0, cyz = 0, czz = 0;
#pragma unroll
  for (int r = 0; r < 16; ++r) {
    float4 v = xsq[widx[r]];
    float ax = v.x - mx, ay = v.y - my, az = v.z - mz;
    cxx = fmaf(ax, ax, cxx); cxy = fmaf(ax, ay, cxy); cxz = fmaf(ax, az, cxz);
    cyy = fmaf(ay, ay, cyy); cyz = fmaf(ay, az, cyz); czz = fmaf(az, az, czz);
  }
  if (lane == 0) {
    float* o = h0 + ((size_t)b * NPTS + nq) * 12;
    *(float4*)&o[0] = make_float4(q4.x, q4.y, q4.z, cxx);
    *(float4*)&o[4] = make_float4(cxy, cxz, cxy, cyy);
    *(float4*)&o[8] = make_float4(cyz, cxz, cyz, czz);
  }
}

// ---------------------------------------------------------------- MLP1 (12->12->64->64, BN folded) + bf16 plane epilogue
__global__ __launch_bounds__(256) void k_mlp1(
    const float* __restrict__ h0,
    const float* __restrict__ w1, const float* __restrict__ cb1,
    const float* __restrict__ w2, const float* __restrict__ cb2,
    const float* __restrict__ w3, const float* __restrict__ cb3,
    const float* __restrict__ bn1g, const float* __restrict__ bn1b,
    const float* __restrict__ bn1m, const float* __restrict__ bn1v,
    const float* __restrict__ bn2g, const float* __restrict__ bn2b,
    const float* __restrict__ bn2m, const float* __restrict__ bn2v,
    const float* __restrict__ bn3g, const float* __restrict__ bn3b,
    const float* __restrict__ bn3m, const float* __restrict__ bn3v,
    float* __restrict__ h3out,
    unsigned short* __restrict__ h3hi, unsigned short* __restrict__ h3lo) {
  __shared__ float W1[144], W2[768], W3[4096];
  __shared__ float S1[12], F1[12], S2[64], F2[64], S3[64], F3[64];
  __shared__ float h0s[64][12];
  __shared__ float A2[64][65];
  const int tid = threadIdx.x;
  for (int i = tid; i < 144; i += 256) W1[i] = w1[i];
  for (int i = tid; i < 768; i += 256) W2[i] = w2[i];
  for (int i = tid; i < 4096; i += 256) W3[i] = w3[i];
  if (tid < 12) {
    float s = bn1g[tid] * rsqrtf(bn1v[tid] + 1e-3f);
    S1[tid] = s; F1[tid] = (cb1[tid] - bn1m[tid]) * s + bn1b[tid];
  }
  if (tid < 64) {
    float s2 = bn2g[tid] * rsqrtf(bn2v[tid] + 1e-3f);
    S2[tid] = s2; F2[tid] = (cb2[tid] - bn2m[tid]) * s2 + bn2b[tid];
    float s3 = bn3g[tid] * rsqrtf(bn3v[tid] + 1e-3f);
    S3[tid] = s3; F3[tid] = (cb3[tid] - bn3m[tid]) * s3 + bn3b[tid];
  }
  const int p0 = blockIdx.x * 64;
  for (int i = tid; i < 64 * 12; i += 256)
    h0s[i / 12][i % 12] = h0[(size_t)p0 * 12 + i];
  __syncthreads();
  const int pl = tid >> 2;
  const int q = tid & 3;
  float v1[12];
#pragma unroll
  for (int o = 0; o < 12; ++o) {
    float a = 0.f;
#pragma unroll
    for (int i = 0; i < 12; ++i) a = fmaf(h0s[pl][i], W1[i * 12 + o], a);
    v1[o] = fmaxf(fmaf(a, S1[o], F1[o]), 0.f);
  }
#pragma unroll
  for (int o = 0; o < 16; ++o) {
    int oo = q * 16 + o;
    float a = 0.f;
#pragma unroll
    for (int i = 0; i < 12; ++i) a = fmaf(v1[i], W2[i * 64 + oo], a);
    A2[pl][oo] = fmaxf(fmaf(a, S2[oo], F2[oo]), 0.f);
  }
  __syncthreads();
  float acc[16];
#pragma unroll
  for (int o = 0; o < 16; ++o) acc[o] = 0.f;
  for (int i = 0; i < 64; ++i) {
    float xv = A2[pl][i];
#pragma unroll
    for (int o = 0; o < 16; ++o) acc[o] = fmaf(xv, W3[i * 64 + q * 16 + o], acc[o]);
  }
  float vals[16];
#pragma unroll
  for (int o = 0; o < 16; ++o) {
    int oo = q * 16 + o;
    vals[o] = fmaxf(fmaf(acc[o], S3[oo], F3[oo]), 0.f);
  }
  const size_t rowo = (size_t)(p0 + pl) * 64 + q * 16;
  float* orow = h3out + rowo;
#pragma unroll
  for (int o4 = 0; o4 < 4; ++o4)
    *(float4*)&orow[4 * o4] = make_float4(vals[4 * o4], vals[4 * o4 + 1],
                                          vals[4 * o4 + 2], vals[4 * o4 + 3]);
  bf16x8 hv0, hv1, lv0, lv1;
#pragma unroll
  for (int o = 0; o < 8; ++o) {
    unsigned short hb = f2bf(vals[o]);
    hv0[o] = (short)hb; lv0[o] = (short)f2bf(vals[o] - bf2f(hb));
    unsigned short hb1 = f2bf(vals[8 + o]);
    hv1[o] = (short)hb1; lv1[o] = (short)f2bf(vals[8 + o] - bf2f(hb1));
  }
  *(bf16x8*)&h3hi[rowo] = hv0; *(bf16x8*)&h3hi[rowo + 8] = hv1;
  *(bf16x8*)&h3lo[rowo] = lv0; *(bf16x8*)&h3lo[rowo + 8] = lv1;
}

// ---------------------------------------------------------------- sq norms
template <int C>
__global__ __launch_bounds__(256) void k_sqnorm(const float* __restrict__ h,
                                                float* __restrict__ sq) {
  const int p = blockIdx.x * 256 + threadIdx.x;
  const float* row = h + (size_t)p * C;
  float a = 0.f;
#pragma unroll
  for (int i = 0; i < C; ++i) a = fmaf(row[i], row[i], a);
  sq[p] = a;
}

// ---------------------------------------------------------------- FUSED knn: MFMA distances -> LDS -> pool select -> gather-max planes
// block: 512 thr / 8 waves; 16 queries; full 2048 candidates. LDS 128 KiB.
template <int C>
__global__ __launch_bounds__(512, 1) void k_knn_fused(
    const unsigned short* __restrict__ hi, const unsigned short* __restrict__ lo,
    const float* __restrict__ sq, const float* __restrict__ h,
    unsigned short* __restrict__ mhi, unsigned short* __restrict__ mlo) {
  __shared__ float dmat[16][NPTS];  // 128 KiB
  const int tid = threadIdx.x, lane = tid & 63, w = tid >> 6;
  const int b = blockIdx.y;
  const int q0 = blockIdx.x * 16;
  const size_t base = (size_t)b * NPTS * C;
  const float* __restrict__ sqb = sq + (size_t)b * NPTS;
  const int r = lane & 15, ks = (lane >> 4) * 8;
  const unsigned short* Ah = hi + base + (size_t)(q0 + r) * C + ks;
  const unsigned short* Al = lo + base + (size_t)(q0 + r) * C + ks;
  float sqq[4];
#pragma unroll
  for (int r2 = 0; r2 < 4; ++r2) sqq[r2] = sqb[q0 + (lane >> 4) * 4 + r2];

  // ---- phase 1: distances (identical MFMA order to proven k_dgemm)
#pragma unroll
  for (int mt = 0; mt < 2; ++mt) {
    const int m0 = (w * 2 + mt) * 128;
    const unsigned short* Bh = hi + base + (size_t)(m0 + r) * C + ks;
    const unsigned short* Bl = lo + base + (size_t)(m0 + r) * C + ks;
    f32x4 acc[8];
#pragma unroll
    for (int s = 0; s < 8; ++s) acc[s] = (f32x4){0.f, 0.f, 0.f, 0.f};
#pragma unroll
    for (int kk = 0; kk < C; kk += 32) {
      bf16x8 ah = *(const bf16x8*)(Ah + kk);
      bf16x8 al = *(const bf16x8*)(Al + kk);
#pragma unroll
      for (int s = 0; s < 8; ++s) {
        bf16x8 bh = *(const bf16x8*)(Bh + (size_t)s * 16 * C + kk);
        bf16x8 bl = *(const bf16x8*)(Bl + (size_t)s * 16 * C + kk);
        acc[s] = __builtin_amdgcn_mfma_f32_16x16x32_bf16(ah, bh, acc[s], 0, 0, 0);
        acc[s] = __builtin_amdgcn_mfma_f32_16x16x32_bf16(ah, bl, acc[s], 0, 0, 0);
        acc[s] = __builtin_amdgcn_mfma_f32_16x16x32_bf16(al, bh, acc[s], 0, 0, 0);
      }
    }
#pragma unroll
    for (int s = 0; s < 8; ++s) {
      const int col = m0 + s * 16 + (lane & 15);
      float smc = sqb[col];
#pragma unroll
      for (int r2 = 0; r2 < 4; ++r2)
        dmat[(lane >> 4) * 4 + r2][col] = fmaf(-2.f, acc[s][r2], sqq[r2] + smc);
    }
  }
  __syncthreads();

  // ---- phase 2: pool select + gather (2 queries per wave)
  const float* __restrict__ hbp = h + base;
#pragma unroll 1
  for (int qi = 0; qi < 2; ++qi) {
    const int ql = w * 2 + qi;
    const int q = q0 + ql;
    float d[32];
    uint64_t s0 = ~0ull, s1 = ~0ull, s2 = ~0ull, s3 = ~0ull;
#pragma unroll
    for (int t = 0; t < 8; ++t) {
      float4 dv = *(const float4*)&dmat[ql][t * 256 + 4 * lane];
      d[4 * t + 0] = dv.x; d[4 * t + 1] = dv.y;
      d[4 * t + 2] = dv.z; d[4 * t + 3] = dv.w;
    }
#pragma unroll
    for (int j = 0; j < 32; ++j) {
      unsigned m = (unsigned)((j >> 2) * 256 + 4 * lane + (j & 3));
      uint64_t k = ((uint64_t)f2sort(d[j]) << 32) | m;
      pool_insert(k, s0, s1, s2, s3);
    }
    int cnt = 0;
    float g0 = -3.4e38f, g1 = -3.4e38f;
#pragma unroll
    for (int rr = 0; rr < 16; ++rr) {
      unsigned m = pool_extract(s0, s1, s2, s3, lane, cnt);
      const float* row = hbp + (size_t)m * C;
      g0 = fmaxf(g0, row[lane]);
      if (C == 128) g1 = fmaxf(g1, row[64 + lane]);
    }
    if (__ballot(cnt == 4) != 0ull) {  // rare exact fallback
      unsigned mask = 0u;
      g0 = -3.4e38f; g1 = -3.4e38f;
#pragma unroll 1
      for (int rr = 0; rr < 16; ++rr) {
        float vmin = 3.4e38f;
        int mmin = 0x7fffffff;
#pragma unroll
        for (int j = 0; j < 32; ++j) {
          const int m = (j >> 2) * 256 + 4 * lane + (j & 3);
          bool ok = !((mask >> j) & 1u) && (d[j] < vmin);
          if (ok) { vmin = d[j]; mmin = m; }
        }
#pragma unroll
        for (int s = 1; s < 64; s <<= 1) {
          float ov = __shfl_xor(vmin, s, 64);
          int om = __shfl_xor(mmin, s, 64);
          if (ov < vmin || (ov == vmin && om < mmin)) { vmin = ov; mmin = om; }
        }
        if (lane == ((mmin >> 2) & 63)) mask |= 1u << (((mmin >> 8) << 2) | (mmin & 3));
        const float* row = hbp + (size_t)mmin * C;
        g0 = fmaxf(g0, row[lane]);
        if (C == 128) g1 = fmaxf(g1, row[64 + lane]);
      }
    }
    const size_t orow = base + (size_t)q * C;
    unsigned short h0b = f2bf(g0);
    mhi[orow + lane] = h0b;
    mlo[orow + lane] = f2bf(g0 - bf2f(h0b));
    if (C == 128) {
      unsigned short h1b = f2bf(g1);
      mhi[orow + 64 + lane] = h1b;
      mlo[orow + 64 + lane] = f2bf(g1 - bf2f(h1b));
    }
  }
}

// ---------------------------------------------------------------- combine denses -> W^T bf16 planes + bias
__global__ __launch_bounds__(256) void k_combine_t(const float* __restrict__ lw,
                                                   const float* __restrict__ lb,
                                                   const float* __restrict__ cw,
                                                   const float* __restrict__ cb,
                                                   unsigned short* __restrict__ wthi,
                                                   unsigned short* __restrict__ wtlo,
                                                   float* __restrict__ bc, int K, int M) {
  const int id = blockIdx.x * 256 + threadIdx.x;
  if (id < K * M) {
    int i = id / M, o = id % M;
    float a = 0.f;
    for (int k = 0; k < K; ++k) a = fmaf(lw[i * K + k], cw[k * M + o], a);
    unsigned short hb = f2bf(a);
    wthi[(size_t)o * K + i] = hb;
    wtlo[(size_t)o * K + i] = f2bf(a - bf2f(hb));
  }
  if (id < M) {
    float a = cb[id];
    for (int k = 0; k < K; ++k) a = fmaf(lb[k], cw[k * M + id], a);
    bc[id] = a;
  }
}

// ---------------------------------------------------------------- MFMA apply: out = A[32768,K]*W[K,M]+bias, RELU->f32+planes | COLMAX->P
template <int K, int M, bool RELU, bool COLMAX>
__global__ __launch_bounds__(256) void k_apply_mfma(
    const unsigned short* __restrict__ Ah, const unsigned short* __restrict__ Al,
    const unsigned short* __restrict__ Wh, const unsigned short* __restrict__ Wl,
    const float* __restrict__ bias, float* __restrict__ fout,
    unsigned short* __restrict__ phi, unsigned short* __restrict__ plo) {
  __shared__ float cm[4][128];
  const int tid = threadIdx.x, lane = tid & 63, w = tid >> 6;
  const int rt = blockIdx.x;
  const int q0 = rt * 64 + w * 16;
  const int m0 = blockIdx.y * 128;
  const int r = lane & 15, ks = (lane >> 4) * 8;
  const unsigned short* ap_h = Ah + (size_t)(q0 + r) * K + ks;
  const unsigned short* ap_l = Al + (size_t)(q0 + r) * K + ks;
  const unsigned short* bp_h = Wh + (size_t)(m0 + r) * K + ks;
  const unsigned short* bp_l = Wl + (size_t)(m0 + r) * K + ks;
  f32x4 acc[8];
#pragma unroll
  for (int mt = 0; mt < 8; ++mt) acc[mt] = (f32x4){0.f, 0.f, 0.f, 0.f};
#pragma unroll
  for (int kk = 0; kk < K; kk += 32) {
    bf16x8 ah = *(const bf16x8*)(ap_h + kk);
    bf16x8 al = *(const bf16x8*)(ap_l + kk);
#pragma unroll
    for (int mt = 0; mt < 8; ++mt) {
      bf16x8 bh = *(const bf16x8*)(bp_h + (size_t)mt * 16 * K + kk);
      bf16x8 bl = *(const bf16x8*)(bp_l + (size_t)mt * 16 * K + kk);
      acc[mt] = __builtin_amdgcn_mfma_f32_16x16x32_bf16(ah, bh, acc[mt], 0, 0, 0);
      acc[mt] = __builtin_amdgcn_mfma_f32_16x16x32_bf16(ah, bl, acc[mt], 0, 0, 0);
      acc[mt] = __builtin_amdgcn_mfma_f32_16x16x32_bf16(al, bh, acc[mt], 0, 0, 0);
    }
  }
  if (RELU) {
#pragma unroll
    for (int mt = 0; mt < 8; ++mt) {
      const int col = m0 + mt * 16 + (lane & 15);
      const float bv = bias[col];
#pragma unroll
      for (int r2 = 0; r2 < 4; ++r2) {
        const int row = q0 + (lane >> 4) * 4 + r2;
        float v = fmaxf(acc[mt][r2] + bv, 0.f);
        const size_t idx = (size_t)row * M + col;
        fout[idx] = v;
        unsigned short hb = f2bf(v);
        phi[idx] = hb;
        plo[idx] = f2bf(v - bf2f(hb));
      }
    }
  }
  if (COLMAX) {
#pragma unroll
    for (int mt = 0; mt < 8; ++mt) {
      float v = fmaxf(fmaxf(acc[mt][0], acc[mt][1]), fmaxf(acc[mt][2], acc[mt][3]));
      v = fmaxf(v, __shfl_xor(v, 16, 64));
      v = fmaxf(v, __shfl_xor(v, 32, 64));
      cm[w][mt * 16 + (lane & 15)] = v;
    }
    __syncthreads();
    if (tid < 128) {
      float m = fmaxf(fmaxf(cm[0][tid], cm[1][tid]), fmaxf(cm[2][tid], cm[3][tid]));
      fout[(size_t)rt * M + m0 + tid] = m + bias[m0 + tid];
    }
  }
}

// ---------------------------------------------------------------- reduce P[512][1024] -> gmax[16][1024]
__global__ __launch_bounds__(256) void k_reduce_max(const float* __restrict__ P,
                                                    float* __restrict__ gmax) {
  const int b = blockIdx.x, tid = threadIdx.x;
  for (int c = tid; c < 1024; c += 256) {
    float m = P[(size_t)(b * 32) * 1024 + c];
    for (int rt = 1; rt < 32; ++rt)
      m = fmaxf(m, P[(size_t)(b * 32 + rt) * 1024 + c]);
    gmax[b * 1024 + c] = m;
  }
}

// ---------------------------------------------------------------- head part 1: hid = relu(gmax*W4+b4), parallel over (colblock, batch)
__global__ __launch_bounds__(256) void k_head1(const float* __restrict__ gmax,
                                               const float* __restrict__ w4,
                                               const float* __restrict__ b4,
                                               float* __restrict__ hid) {
  const int b = blockIdx.y, c0 = blockIdx.x * 64;
  const int tid = threadIdx.x;
  const int c = tid & 63, iq = tid >> 6;
  __shared__ float xs[1024];
  __shared__ float red[4][64];
  for (int i = tid; i < 1024; i += 256) xs[i] = gmax[b * 1024 + i];
  __syncthreads();
  float a = 0.f;
  for (int i = iq * 256; i < iq * 256 + 256; ++i)
    a = fmaf(xs[i], w4[(size_t)i * 1024 + c0 + c], a);
  red[iq][c] = a;
  __syncthreads();
  if (tid < 64) {
    float v = red[0][tid] + red[1][tid] + red[2][tid] + red[3][tid];
    hid[b * 1024 + c0 + tid] = fmaxf(v + b4[c0 + tid], 0.f);
  }
}

// ---------------------------------------------------------------- head part 2: out = hid*W5+b5
__global__ __launch_bounds__(256) void k_head2(const float* __restrict__ hid,
                                               const float* __restrict__ w5,
                                               const float* __restrict__ b5,
                                               float* __restrict__ out) {
  const int b = blockIdx.y, c0 = blockIdx.x * 64;
  const int tid = threadIdx.x;
  const int c = tid & 63, iq = tid >> 6;
  __shared__ float xs[1024];
  __shared__ float red[4][64];
  for (int i = tid; i < 1024; i += 256) xs[i] = hid[b * 1024 + i];
  __syncthreads();
  float a = 0.f;
  for (int i = iq * 256; i < iq * 256 + 256; ++i)
    a = fmaf(xs[i], w5[(size_t)i * 512 + c0 + c], a);
  red[iq][c] = a;
  __syncthreads();
  if (tid < 64) {
    float v = red[0][tid] + red[1][tid] + red[2][tid] + red[3][tid];
    out[(size_t)b * 512 + c0 + tid] = v + b5[c0 + tid];
  }
}

// ----------------------------------------------------------------
extern "C" void kernel_launch(void* const* d_in, const int* in_sizes, int n_in,
                              void* d_out, int out_size, void* d_ws, size_t ws_size,
                              hipStream_t stream) {
  (void)in_sizes; (void)n_in; (void)out_size; (void)ws_size;
  const float* x = (const float*)d_in[0];
  const float* w1 = (const float*)d_in[1];  const float* b1 = (const float*)d_in[2];
  const float* w2 = (const float*)d_in[3];  const float* b2 = (const float*)d_in[4];
  const float* w3 = (const float*)d_in[5];  const float* b3 = (const float*)d_in[6];
  const float* g1lw = (const float*)d_in[7];  const float* g1lb = (const float*)d_in[8];
  const float* g1cw = (const float*)d_in[9];  const float* g1cb = (const float*)d_in[10];
  const float* g2lw = (const float*)d_in[11]; const float* g2lb = (const float*)d_in[12];
  const float* g2cw = (const float*)d_in[13]; const float* g2cb = (const float*)d_in[14];
  const float* w4 = (const float*)d_in[15]; const float* b4 = (const float*)d_in[16];
  const float* w5 = (const float*)d_in[17]; const float* b5 = (const float*)d_in[18];
  const float* bn1g = (const float*)d_in[19]; const float* bn1b = (const float*)d_in[20];
  const float* bn1m = (const float*)d_in[21]; const float* bn1v = (const float*)d_in[22];
  const float* bn2g = (const float*)d_in[23]; const float* bn2b = (const float*)d_in[24];
  const float* bn2m = (const float*)d_in[25]; const float* bn2v = (const float*)d_in[26];
  const float* bn3g = (const float*)d_in[27]; const float* bn3b = (const float*)d_in[28];
  const float* bn3m = (const float*)d_in[29]; const float* bn3v = (const float*)d_in[30];

  float* ws = (float*)d_ws;
  size_t off = 0;
  auto alloc = [&](size_t n) { float* p = ws + off; off += (n + 63) & ~(size_t)63; return p; };
  float* slotA = alloc(16u * 2048 * 128);   // h0 then h4 f32
  float* slotB = alloc(16u * 2048 * 64);    // h3 f32
  float* sqv  = alloc(16u * 2048);
  unsigned short* hi_h = (unsigned short*)alloc(16u * 2048 * 64);  // h planes (stride 64 then 128)
  unsigned short* lo_h = (unsigned short*)alloc(16u * 2048 * 64);
  unsigned short* mhi = (unsigned short*)alloc(16u * 2048 * 64);   // gather-max planes
  unsigned short* mlo = (unsigned short*)alloc(16u * 2048 * 64);
  unsigned short* wthi = (unsigned short*)alloc(65536);            // W^T planes (max 1024x128)
  unsigned short* wtlo = (unsigned short*)alloc(65536);
  float* bc   = alloc(1024);
  float* P    = alloc(512u * 1024);
  float* gm   = alloc(16u * 1024);
  float* hid  = alloc(16u * 1024);

  // 1: knn on xyz + covariance -> h0[B,N,12]
  k_knn1_cov<<<dim3(512, 16), 256, 0, stream>>>(x, slotA);
  // 2: MLP1 -> h3 f32 + bf16 planes
  k_mlp1<<<512, 256, 0, stream>>>(slotA, w1, b1, w2, b2, w3, b3,
                                  bn1g, bn1b, bn1m, bn1v,
                                  bn2g, bn2b, bn2m, bn2v,
                                  bn3g, bn3b, bn3m, bn3v, slotB, hi_h, lo_h);
  // 3: knn(64) fused -> m1 planes
  k_sqnorm<64><<<128, 256, 0, stream>>>(slotB, sqv);
  k_knn_fused<64><<<dim3(128, 16), 512, 0, stream>>>(hi_h, lo_h, sqv, slotB, mhi, mlo);
  // 4: g1 combined dense 64->128 + relu -> h4 f32 + planes (MFMA)
  k_combine_t<<<32, 256, 0, stream>>>(g1lw, g1lb, g1cw, g1cb, wthi, wtlo, bc, 64, 128);
  k_apply_mfma<64, 128, true, false><<<dim3(512, 1), 256, 0, stream>>>(
      mhi, mlo, wthi, wtlo, bc, slotA, hi_h, lo_h);
  // 5: knn(128) fused -> m2 planes
  k_sqnorm<128><<<128, 256, 0, stream>>>(slotA, sqv);
  k_knn_fused<128><<<dim3(128, 16), 512, 0, stream>>>(hi_h, lo_h, sqv, slotA, mhi, mlo);
  // 6: g2 combined dense 128->1024 + colmax -> P (MFMA)
  k_combine_t<<<512, 256, 0, stream>>>(g2lw, g2lb, g2cw, g2cb, wthi, wtlo, bc, 128, 1024);
  k_apply_mfma<128, 1024, false, true><<<dim3(512, 8), 256, 0, stream>>>(
      mhi, mlo, wthi, wtlo, bc, P, nullptr, nullptr);
  // 7: reduce -> gmax[16][1024]
  k_reduce_max<<<16, 256, 0, stream>>>(P, gm);
  // 8: head -> out[16][512]
  k_head1<<<dim3(16, 16), 256, 0, stream>>>(gm, w4, b4, hid);
  k_head2<<<dim3(8, 16), 256, 0, stream>>>(hid, w5, b5, (float*)d_out);
}

// Round 9
// 1047.377 us; speedup vs baseline: 2.5532x; 1.0659x over previous
//
#include <hip/hip_runtime.h>
#include <cstddef>
#include <cstdint>

#define NPTS 2048

typedef short bf16x8 __attribute__((ext_vector_type(8)));
typedef float f32x4 __attribute__((ext_vector_type(4)));

__device__ __forceinline__ unsigned short f2bf(float f) {
  unsigned u = __builtin_bit_cast(unsigned, f);
  unsigned r = u + 0x7fffu + ((u >> 16) & 1u);  // RNE (finite inputs)
  return (unsigned short)(r >> 16);
}
__device__ __forceinline__ float bf2f(unsigned short s) {
  unsigned u = ((unsigned)s) << 16;
  return __builtin_bit_cast(float, u);
}
// float -> order-preserving u32 (handles negatives)
__device__ __forceinline__ unsigned f2sort(float f) {
  unsigned u = __builtin_bit_cast(unsigned, f);
  return u ^ (unsigned)(((int)u >> 31) | 0x80000000);
}

// sorted-4 pool insert (ascending); keys unique
__device__ __forceinline__ void pool_insert(uint64_t k, uint64_t& s0, uint64_t& s1,
                                            uint64_t& s2, uint64_t& s3) {
  s3 = k < s3 ? k : s3;
  uint64_t t;
  t = s2 < s3 ? s2 : s3; s3 = s2 < s3 ? s3 : s2; s2 = t;
  t = s1 < s2 ? s1 : s2; s2 = s1 < s2 ? s2 : s1; s1 = t;
  t = s0 < s1 ? s0 : s1; s1 = s0 < s1 ? s1 : s0; s0 = t;
}

// one extraction round: returns wave-uniform winning m (low 32 of min key)
__device__ __forceinline__ unsigned pool_extract(uint64_t& s0, uint64_t& s1,
                                                 uint64_t& s2, uint64_t& s3, int lane,
                                                 int& cnt) {
  unsigned h32 = (unsigned)(s0 >> 32);
  unsigned wmin = h32;
#pragma unroll
  for (int s = 1; s < 64; s <<= 1)
    wmin = min(wmin, (unsigned)__shfl_xor((int)wmin, s, 64));
  bool own = (h32 == wmin);
  unsigned long long bal = __ballot(own);
  unsigned lo = (unsigned)s0;
  unsigned wlo;
  if (__popcll(bal) > 1) {  // hi-tie (rare): resolve by low word (index)
    unsigned lo2 = own ? lo : 0xFFFFFFFFu;
#pragma unroll
    for (int s = 1; s < 64; s <<= 1)
      lo2 = min(lo2, (unsigned)__shfl_xor((int)lo2, s, 64));
    wlo = lo2;
  } else {
    int owner = __ffsll((unsigned long long)bal) - 1;
    wlo = (unsigned)__shfl((int)lo, owner, 64);
  }
  bool ex = own && (lo == wlo);
  cnt += ex ? 1 : 0;
  s0 = ex ? s1 : s0; s1 = ex ? s2 : s1; s2 = ex ? s3 : s2; s3 = ex ? ~0ull : s3;
  return wlo;
}

// ---------------------------------------------------------------- knn1 + cov (1 query per wave)
__global__ __launch_bounds__(256) void k_knn1_cov(const float* __restrict__ x,
                                                  float* __restrict__ h0) {
  const int b = blockIdx.y;
  const int tid = threadIdx.x;
  const int lane = tid & 63;
  const int w = tid >> 6;
  __shared__ float4 xsq[NPTS];
  const float* xb = x + (size_t)b * NPTS * 3;
  for (int i = tid; i < NPTS; i += 256) {
    float a0 = xb[3 * i], a1 = xb[3 * i + 1], a2 = xb[3 * i + 2];
    xsq[i] = make_float4(a0, a1, a2, fmaf(a0, a0, fmaf(a1, a1, a2 * a2)));
  }
  __syncthreads();
  const int nq = blockIdx.x * 4 + w;
  const float4 q4 = xsq[nq];
  const float sqq = q4.w;
  float d[32];
  uint64_t s0 = ~0ull, s1 = ~0ull, s2 = ~0ull, s3 = ~0ull;
#pragma unroll
  for (int j = 0; j < 32; ++j) {
    float4 v = xsq[j * 64 + lane];
    float dot = q4.x * v.x;
    dot = fmaf(q4.y, v.y, dot);
    dot = fmaf(q4.z, v.z, dot);
    float dd = fmaf(-2.f, dot, sqq + v.w);
    d[j] = dd;
    uint64_t k = ((uint64_t)f2sort(dd) << 32) | (unsigned)(j * 64 + lane);
    pool_insert(k, s0, s1, s2, s3);
  }
  int widx[16];
  int cnt = 0;
#pragma unroll
  for (int r = 0; r < 16; ++r)
    widx[r] = (int)pool_extract(s0, s1, s2, s3, lane, cnt);
  if (__ballot(cnt == 4) != 0ull) {  // rare exact fallback
    unsigned mask = 0;
#pragma unroll
    for (int r = 0; r < 16; ++r) {
      float vmin = 3.4e38f;
      int mmin = 0x7fffffff;
#pragma unroll
      for (int j = 0; j < 32; ++j) {
        bool ok = !((mask >> j) & 1u) && (d[j] < vmin);
        if (ok) { vmin = d[j]; mmin = j * 64 + lane; }
      }
#pragma unroll
      for (int s = 1; s < 64; s <<= 1) {
        float ov = __shfl_xor(vmin, s, 64);
        int om = __shfl_xor(mmin, s, 64);
        if (ov < vmin || (ov == vmin && om < mmin)) { vmin = ov; mmin = om; }
      }
      widx[r] = mmin;
      if (lane == (mmin & 63)) mask |= 1u << (mmin >> 6);
    }
  }
  // two-pass mean/cov (wave-uniform broadcast reads)
  float sx = 0, sy = 0, sz = 0;
#pragma unroll
  for (int r = 0; r < 16; ++r) {
    float4 v = xsq[widx[r]];
    sx += v.x; sy += v.y; sz += v.z;
  }
  const float mx = sx * 0.0625f, my = sy * 0.0625f, mz = sz * 0.0625f;
  float cxx = 0, cxy = 0, cxz = 0, cyy = 0, cyz = 0, czz = 0;
#pragma unroll
  for (int r = 0; r < 16; ++r) {
    float4 v = xsq[widx[r]];
    float ax = v.x - mx, ay = v.y - my, az = v.z - mz;
    cxx = fmaf(ax, ax, cxx); cxy = fmaf(ax, ay, cxy); cxz = fmaf(ax, az, cxz);
    cyy = fmaf(ay, ay, cyy); cyz = fmaf(ay, az, cyz); czz = fmaf(az, az, czz);
  }
  if (lane == 0) {
    float* o = h0 + ((size_t)b * NPTS + nq) * 12;
    *(float4*)&o[0] = make_float4(q4.x, q4.y, q4.z, cxx);
    *(float4*)&o[4] = make_float4(cxy, cxz, cxy, cyy);
    *(float4*)&o[8] = make_float4(cyz, cxz, cyz, czz);
  }
}

// ---------------------------------------------------------------- MLP1 (12->12->64->64, BN folded) + bf16 plane epilogue
__global__ __launch_bounds__(256) void k_mlp1(
    const float* __restrict__ h0,
    const float* __restrict__ w1, const float* __restrict__ cb1,
    const float* __restrict__ w2, const float* __restrict__ cb2,
    const float* __restrict__ w3, const float* __restrict__ cb3,
    const float* __restrict__ bn1g, const float* __restrict__ bn1b,
    const float* __restrict__ bn1m, const float* __restrict__ bn1v,
    const float* __restrict__ bn2g, const float* __restrict__ bn2b,
    const float* __restrict__ bn2m, const float* __restrict__ bn2v,
    const float* __restrict__ bn3g, const float* __restrict__ bn3b,
    const float* __restrict__ bn3m, const float* __restrict__ bn3v,
    float* __restrict__ h3out,
    unsigned short* __restrict__ h3hi, unsigned short* __restrict__ h3lo) {
  __shared__ float W1[144], W2[768], W3[4096];
  __shared__ float S1[12], F1[12], S2[64], F2[64], S3[64], F3[64];
  __shared__ float h0s[64][12];
  __shared__ float A2[64][65];
  const int tid = threadIdx.x;
  for (int i = tid; i < 144; i += 256) W1[i] = w1[i];
  for (int i = tid; i < 768; i += 256) W2[i] = w2[i];
  for (int i = tid; i < 4096; i += 256) W3[i] = w3[i];
  if (tid < 12) {
    float s = bn1g[tid] * rsqrtf(bn1v[tid] + 1e-3f);
    S1[tid] = s; F1[tid] = (cb1[tid] - bn1m[tid]) * s + bn1b[tid];
  }
  if (tid < 64) {
    float s2 = bn2g[tid] * rsqrtf(bn2v[tid] + 1e-3f);
    S2[tid] = s2; F2[tid] = (cb2[tid] - bn2m[tid]) * s2 + bn2b[tid];
    float s3 = bn3g[tid] * rsqrtf(bn3v[tid] + 1e-3f);
    S3[tid] = s3; F3[tid] = (cb3[tid] - bn3m[tid]) * s3 + bn3b[tid];
  }
  const int p0 = blockIdx.x * 64;
  for (int i = tid; i < 64 * 12; i += 256)
    h0s[i / 12][i % 12] = h0[(size_t)p0 * 12 + i];
  __syncthreads();
  const int pl = tid >> 2;
  const int q = tid & 3;
  float v1[12];
#pragma unroll
  for (int o = 0; o < 12; ++o) {
    float a = 0.f;
#pragma unroll
    for (int i = 0; i < 12; ++i) a = fmaf(h0s[pl][i], W1[i * 12 + o], a);
    v1[o] = fmaxf(fmaf(a, S1[o], F1[o]), 0.f);
  }
#pragma unroll
  for (int o = 0; o < 16; ++o) {
    int oo = q * 16 + o;
    float a = 0.f;
#pragma unroll
    for (int i = 0; i < 12; ++i) a = fmaf(v1[i], W2[i * 64 + oo], a);
    A2[pl][oo] = fmaxf(fmaf(a, S2[oo], F2[oo]), 0.f);
  }
  __syncthreads();
  float acc[16];
#pragma unroll
  for (int o = 0; o < 16; ++o) acc[o] = 0.f;
  for (int i = 0; i < 64; ++i) {
    float xv = A2[pl][i];
#pragma unroll
    for (int o = 0; o < 16; ++o) acc[o] = fmaf(xv, W3[i * 64 + q * 16 + o], acc[o]);
  }
  float vals[16];
#pragma unroll
  for (int o = 0; o < 16; ++o) {
    int oo = q * 16 + o;
    vals[o] = fmaxf(fmaf(acc[o], S3[oo], F3[oo]), 0.f);
  }
  const size_t rowo = (size_t)(p0 + pl) * 64 + q * 16;
  float* orow = h3out + rowo;
#pragma unroll
  for (int o4 = 0; o4 < 4; ++o4)
    *(float4*)&orow[4 * o4] = make_float4(vals[4 * o4], vals[4 * o4 + 1],
                                          vals[4 * o4 + 2], vals[4 * o4 + 3]);
  bf16x8 hv0, hv1, lv0, lv1;
#pragma unroll
  for (int o = 0; o < 8; ++o) {
    unsigned short hb = f2bf(vals[o]);
    hv0[o] = (short)hb; lv0[o] = (short)f2bf(vals[o] - bf2f(hb));
    unsigned short hb1 = f2bf(vals[8 + o]);
    hv1[o] = (short)hb1; lv1[o] = (short)f2bf(vals[8 + o] - bf2f(hb1));
  }
  *(bf16x8*)&h3hi[rowo] = hv0; *(bf16x8*)&h3hi[rowo + 8] = hv1;
  *(bf16x8*)&h3lo[rowo] = lv0; *(bf16x8*)&h3lo[rowo + 8] = lv1;
}

// ---------------------------------------------------------------- sq norms
template <int C>
__global__ __launch_bounds__(256) void k_sqnorm(const float* __restrict__ h,
                                                float* __restrict__ sq) {
  const int p = blockIdx.x * 256 + threadIdx.x;
  const float* row = h + (size_t)p * C;
  float a = 0.f;
#pragma unroll
  for (int i = 0; i < C; ++i) a = fmaf(row[i], row[i], a);
  sq[p] = a;
}

// ---------------------------------------------------------------- FUSED knn v2: 1024 thr / 16 waves; 16 queries; XCD-swizzled grid
// phase1: wave w computes 16q x 128cand tile -> dmat; phase2: wave w selects query w.
template <int C>
__global__ __launch_bounds__(1024, 4) void k_knn_fused(
    const unsigned short* __restrict__ hi, const unsigned short* __restrict__ lo,
    const float* __restrict__ sq, const float* __restrict__ h,
    unsigned short* __restrict__ mhi, unsigned short* __restrict__ mlo) {
  __shared__ float dmat[16][NPTS];  // 128 KiB
  const int tid = threadIdx.x, lane = tid & 63, w = tid >> 6;
  // XCD swizzle: each XCD owns 2 batches -> B-plane slab stays L2-resident
  const int f = blockIdx.x;
  const int g = ((f & 7) << 8) | (f >> 3);
  const int b = g >> 7;
  const int q0 = (g & 127) * 16;
  const size_t base = (size_t)b * NPTS * C;
  const float* __restrict__ sqb = sq + (size_t)b * NPTS;
  const int r = lane & 15, ks = (lane >> 4) * 8;
  const unsigned short* Ah = hi + base + (size_t)(q0 + r) * C + ks;
  const unsigned short* Al = lo + base + (size_t)(q0 + r) * C + ks;
  float sqq[4];
#pragma unroll
  for (int r2 = 0; r2 < 4; ++r2) sqq[r2] = sqb[q0 + (lane >> 4) * 4 + r2];

  // ---- phase 1: wave w -> candidates [w*128, w*128+128)
  {
    const int m0 = w * 128;
    const unsigned short* Bh = hi + base + (size_t)(m0 + r) * C + ks;
    const unsigned short* Bl = lo + base + (size_t)(m0 + r) * C + ks;
    f32x4 acc[8];
#pragma unroll
    for (int s = 0; s < 8; ++s) acc[s] = (f32x4){0.f, 0.f, 0.f, 0.f};
#pragma unroll
    for (int kk = 0; kk < C; kk += 32) {
      bf16x8 ah = *(const bf16x8*)(Ah + kk);
      bf16x8 al = *(const bf16x8*)(Al + kk);
#pragma unroll
      for (int s = 0; s < 8; ++s) {
        bf16x8 bh = *(const bf16x8*)(Bh + (size_t)s * 16 * C + kk);
        bf16x8 bl = *(const bf16x8*)(Bl + (size_t)s * 16 * C + kk);
        acc[s] = __builtin_amdgcn_mfma_f32_16x16x32_bf16(ah, bh, acc[s], 0, 0, 0);
        acc[s] = __builtin_amdgcn_mfma_f32_16x16x32_bf16(ah, bl, acc[s], 0, 0, 0);
        acc[s] = __builtin_amdgcn_mfma_f32_16x16x32_bf16(al, bh, acc[s], 0, 0, 0);
      }
    }
#pragma unroll
    for (int s = 0; s < 8; ++s) {
      const int col = m0 + s * 16 + (lane & 15);
      float smc = sqb[col];
#pragma unroll
      for (int r2 = 0; r2 < 4; ++r2)
        dmat[(lane >> 4) * 4 + r2][col] = fmaf(-2.f, acc[s][r2], sqq[r2] + smc);
    }
  }
  __syncthreads();

  // ---- phase 2: wave w selects query w
  const float* __restrict__ hbp = h + base;
  const int q = q0 + w;
  float d[32];
  uint64_t s0 = ~0ull, s1 = ~0ull, s2 = ~0ull, s3 = ~0ull;
#pragma unroll
  for (int t = 0; t < 8; ++t) {
    float4 dv = *(const float4*)&dmat[w][t * 256 + 4 * lane];
    d[4 * t + 0] = dv.x; d[4 * t + 1] = dv.y;
    d[4 * t + 2] = dv.z; d[4 * t + 3] = dv.w;
  }
#pragma unroll
  for (int j = 0; j < 32; ++j) {
    unsigned m = (unsigned)((j >> 2) * 256 + 4 * lane + (j & 3));
    uint64_t k = ((uint64_t)f2sort(d[j]) << 32) | m;
    pool_insert(k, s0, s1, s2, s3);
  }
  int cnt = 0;
  float g0 = -3.4e38f, g1 = -3.4e38f;
#pragma unroll
  for (int rr = 0; rr < 16; ++rr) {
    unsigned m = pool_extract(s0, s1, s2, s3, lane, cnt);
    const float* row = hbp + (size_t)m * C;
    g0 = fmaxf(g0, row[lane]);
    if (C == 128) g1 = fmaxf(g1, row[64 + lane]);
  }
  if (__ballot(cnt == 4) != 0ull) {  // rare exact fallback
    unsigned mask = 0u;
    g0 = -3.4e38f; g1 = -3.4e38f;
#pragma unroll 1
    for (int rr = 0; rr < 16; ++rr) {
      float vmin = 3.4e38f;
      int mmin = 0x7fffffff;
#pragma unroll
      for (int j = 0; j < 32; ++j) {
        const int m = (j >> 2) * 256 + 4 * lane + (j & 3);
        bool ok = !((mask >> j) & 1u) && (d[j] < vmin);
        if (ok) { vmin = d[j]; mmin = m; }
      }
#pragma unroll
      for (int s = 1; s < 64; s <<= 1) {
        float ov = __shfl_xor(vmin, s, 64);
        int om = __shfl_xor(mmin, s, 64);
        if (ov < vmin || (ov == vmin && om < mmin)) { vmin = ov; mmin = om; }
      }
      if (lane == ((mmin >> 2) & 63)) mask |= 1u << (((mmin >> 8) << 2) | (mmin & 3));
      const float* row = hbp + (size_t)mmin * C;
      g0 = fmaxf(g0, row[lane]);
      if (C == 128) g1 = fmaxf(g1, row[64 + lane]);
    }
  }
  const size_t orow = base + (size_t)q * C;
  unsigned short h0b = f2bf(g0);
  mhi[orow + lane] = h0b;
  mlo[orow + lane] = f2bf(g0 - bf2f(h0b));
  if (C == 128) {
    unsigned short h1b = f2bf(g1);
    mhi[orow + 64 + lane] = h1b;
    mlo[orow + 64 + lane] = f2bf(g1 - bf2f(h1b));
  }
}

// ---------------------------------------------------------------- combine denses -> W^T bf16 planes + bias
__global__ __launch_bounds__(256) void k_combine_t(const float* __restrict__ lw,
                                                   const float* __restrict__ lb,
                                                   const float* __restrict__ cw,
                                                   const float* __restrict__ cb,
                                                   unsigned short* __restrict__ wthi,
                                                   unsigned short* __restrict__ wtlo,
                                                   float* __restrict__ bc, int K, int M) {
  const int id = blockIdx.x * 256 + threadIdx.x;
  if (id < K * M) {
    int i = id / M, o = id % M;
    float a = 0.f;
    for (int k = 0; k < K; ++k) a = fmaf(lw[i * K + k], cw[k * M + o], a);
    unsigned short hb = f2bf(a);
    wthi[(size_t)o * K + i] = hb;
    wtlo[(size_t)o * K + i] = f2bf(a - bf2f(hb));
  }
  if (id < M) {
    float a = cb[id];
    for (int k = 0; k < K; ++k) a = fmaf(lb[k], cw[k * M + id], a);
    bc[id] = a;
  }
}

// ---------------------------------------------------------------- MFMA apply: out = A[32768,K]*W[K,M]+bias, RELU->f32+planes | COLMAX->P
template <int K, int M, bool RELU, bool COLMAX>
__global__ __launch_bounds__(256) void k_apply_mfma(
    const unsigned short* __restrict__ Ah, const unsigned short* __restrict__ Al,
    const unsigned short* __restrict__ Wh, const unsigned short* __restrict__ Wl,
    const float* __restrict__ bias, float* __restrict__ fout,
    unsigned short* __restrict__ phi, unsigned short* __restrict__ plo) {
  __shared__ float cm[4][128];
  const int tid = threadIdx.x, lane = tid & 63, w = tid >> 6;
  const int rt = blockIdx.x;
  const int q0 = rt * 64 + w * 16;
  const int m0 = blockIdx.y * 128;
  const int r = lane & 15, ks = (lane >> 4) * 8;
  const unsigned short* ap_h = Ah + (size_t)(q0 + r) * K + ks;
  const unsigned short* ap_l = Al + (size_t)(q0 + r) * K + ks;
  const unsigned short* bp_h = Wh + (size_t)(m0 + r) * K + ks;
  const unsigned short* bp_l = Wl + (size_t)(m0 + r) * K + ks;
  f32x4 acc[8];
#pragma unroll
  for (int mt = 0; mt < 8; ++mt) acc[mt] = (f32x4){0.f, 0.f, 0.f, 0.f};
#pragma unroll
  for (int kk = 0; kk < K; kk += 32) {
    bf16x8 ah = *(const bf16x8*)(ap_h + kk);
    bf16x8 al = *(const bf16x8*)(ap_l + kk);
#pragma unroll
    for (int mt = 0; mt < 8; ++mt) {
      bf16x8 bh = *(const bf16x8*)(bp_h + (size_t)mt * 16 * K + kk);
      bf16x8 bl = *(const bf16x8*)(bp_l + (size_t)mt * 16 * K + kk);
      acc[mt] = __builtin_amdgcn_mfma_f32_16x16x32_bf16(ah, bh, acc[mt], 0, 0, 0);
      acc[mt] = __builtin_amdgcn_mfma_f32_16x16x32_bf16(ah, bl, acc[mt], 0, 0, 0);
      acc[mt] = __builtin_amdgcn_mfma_f32_16x16x32_bf16(al, bh, acc[mt], 0, 0, 0);
    }
  }
  if (RELU) {
#pragma unroll
    for (int mt = 0; mt < 8; ++mt) {
      const int col = m0 + mt * 16 + (lane & 15);
      const float bv = bias[col];
#pragma unroll
      for (int r2 = 0; r2 < 4; ++r2) {
        const int row = q0 + (lane >> 4) * 4 + r2;
        float v = fmaxf(acc[mt][r2] + bv, 0.f);
        const size_t idx = (size_t)row * M + col;
        fout[idx] = v;
        unsigned short hb = f2bf(v);
        phi[idx] = hb;
        plo[idx] = f2bf(v - bf2f(hb));
      }
    }
  }
  if (COLMAX) {
#pragma unroll
    for (int mt = 0; mt < 8; ++mt) {
      float v = fmaxf(fmaxf(acc[mt][0], acc[mt][1]), fmaxf(acc[mt][2], acc[mt][3]));
      v = fmaxf(v, __shfl_xor(v, 16, 64));
      v = fmaxf(v, __shfl_xor(v, 32, 64));
      cm[w][mt * 16 + (lane & 15)] = v;
    }
    __syncthreads();
    if (tid < 128) {
      float m = fmaxf(fmaxf(cm[0][tid], cm[1][tid]), fmaxf(cm[2][tid], cm[3][tid]));
      fout[(size_t)rt * M + m0 + tid] = m + bias[m0 + tid];
    }
  }
}

// ---------------------------------------------------------------- reduce P[512][1024] -> gmax[16][1024]
__global__ __launch_bounds__(256) void k_reduce_max(const float* __restrict__ P,
                                                    float* __restrict__ gmax) {
  const int b = blockIdx.x, tid = threadIdx.x;
  for (int c = tid; c < 1024; c += 256) {
    float m = P[(size_t)(b * 32) * 1024 + c];
    for (int rt = 1; rt < 32; ++rt)
      m = fmaxf(m, P[(size_t)(b * 32 + rt) * 1024 + c]);
    gmax[b * 1024 + c] = m;
  }
}

// ---------------------------------------------------------------- head part 1: hid = relu(gmax*W4+b4)
__global__ __launch_bounds__(256) void k_head1(const float* __restrict__ gmax,
                                               const float* __restrict__ w4,
                                               const float* __restrict__ b4,
                                               float* __restrict__ hid) {
  const int b = blockIdx.y, c0 = blockIdx.x * 64;
  const int tid = threadIdx.x;
  const int c = tid & 63, iq = tid >> 6;
  __shared__ float xs[1024];
  __shared__ float red[4][64];
  for (int i = tid; i < 1024; i += 256) xs[i] = gmax[b * 1024 + i];
  __syncthreads();
  float a = 0.f;
  for (int i = iq * 256; i < iq * 256 + 256; ++i)
    a = fmaf(xs[i], w4[(size_t)i * 1024 + c0 + c], a);
  red[iq][c] = a;
  __syncthreads();
  if (tid < 64) {
    float v = red[0][tid] + red[1][tid] + red[2][tid] + red[3][tid];
    hid[b * 1024 + c0 + tid] = fmaxf(v + b4[c0 + tid], 0.f);
  }
}

// ---------------------------------------------------------------- head part 2: out = hid*W5+b5
__global__ __launch_bounds__(256) void k_head2(const float* __restrict__ hid,
                                               const float* __restrict__ w5,
                                               const float* __restrict__ b5,
                                               float* __restrict__ out) {
  const int b = blockIdx.y, c0 = blockIdx.x * 64;
  const int tid = threadIdx.x;
  const int c = tid & 63, iq = tid >> 6;
  __shared__ float xs[1024];
  __shared__ float red[4][64];
  for (int i = tid; i < 1024; i += 256) xs[i] = hid[b * 1024 + i];
  __syncthreads();
  float a = 0.f;
  for (int i = iq * 256; i < iq * 256 + 256; ++i)
    a = fmaf(xs[i], w5[(size_t)i * 512 + c0 + c], a);
  red[iq][c] = a;
  __syncthreads();
  if (tid < 64) {
    float v = red[0][tid] + red[1][tid] + red[2][tid] + red[3][tid];
    out[(size_t)b * 512 + c0 + tid] = v + b5[c0 + tid];
  }
}

// ----------------------------------------------------------------
extern "C" void kernel_launch(void* const* d_in, const int* in_sizes, int n_in,
                              void* d_out, int out_size, void* d_ws, size_t ws_size,
                              hipStream_t stream) {
  (void)in_sizes; (void)n_in; (void)out_size; (void)ws_size;
  const float* x = (const float*)d_in[0];
  const float* w1 = (const float*)d_in[1];  const float* b1 = (const float*)d_in[2];
  const float* w2 = (const float*)d_in[3];  const float* b2 = (const float*)d_in[4];
  const float* w3 = (const float*)d_in[5];  const float* b3 = (const float*)d_in[6];
  const float* g1lw = (const float*)d_in[7];  const float* g1lb = (const float*)d_in[8];
  const float* g1cw = (const float*)d_in[9];  const float* g1cb = (const float*)d_in[10];
  const float* g2lw = (const float*)d_in[11]; const float* g2lb = (const float*)d_in[12];
  const float* g2cw = (const float*)d_in[13]; const float* g2cb = (const float*)d_in[14];
  const float* w4 = (const float*)d_in[15]; const float* b4 = (const float*)d_in[16];
  const float* w5 = (const float*)d_in[17]; const float* b5 = (const float*)d_in[18];
  const float* bn1g = (const float*)d_in[19]; const float* bn1b = (const float*)d_in[20];
  const float* bn1m = (const float*)d_in[21]; const float* bn1v = (const float*)d_in[22];
  const float* bn2g = (const float*)d_in[23]; const float* bn2b = (const float*)d_in[24];
  const float* bn2m = (const float*)d_in[25]; const float* bn2v = (const float*)d_in[26];
  const float* bn3g = (const float*)d_in[27]; const float* bn3b = (const float*)d_in[28];
  const float* bn3m = (const float*)d_in[29]; const float* bn3v = (const float*)d_in[30];

  float* ws = (float*)d_ws;
  size_t off = 0;
  auto alloc = [&](size_t n) { float* p = ws + off; off += (n + 63) & ~(size_t)63; return p; };
  float* slotA = alloc(16u * 2048 * 128);   // h0 then h4 f32
  float* slotB = alloc(16u * 2048 * 64);    // h3 f32
  float* sqv  = alloc(16u * 2048);
  unsigned short* hi_h = (unsigned short*)alloc(16u * 2048 * 64);  // h planes (stride 64 then 128)
  unsigned short* lo_h = (unsigned short*)alloc(16u * 2048 * 64);
  unsigned short* mhi = (unsigned short*)alloc(16u * 2048 * 64);   // gather-max planes
  unsigned short* mlo = (unsigned short*)alloc(16u * 2048 * 64);
  unsigned short* wthi = (unsigned short*)alloc(65536);            // W^T planes (max 1024x128)
  unsigned short* wtlo = (unsigned short*)alloc(65536);
  float* bc   = alloc(1024);
  float* P    = alloc(512u * 1024);
  float* gm   = alloc(16u * 1024);
  float* hid  = alloc(16u * 1024);

  // 1: knn on xyz + covariance -> h0[B,N,12]
  k_knn1_cov<<<dim3(512, 16), 256, 0, stream>>>(x, slotA);
  // 2: MLP1 -> h3 f32 + bf16 planes
  k_mlp1<<<512, 256, 0, stream>>>(slotA, w1, b1, w2, b2, w3, b3,
                                  bn1g, bn1b, bn1m, bn1v,
                                  bn2g, bn2b, bn2m, bn2v,
                                  bn3g, bn3b, bn3m, bn3v, slotB, hi_h, lo_h);
  // 3: knn(64) fused -> m1 planes
  k_sqnorm<64><<<128, 256, 0, stream>>>(slotB, sqv);
  k_knn_fused<64><<<2048, 1024, 0, stream>>>(hi_h, lo_h, sqv, slotB, mhi, mlo);
  // 4: g1 combined dense 64->128 + relu -> h4 f32 + planes (MFMA)
  k_combine_t<<<32, 256, 0, stream>>>(g1lw, g1lb, g1cw, g1cb, wthi, wtlo, bc, 64, 128);
  k_apply_mfma<64, 128, true, false><<<dim3(512, 1), 256, 0, stream>>>(
      mhi, mlo, wthi, wtlo, bc, slotA, hi_h, lo_h);
  // 5: knn(128) fused -> m2 planes
  k_sqnorm<128><<<128, 256, 0, stream>>>(slotA, sqv);
  k_knn_fused<128><<<2048, 1024, 0, stream>>>(hi_h, lo_h, sqv, slotA, mhi, mlo);
  // 6: g2 combined dense 128->1024 + colmax -> P (MFMA)
  k_combine_t<<<512, 256, 0, stream>>>(g2lw, g2lb, g2cw, g2cb, wthi, wtlo, bc, 128, 1024);
  k_apply_mfma<128, 1024, false, true><<<dim3(512, 8), 256, 0, stream>>>(
      mhi, mlo, wthi, wtlo, bc, P, nullptr, nullptr);
  // 7: reduce -> gmax[16][1024]
  k_reduce_max<<<16, 256, 0, stream>>>(P, gm);
  // 8: head -> out[16][512]
  k_head1<<<dim3(16, 16), 256, 0, stream>>>(gm, w4, b4, hid);
  k_head2<<<dim3(8, 16), 256, 0, stream>>>(hid, w5, b5, (float*)d_out);
}